// Round 1
// baseline (5043.167 us; speedup 1.0000x reference)
//
#include <hip/hip_runtime.h>
#include <math.h>

// ---------------------------------------------------------------------------
// TACDSR forward on MI355X — round 0: full f32 implementation, correctness
// first. Structure: per encoder e in {o,x,y}:
//   spmm(acc) -> gather seqs -> temb MLP -> +pos -> gates -> mask ->
//   2x [ LN -> Q/K/V proj -> fused gated causal attention -> residual ->
//        LN -> FFN(relu 128->128) -> residual -> mask ] -> final LN -> out
// ---------------------------------------------------------------------------

#define kH 128
#define kT 200
#define kBATCH 128
#define kM (kBATCH * kT)         // 25600 tokens
#define kITEMS 100000
#define kNNZ 1600000
#define kNEG_INF (-__builtin_huge_valf())

// ---------------- SpMM scatter: acc[row] += val * emb[col] ----------------
__global__ __launch_bounds__(256) void spmm_kernel(
    const int* __restrict__ idx, const float* __restrict__ val,
    const float* __restrict__ emb, float* __restrict__ acc, int nnz)
{
    const int j = blockIdx.x * 4 + (threadIdx.x >> 6);
    const int lane = threadIdx.x & 63;
    if (j >= nnz) return;
    const int row = idx[j];
    const int col = idx[nnz + j];
    const float v = val[j];
    atomicAdd(&acc[(size_t)row * kH + lane],      v * emb[(size_t)col * kH + lane]);
    atomicAdd(&acc[(size_t)row * kH + 64 + lane], v * emb[(size_t)col * kH + 64 + lane]);
}

// ------------- seqs = 1.5*emb[s] + 0.5 * acc[s]/max(||acc[s]||,1e-12) -----
__global__ void gather_seq_kernel(
    const int* __restrict__ ids, const float* __restrict__ emb,
    const float* __restrict__ acc, float* __restrict__ seqs)
{
    const int tok = blockIdx.x;
    const int c = threadIdx.x;
    const int s = ids[tok];
    const float a = acc[(size_t)s * kH + c];
    __shared__ float red[128];
    red[c] = a * a;
    __syncthreads();
    for (int st = 64; st > 0; st >>= 1) {
        if (c < st) red[c] += red[c + st];
        __syncthreads();
    }
    const float denom = fmaxf(sqrtf(red[0]), 1e-12f);
    seqs[(size_t)tok * kH + c] = 1.5f * emb[(size_t)s * kH + c] + 0.5f * a / denom;
}

// ------------- x = interval_table[floor(log2(t+1))] + time_table[tt] ------
__global__ void build_x_kernel(
    const int* __restrict__ itv, const int* __restrict__ tt,
    const float* __restrict__ interval_table, const float* __restrict__ time_table,
    float* __restrict__ x)
{
    const int tok = blockIdx.x * 2 + (threadIdx.x >> 7);
    const int c = threadIdx.x & 127;
    const int t = itv[tok];
    int idx = (int)floorf(log2f((float)t + 1.0f));
    idx = idx < 0 ? 0 : (idx > 30 ? 30 : idx);
    x[(size_t)tok * kH + c] = interval_table[idx * kH + c] + time_table[(size_t)tt[tok] * kH + c];
}

// ---------------- tiled f32 GEMM: C = [relu](A@B + bias) [+ C] ------------
// A: MxK row-major, B: KxN row-major, tile 128x128, BK=8, 256 thr, 8x8 micro
__global__ __launch_bounds__(256) void gemm_kernel(
    const float* __restrict__ A, const float* __restrict__ B,
    const float* __restrict__ bias, float* __restrict__ C,
    int M, int N, int K, int relu, int accum)
{
    __shared__ __align__(16) float AsT[8][132];
    __shared__ __align__(16) float Bs[8][132];
    const int tid = threadIdx.x;
    const int tx = tid & 15;
    const int ty = tid >> 4;
    const int rowBase = blockIdx.y * 128;
    const int colBase = blockIdx.x * 128;
    float acc[8][8] = {};
    for (int k0 = 0; k0 < K; k0 += 8) {
        {
            const int r = tid >> 1;
            const int c4 = (tid & 1) * 4;
            const float4 a = *reinterpret_cast<const float4*>(
                &A[(size_t)(rowBase + r) * K + k0 + c4]);
            AsT[c4 + 0][r] = a.x; AsT[c4 + 1][r] = a.y;
            AsT[c4 + 2][r] = a.z; AsT[c4 + 3][r] = a.w;
        }
        {
            const int r = tid >> 5;
            const int c4 = (tid & 31) * 4;
            const float4 b = *reinterpret_cast<const float4*>(
                &B[(size_t)(k0 + r) * N + colBase + c4]);
            Bs[r][c4 + 0] = b.x; Bs[r][c4 + 1] = b.y;
            Bs[r][c4 + 2] = b.z; Bs[r][c4 + 3] = b.w;
        }
        __syncthreads();
#pragma unroll
        for (int kk = 0; kk < 8; ++kk) {
            const float4 a0 = *reinterpret_cast<const float4*>(&AsT[kk][ty * 8]);
            const float4 a1 = *reinterpret_cast<const float4*>(&AsT[kk][ty * 8 + 4]);
            const float4 b0 = *reinterpret_cast<const float4*>(&Bs[kk][tx * 8]);
            const float4 b1 = *reinterpret_cast<const float4*>(&Bs[kk][tx * 8 + 4]);
            const float ar[8] = {a0.x, a0.y, a0.z, a0.w, a1.x, a1.y, a1.z, a1.w};
            const float br[8] = {b0.x, b0.y, b0.z, b0.w, b1.x, b1.y, b1.z, b1.w};
#pragma unroll
            for (int i = 0; i < 8; ++i)
#pragma unroll
                for (int j = 0; j < 8; ++j)
                    acc[i][j] += ar[i] * br[j];
        }
        __syncthreads();
    }
#pragma unroll
    for (int i = 0; i < 8; ++i) {
        const int row = rowBase + ty * 8 + i;
#pragma unroll
        for (int j = 0; j < 8; ++j) {
            const int col = colBase + tx * 8 + j;
            float v = acc[i][j] + bias[col];
            if (relu) v = fmaxf(v, 0.f);
            const size_t off = (size_t)row * N + col;
            if (accum) v += C[off];
            C[off] = v;
        }
    }
}

// ---------------- LayerNorm over H=128 (in may equal out) -----------------
__global__ void ln_kernel(
    const float* __restrict__ in, float* __restrict__ out,
    const float* __restrict__ g, const float* __restrict__ bb, float eps)
{
    const int tok = blockIdx.x;
    const int c = threadIdx.x;
    const float x = in[(size_t)tok * kH + c];
    __shared__ float r1[128], r2[128];
    r1[c] = x; r2[c] = x * x;
    __syncthreads();
    for (int st = 64; st > 0; st >>= 1) {
        if (c < st) { r1[c] += r1[c + st]; r2[c] += r2[c + st]; }
        __syncthreads();
    }
    const float mean = r1[0] * (1.f / 128.f);
    float var = r2[0] * (1.f / 128.f) - mean * mean;
    var = fmaxf(var, 0.f);
    out[(size_t)tok * kH + c] = (x - mean) * rsqrtf(var + eps) * g[c] + bb[c];
}

// ---------------- seqs += pos_emb[pos]; temb += pos_emb[pos] --------------
__global__ void posadd_kernel(
    const int* __restrict__ pos, const float* __restrict__ pemb,
    float* __restrict__ seqs, float* __restrict__ temb)
{
    const int tok = blockIdx.x * 2 + (threadIdx.x >> 7);
    const int c = threadIdx.x & 127;
    const float p = pemb[(size_t)pos[tok] * kH + c];
    seqs[(size_t)tok * kH + c] += p;
    temb[(size_t)tok * kH + c] += p;
}

// ---------------- gates = sigmoid(temb @ gate_W + gate_b) -----------------
__global__ void gates_kernel(
    const float* __restrict__ temb, const float* __restrict__ gW,
    const float* __restrict__ gb, float* __restrict__ gates)
{
    const int wv = threadIdx.x >> 6;
    const int lane = threadIdx.x & 63;
    const int tok = blockIdx.x * 4 + wv;
    const float t0 = temb[(size_t)tok * kH + lane];
    const float t1 = temb[(size_t)tok * kH + 64 + lane];
#pragma unroll
    for (int i = 0; i < 2; ++i) {
        float p = t0 * gW[lane * 2 + i] + t1 * gW[(64 + lane) * 2 + i];
#pragma unroll
        for (int off = 1; off < 64; off <<= 1) p += __shfl_xor(p, off);
        if (lane == 0) gates[tok * 2 + i] = 1.f / (1.f + expf(-(p + gb[i])));
    }
}

// ---------------- seqs *= (ids != ITEMNUM-1) ------------------------------
__global__ void mask_kernel(float* __restrict__ seqs, const int* __restrict__ ids)
{
    const int i = blockIdx.x * 256 + threadIdx.x;
    if (ids[i >> 7] == kITEMS - 1) seqs[i] = 0.f;
}

// ---------------- out = a + b ---------------------------------------------
__global__ void add_kernel(const float* __restrict__ a, const float* __restrict__ b,
                           float* __restrict__ out)
{
    const int i = blockIdx.x * 256 + threadIdx.x;
    out[i] = a[i] + b[i];
}

// ---------------- fused gated causal attention per (b,h) ------------------
// scores = (q.k)*scale*g_q*g_k, causal mask (k<=q), softmax over k, out=attn@v
__global__ __launch_bounds__(256) void attn_kernel(
    const float* __restrict__ qp, const float* __restrict__ kp,
    const float* __restrict__ vp, const float* __restrict__ gates,
    const int gi, float* __restrict__ outp)
{
    __shared__ float klds[kT * 65];
    __shared__ float vlds[kT * 65];
    __shared__ float glds[kT];
    __shared__ __align__(16) float qlds[4][2][64];
    __shared__ float plds[4][2][kT];
    const int b = (int)blockIdx.x >> 1;
    const int h = (int)blockIdx.x & 1;
    const int hoff = h * 64;
    const int tid = threadIdx.x;
    const size_t base = (size_t)b * kT * kH;
    for (int i = tid; i < kT * 64; i += 256) {
        const int r = i >> 6, d = i & 63;
        klds[r * 65 + d] = kp[base + (size_t)r * kH + hoff + d];
        vlds[r * 65 + d] = vp[base + (size_t)r * kH + hoff + d];
    }
    if (tid < kT) glds[tid] = gates[(b * kT + tid) * 2 + gi];
    __syncthreads();
    const int wv = tid >> 6;
    const int lane = tid & 63;
    const float scale = 0.125f;

    for (int qr0 = wv * 2; qr0 < kT; qr0 += 8) {
        const int qr1 = qr0 + 1;
        qlds[wv][0][lane] = qp[base + (size_t)qr0 * kH + hoff + lane];
        qlds[wv][1][lane] = qp[base + (size_t)qr1 * kH + hoff + lane];
        const float gq0 = glds[qr0];
        const float gq1 = glds[qr1];
        float sc0[4], sc1[4];
#pragma unroll
        for (int kc = 0; kc < 4; ++kc) {
            const int kidx = kc * 64 + lane;
            float v0 = kNEG_INF, v1 = kNEG_INF;
            if (kidx < kT) {
                const float* kr = &klds[kidx * 65];
                float s0 = 0.f, s1 = 0.f;
#pragma unroll
                for (int d = 0; d < 64; d += 4) {
                    const float4 q0 = *reinterpret_cast<const float4*>(&qlds[wv][0][d]);
                    const float4 q1 = *reinterpret_cast<const float4*>(&qlds[wv][1][d]);
                    const float k0 = kr[d], k1 = kr[d + 1], k2 = kr[d + 2], k3 = kr[d + 3];
                    s0 += q0.x * k0 + q0.y * k1 + q0.z * k2 + q0.w * k3;
                    s1 += q1.x * k0 + q1.y * k1 + q1.z * k2 + q1.w * k3;
                }
                const float gk = glds[kidx];
                if (kidx <= qr0) v0 = s0 * scale * gq0 * gk;
                if (kidx <= qr1) v1 = s1 * scale * gq1 * gk;
            }
            sc0[kc] = v0; sc1[kc] = v1;
        }
        float m0 = fmaxf(fmaxf(sc0[0], sc0[1]), fmaxf(sc0[2], sc0[3]));
        float m1 = fmaxf(fmaxf(sc1[0], sc1[1]), fmaxf(sc1[2], sc1[3]));
#pragma unroll
        for (int off = 1; off < 64; off <<= 1) {
            m0 = fmaxf(m0, __shfl_xor(m0, off));
            m1 = fmaxf(m1, __shfl_xor(m1, off));
        }
        float ps0 = 0.f, ps1 = 0.f;
#pragma unroll
        for (int kc = 0; kc < 4; ++kc) {
            const int kidx = kc * 64 + lane;
            const float p0 = expf(sc0[kc] - m0);
            const float p1 = expf(sc1[kc] - m1);
            ps0 += p0; ps1 += p1;
            if (kidx < kT) { plds[wv][0][kidx] = p0; plds[wv][1][kidx] = p1; }
        }
#pragma unroll
        for (int off = 1; off < 64; off <<= 1) {
            ps0 += __shfl_xor(ps0, off);
            ps1 += __shfl_xor(ps1, off);
        }
        float o0 = 0.f, o1 = 0.f;
        for (int k = 0; k <= qr1; ++k) {
            const float vv = vlds[k * 65 + lane];
            o0 += plds[wv][0][k] * vv;
            o1 += plds[wv][1][k] * vv;
        }
        outp[base + (size_t)qr0 * kH + hoff + lane] = o0 / ps0;
        outp[base + (size_t)qr1 * kH + hoff + lane] = o1 / ps1;
    }
}

// ---------------------------------------------------------------------------
extern "C" void kernel_launch(void* const* d_in, const int* in_sizes, int n_in,
                              void* d_out, int out_size, void* d_ws, size_t ws_size,
                              hipStream_t stream)
{
    const int* ids_o = (const int*)d_in[0];
    const int* ids_x = (const int*)d_in[1];
    const int* ids_y = (const int*)d_in[2];
    const int* pos_o = (const int*)d_in[3];
    const int* pos_x = (const int*)d_in[4];
    const int* pos_y = (const int*)d_in[5];
    const int* tm_o  = (const int*)d_in[6];
    const int* tm_x  = (const int*)d_in[7];
    const int* tm_y  = (const int*)d_in[8];
    const int* itv_x = (const int*)d_in[9];
    const int* itv_y = (const int*)d_in[10];
    const int* itv_o = (const int*)d_in[11];
    const float* embX = (const float*)d_in[12];
    const float* embY = (const float*)d_in[13];
    const float* embO = (const float*)d_in[14];
    const float* time_table = (const float*)d_in[15];
    const float* interval_table = (const float*)d_in[16];
    const int* adj_idx  = (const int*)d_in[17];
    const float* adj_val = (const float*)d_in[18];
    const int* adjs_idx  = (const int*)d_in[19];
    const float* adjs_val = (const float*)d_in[20];
    const float* mlp_W1 = (const float*)d_in[21];
    const float* mlp_b1 = (const float*)d_in[22];
    const float* mlp_W2 = (const float*)d_in[23];
    const float* mlp_b2 = (const float*)d_in[24];
    const float* mlp_lng = (const float*)d_in[25];
    const float* mlp_lnb = (const float*)d_in[26];
    const float* pos_emb = (const float*)d_in[27];
    const float* gate_W = (const float*)d_in[28];
    const float* gate_b = (const float*)d_in[29];
    const float* aln_g = (const float*)d_in[30];
    const float* aln_b = (const float*)d_in[31];
    const float* qW = (const float*)d_in[32];
    const float* kW = (const float*)d_in[33];
    const float* vW = (const float*)d_in[34];
    const float* c1W = (const float*)d_in[35];
    const float* c2W = (const float*)d_in[36];
    const float* qb = (const float*)d_in[37];
    const float* kb = (const float*)d_in[38];
    const float* vb = (const float*)d_in[39];
    const float* c1b = (const float*)d_in[40];
    const float* c2b = (const float*)d_in[41];
    const float* fln_g = (const float*)d_in[42];
    const float* fln_b = (const float*)d_in[43];
    const float* lln_g = (const float*)d_in[44];
    const float* lln_b = (const float*)d_in[45];

    float* out = (float*)d_out;
    float* ws = (float*)d_ws;

    // workspace layout (floats)
    const size_t SZ_TOK = (size_t)kM * kH;       // 3,276,800
    float* BIG  = ws;                             // max(acc 12.8M, hid 13.1072M)
    float* XBUF = BIG  + 13107200;
    float* TEMB = XBUF + SZ_TOK;
    float* SEQS = TEMB + SZ_TOK;
    float* QBUF = SEQS + SZ_TOK;
    float* QP   = QBUF + SZ_TOK;
    float* KP   = QP   + SZ_TOK;
    float* VP   = KP   + SZ_TOK;
    float* GATES = VP  + SZ_TOK;                  // 51,200
    const size_t needed = (size_t)(13107200 + 7 * SZ_TOK + 51200) * sizeof(float);
    if (ws_size < needed) return;  // would fail validation loudly

    struct Enc {
        const int* ids; const int* pos; const int* tm; const int* itv;
        const float* emb; const int* a_idx; const float* a_val; int mi;
    };
    const Enc encs[3] = {
        { ids_o, pos_o, tm_o, itv_o, embO, adj_idx,  adj_val,  2 },
        { ids_x, pos_x, tm_x, itv_x, embX, adjs_idx, adjs_val, 0 },
        { ids_y, pos_y, tm_y, itv_y, embY, adjs_idx, adjs_val, 1 },
    };

    const int nEl = kM * kH / 256;   // elementwise grid = 12800

    for (int e = 0; e < 3; ++e) {
        const Enc& E = encs[e];
        // ---- embedding smoothing: acc = spmm(adj, emb); seqs = gather ----
        hipMemsetAsync(BIG, 0, (size_t)kITEMS * kH * sizeof(float), stream);
        spmm_kernel<<<kNNZ / 4, 256, 0, stream>>>(E.a_idx, E.a_val, E.emb, BIG, kNNZ);
        gather_seq_kernel<<<kM, 128, 0, stream>>>(E.ids, E.emb, BIG, SEQS);
        // ---- temb = LN(MLP(interval_emb + time_emb)) ----
        build_x_kernel<<<kM / 2, 256, 0, stream>>>(E.itv, E.tm, interval_table, time_table, XBUF);
        gemm_kernel<<<dim3(4, kM / 128), 256, 0, stream>>>(
            XBUF, mlp_W1 + (size_t)E.mi * kH * 512, mlp_b1 + E.mi * 512, BIG,
            kM, 512, kH, 1, 0);
        gemm_kernel<<<dim3(1, kM / 128), 256, 0, stream>>>(
            BIG, mlp_W2 + (size_t)E.mi * 512 * kH, mlp_b2 + E.mi * kH, TEMB,
            kM, kH, 512, 0, 0);
        ln_kernel<<<kM, 128, 0, stream>>>(TEMB, TEMB, mlp_lng + E.mi * kH, mlp_lnb + E.mi * kH, 1e-5f);
        // ---- +pos, gates, keep-mask ----
        posadd_kernel<<<kM / 2, 256, 0, stream>>>(E.pos, pos_emb + (size_t)e * kT * kH, SEQS, TEMB);
        gates_kernel<<<kM / 4, 256, 0, stream>>>(TEMB, gate_W + e * kH * 2, gate_b + e * 2, GATES);
        mask_kernel<<<nEl, 256, 0, stream>>>(SEQS, E.ids);
        // ---- 2 attention blocks ----
        for (int i = 0; i < 2; ++i) {
            const int wo = e * 2 + i;
            const float* qWp = qW + (size_t)wo * kH * kH;
            const float* kWp = kW + (size_t)wo * kH * kH;
            const float* vWp = vW + (size_t)wo * kH * kH;
            const float* c1Wp = c1W + (size_t)wo * kH * kH;
            const float* c2Wp = c2W + (size_t)wo * kH * kH;
            ln_kernel<<<kM, 128, 0, stream>>>(SEQS, QBUF, aln_g + wo * kH, aln_b + wo * kH, 1e-8f);
            gemm_kernel<<<dim3(1, kM / 128), 256, 0, stream>>>(QBUF, qWp, qb + wo * kH, QP, kM, kH, kH, 0, 0);
            gemm_kernel<<<dim3(1, kM / 128), 256, 0, stream>>>(TEMB, kWp, kb + wo * kH, KP, kM, kH, kH, 0, 0);
            add_kernel<<<nEl, 256, 0, stream>>>(SEQS, TEMB, XBUF);
            gemm_kernel<<<dim3(1, kM / 128), 256, 0, stream>>>(XBUF, vWp, vb + wo * kH, VP, kM, kH, kH, 0, 0);
            attn_kernel<<<kBATCH * 2, 256, 0, stream>>>(QP, KP, VP, GATES, i, XBUF);
            add_kernel<<<nEl, 256, 0, stream>>>(QBUF, XBUF, SEQS);
            ln_kernel<<<kM, 128, 0, stream>>>(SEQS, SEQS, fln_g + wo * kH, fln_b + wo * kH, 1e-8f);
            gemm_kernel<<<dim3(1, kM / 128), 256, 0, stream>>>(SEQS, c1Wp, c1b + wo * kH, XBUF, kM, kH, kH, 1, 0);
            gemm_kernel<<<dim3(1, kM / 128), 256, 0, stream>>>(XBUF, c2Wp, c2b + wo * kH, SEQS, kM, kH, kH, 0, 1);
            mask_kernel<<<nEl, 256, 0, stream>>>(SEQS, E.ids);
        }
        ln_kernel<<<kM, 128, 0, stream>>>(SEQS, out + (size_t)e * kM * kH, lln_g + e * kH, lln_b + e * kH, 1e-8f);
    }
}

// Round 2
// 2707.843 us; speedup vs baseline: 1.8624x; 1.8624x over previous
//
#include <hip/hip_runtime.h>
#include <math.h>

// ---------------------------------------------------------------------------
// TACDSR forward — round 2: spmm row-filtering + bf16 MFMA GEMMs.
// ---------------------------------------------------------------------------

#define kH 128
#define kT 200
#define kBATCH 128
#define kM (kBATCH * kT)         // 25600 tokens
#define kITEMS 100000
#define kNNZ 1600000
#define kNEG_INF (-__builtin_huge_valf())

typedef short s16x8 __attribute__((ext_vector_type(8)));
typedef __bf16 b16x8 __attribute__((ext_vector_type(8)));
typedef float f32x4 __attribute__((ext_vector_type(4)));

static __device__ __forceinline__ short f2bf(float f) {
    unsigned u = __float_as_uint(f);
    unsigned r = (u + 0x7FFFu + ((u >> 16) & 1u)) >> 16;
    return (short)r;
}
static __device__ __forceinline__ f32x4 mfma16(s16x8 a, s16x8 b, f32x4 c) {
    return __builtin_amdgcn_mfma_f32_16x16x32_bf16(
        __builtin_bit_cast(b16x8, a), __builtin_bit_cast(b16x8, b), c, 0, 0, 0);
}

// ---------------- flag rows that will be gathered -------------------------
__global__ void flag_kernel(const int* __restrict__ ids, unsigned char* __restrict__ flags)
{
    flags[ids[blockIdx.x * 256 + threadIdx.x]] = 1;
}

// ---------------- SpMM scatter (filtered): acc[row] += val * emb[col] -----
__global__ __launch_bounds__(256) void spmm_kernel(
    const int* __restrict__ idx, const float* __restrict__ val,
    const float* __restrict__ emb, float* __restrict__ acc,
    const unsigned char* __restrict__ flags, int nnz)
{
    const int j = blockIdx.x * 4 + (threadIdx.x >> 6);
    const int lane = threadIdx.x & 63;
    const int row = idx[j];
    if (!flags[row]) return;
    const int col = idx[nnz + j];
    const float v = val[j];
    atomicAdd(&acc[(size_t)row * kH + lane],      v * emb[(size_t)col * kH + lane]);
    atomicAdd(&acc[(size_t)row * kH + 64 + lane], v * emb[(size_t)col * kH + 64 + lane]);
}

// ------------- seqs = 1.5*emb[s] + 0.5 * acc[s]/max(||acc[s]||,1e-12) -----
__global__ void gather_seq_kernel(
    const int* __restrict__ ids, const float* __restrict__ emb,
    const float* __restrict__ acc, float* __restrict__ seqs)
{
    const int tok = blockIdx.x;
    const int c = threadIdx.x;
    const int s = ids[tok];
    const float a = acc[(size_t)s * kH + c];
    __shared__ float red[128];
    red[c] = a * a;
    __syncthreads();
    for (int st = 64; st > 0; st >>= 1) {
        if (c < st) red[c] += red[c + st];
        __syncthreads();
    }
    const float denom = fmaxf(sqrtf(red[0]), 1e-12f);
    seqs[(size_t)tok * kH + c] = 1.5f * emb[(size_t)s * kH + c] + 0.5f * a / denom;
}

// ------------- x = interval_table[floor(log2(t+1))] + time_table[tt] ------
__global__ void build_x_kernel(
    const int* __restrict__ itv, const int* __restrict__ tt,
    const float* __restrict__ interval_table, const float* __restrict__ time_table,
    float* __restrict__ x)
{
    const int tok = blockIdx.x * 2 + (threadIdx.x >> 7);
    const int c = threadIdx.x & 127;
    const int t = itv[tok];
    int idx = (int)floorf(log2f((float)t + 1.0f));
    idx = idx < 0 ? 0 : (idx > 30 ? 30 : idx);
    x[(size_t)tok * kH + c] = interval_table[idx * kH + c] + time_table[(size_t)tt[tok] * kH + c];
}

// ---------------- weight transpose+convert: [B][K][N] f32 -> [B][N][K] bf16
__global__ void wt_kernel(const float* __restrict__ in, short* __restrict__ out,
                          int kLog, int nLog)
{
    const int i = blockIdx.x * 256 + threadIdx.x;
    const int knLog = kLog + nLog;
    const int b = i >> knLog;
    const int rem = i & ((1 << knLog) - 1);
    const int n = rem >> kLog;
    const int k = rem & ((1 << kLog) - 1);
    out[i] = f2bf(in[((size_t)b << knLog) + ((size_t)k << nLog) + n]);
}

// ---------------- bf16 MFMA GEMM: C = [relu](A@B + bias) [+ C] ------------
// A: MxK f32 row-major (optionally A+A2), BT: NxK bf16 row-major.
// tile 128x128, K staged in 128 chunks, 256 thr = 4 waves x (32 rows x 128 cols)
__global__ __launch_bounds__(256) void gemm_bf16(
    const float* __restrict__ A, const float* __restrict__ A2,
    const short* __restrict__ BT, const float* __restrict__ bias,
    float* __restrict__ C, int M, int N, int K, int relu, int accum)
{
    __shared__ short As[128 * 128];
    __shared__ short Bs[128 * 128];
    const int tid = threadIdx.x;
    const int lane = tid & 63;
    const int w = tid >> 6;
    const int rowBase = blockIdx.y * 128;
    const int colBase = blockIdx.x * 128;
    f32x4 acc[2][8] = {};

    for (int k0 = 0; k0 < K; k0 += 128) {
        // stage A (f32 -> bf16) and BT (bf16 copy), XOR-swizzled rows
#pragma unroll
        for (int p = 0; p < 8; ++p) {
            const int chunk = p * 256 + tid;          // 2048 chunks of 8 elems
            const int r = chunk >> 4;                 // 0..127
            const int kc = chunk & 15;                // 0..15
            const int byteoff = (r * 256 + kc * 16) ^ ((r & 7) << 4);
            // A
            {
                const float* src = &A[(size_t)(rowBase + r) * K + k0 + kc * 8];
                float4 a0 = *reinterpret_cast<const float4*>(src);
                float4 a1 = *reinterpret_cast<const float4*>(src + 4);
                if (A2) {
                    const float* s2 = &A2[(size_t)(rowBase + r) * K + k0 + kc * 8];
                    float4 b0 = *reinterpret_cast<const float4*>(s2);
                    float4 b1 = *reinterpret_cast<const float4*>(s2 + 4);
                    a0.x += b0.x; a0.y += b0.y; a0.z += b0.z; a0.w += b0.w;
                    a1.x += b1.x; a1.y += b1.y; a1.z += b1.z; a1.w += b1.w;
                }
                s16x8 v;
                v[0] = f2bf(a0.x); v[1] = f2bf(a0.y); v[2] = f2bf(a0.z); v[3] = f2bf(a0.w);
                v[4] = f2bf(a1.x); v[5] = f2bf(a1.y); v[6] = f2bf(a1.z); v[7] = f2bf(a1.w);
                *reinterpret_cast<s16x8*>(reinterpret_cast<char*>(As) + byteoff) = v;
            }
            // B (already bf16, [N][K] row-major)
            {
                const s16x8 v = *reinterpret_cast<const s16x8*>(
                    &BT[(size_t)(colBase + r) * K + k0 + kc * 8]);
                *reinterpret_cast<s16x8*>(reinterpret_cast<char*>(Bs) + byteoff) = v;
            }
        }
        __syncthreads();
#pragma unroll
        for (int kk = 0; kk < 4; ++kk) {
            const int kb = (kk * 32 + (lane >> 4) * 8) * 2;   // byte offset of k
            s16x8 af[2];
#pragma unroll
            for (int mi = 0; mi < 2; ++mi) {
                const int r = w * 32 + mi * 16 + (lane & 15);
                af[mi] = *reinterpret_cast<const s16x8*>(
                    reinterpret_cast<const char*>(As) + ((r * 256 + kb) ^ ((r & 7) << 4)));
            }
#pragma unroll
            for (int nj = 0; nj < 8; ++nj) {
                const int r = nj * 16 + (lane & 15);
                const s16x8 bf = *reinterpret_cast<const s16x8*>(
                    reinterpret_cast<const char*>(Bs) + ((r * 256 + kb) ^ ((r & 7) << 4)));
#pragma unroll
                for (int mi = 0; mi < 2; ++mi)
                    acc[mi][nj] = mfma16(af[mi], bf, acc[mi][nj]);
            }
        }
        __syncthreads();
    }
    // epilogue: C/D layout col=lane&15, row=(lane>>4)*4+reg
#pragma unroll
    for (int mi = 0; mi < 2; ++mi) {
        const int rowb = rowBase + w * 32 + mi * 16 + (lane >> 4) * 4;
#pragma unroll
        for (int nj = 0; nj < 8; ++nj) {
            const int col = colBase + nj * 16 + (lane & 15);
            const float bc = bias[col];
            f32x4 v = acc[mi][nj];
#pragma unroll
            for (int r = 0; r < 4; ++r) {
                float x = v[r] + bc;
                if (relu) x = fmaxf(x, 0.f);
                const size_t off = (size_t)(rowb + r) * N + col;
                if (accum) x += C[off];
                C[off] = x;
            }
        }
    }
}

// ---------------- LayerNorm over H=128 (in may equal out) -----------------
__global__ void ln_kernel(
    const float* __restrict__ in, float* __restrict__ out,
    const float* __restrict__ g, const float* __restrict__ bb, float eps)
{
    const int tok = blockIdx.x;
    const int c = threadIdx.x;
    const float x = in[(size_t)tok * kH + c];
    __shared__ float r1[128], r2[128];
    r1[c] = x; r2[c] = x * x;
    __syncthreads();
    for (int st = 64; st > 0; st >>= 1) {
        if (c < st) { r1[c] += r1[c + st]; r2[c] += r2[c + st]; }
        __syncthreads();
    }
    const float mean = r1[0] * (1.f / 128.f);
    float var = r2[0] * (1.f / 128.f) - mean * mean;
    var = fmaxf(var, 0.f);
    out[(size_t)tok * kH + c] = (x - mean) * rsqrtf(var + eps) * g[c] + bb[c];
}

// ---------------- seqs += pos_emb[pos]; temb += pos_emb[pos] --------------
__global__ void posadd_kernel(
    const int* __restrict__ pos, const float* __restrict__ pemb,
    float* __restrict__ seqs, float* __restrict__ temb)
{
    const int tok = blockIdx.x * 2 + (threadIdx.x >> 7);
    const int c = threadIdx.x & 127;
    const float p = pemb[(size_t)pos[tok] * kH + c];
    seqs[(size_t)tok * kH + c] += p;
    temb[(size_t)tok * kH + c] += p;
}

// ---------------- gates = sigmoid(temb @ gate_W + gate_b) -----------------
__global__ void gates_kernel(
    const float* __restrict__ temb, const float* __restrict__ gW,
    const float* __restrict__ gb, float* __restrict__ gates)
{
    const int wv = threadIdx.x >> 6;
    const int lane = threadIdx.x & 63;
    const int tok = blockIdx.x * 4 + wv;
    const float t0 = temb[(size_t)tok * kH + lane];
    const float t1 = temb[(size_t)tok * kH + 64 + lane];
#pragma unroll
    for (int i = 0; i < 2; ++i) {
        float p = t0 * gW[lane * 2 + i] + t1 * gW[(64 + lane) * 2 + i];
#pragma unroll
        for (int off = 1; off < 64; off <<= 1) p += __shfl_xor(p, off);
        if (lane == 0) gates[tok * 2 + i] = 1.f / (1.f + expf(-(p + gb[i])));
    }
}

// ---------------- seqs *= (ids != ITEMNUM-1) ------------------------------
__global__ void mask_kernel(float* __restrict__ seqs, const int* __restrict__ ids)
{
    const int i = blockIdx.x * 256 + threadIdx.x;
    if (ids[i >> 7] == kITEMS - 1) seqs[i] = 0.f;
}

// ---------------- fused gated causal attention per (b,h) ------------------
// out = resid + softmax(causal(q.k*scale*gq*gk)) @ v
__global__ __launch_bounds__(256) void attn_kernel(
    const float* __restrict__ qp, const float* __restrict__ kp,
    const float* __restrict__ vp, const float* __restrict__ gates,
    const int gi, const float* __restrict__ resid, float* __restrict__ outp)
{
    __shared__ float klds[kT * 65];
    __shared__ float vlds[kT * 65];
    __shared__ float glds[kT];
    __shared__ __align__(16) float qlds[4][2][64];
    __shared__ float plds[4][2][kT];
    const int b = (int)blockIdx.x >> 1;
    const int h = (int)blockIdx.x & 1;
    const int hoff = h * 64;
    const int tid = threadIdx.x;
    const size_t base = (size_t)b * kT * kH;
    for (int i = tid; i < kT * 64; i += 256) {
        const int r = i >> 6, d = i & 63;
        klds[r * 65 + d] = kp[base + (size_t)r * kH + hoff + d];
        vlds[r * 65 + d] = vp[base + (size_t)r * kH + hoff + d];
    }
    if (tid < kT) glds[tid] = gates[(b * kT + tid) * 2 + gi];
    __syncthreads();
    const int wv = tid >> 6;
    const int lane = tid & 63;
    const float scale = 0.125f;

    for (int qr0 = wv * 2; qr0 < kT; qr0 += 8) {
        const int qr1 = qr0 + 1;
        qlds[wv][0][lane] = qp[base + (size_t)qr0 * kH + hoff + lane];
        qlds[wv][1][lane] = qp[base + (size_t)qr1 * kH + hoff + lane];
        const float gq0 = glds[qr0];
        const float gq1 = glds[qr1];
        float sc0[4], sc1[4];
#pragma unroll
        for (int kc = 0; kc < 4; ++kc) {
            const int kidx = kc * 64 + lane;
            float v0 = kNEG_INF, v1 = kNEG_INF;
            if (kidx < kT) {
                const float* kr = &klds[kidx * 65];
                float s0 = 0.f, s1 = 0.f;
#pragma unroll
                for (int d = 0; d < 64; d += 4) {
                    const float4 q0 = *reinterpret_cast<const float4*>(&qlds[wv][0][d]);
                    const float4 q1 = *reinterpret_cast<const float4*>(&qlds[wv][1][d]);
                    const float k0 = kr[d], k1 = kr[d + 1], k2 = kr[d + 2], k3 = kr[d + 3];
                    s0 += q0.x * k0 + q0.y * k1 + q0.z * k2 + q0.w * k3;
                    s1 += q1.x * k0 + q1.y * k1 + q1.z * k2 + q1.w * k3;
                }
                const float gk = glds[kidx];
                if (kidx <= qr0) v0 = s0 * scale * gq0 * gk;
                if (kidx <= qr1) v1 = s1 * scale * gq1 * gk;
            }
            sc0[kc] = v0; sc1[kc] = v1;
        }
        float m0 = fmaxf(fmaxf(sc0[0], sc0[1]), fmaxf(sc0[2], sc0[3]));
        float m1 = fmaxf(fmaxf(sc1[0], sc1[1]), fmaxf(sc1[2], sc1[3]));
#pragma unroll
        for (int off = 1; off < 64; off <<= 1) {
            m0 = fmaxf(m0, __shfl_xor(m0, off));
            m1 = fmaxf(m1, __shfl_xor(m1, off));
        }
        float ps0 = 0.f, ps1 = 0.f;
#pragma unroll
        for (int kc = 0; kc < 4; ++kc) {
            const int kidx = kc * 64 + lane;
            const float p0 = expf(sc0[kc] - m0);
            const float p1 = expf(sc1[kc] - m1);
            ps0 += p0; ps1 += p1;
            if (kidx < kT) { plds[wv][0][kidx] = p0; plds[wv][1][kidx] = p1; }
        }
#pragma unroll
        for (int off = 1; off < 64; off <<= 1) {
            ps0 += __shfl_xor(ps0, off);
            ps1 += __shfl_xor(ps1, off);
        }
        float o0 = 0.f, o1 = 0.f;
        for (int k = 0; k <= qr1; ++k) {
            const float vv = vlds[k * 65 + lane];
            o0 += plds[wv][0][k] * vv;
            o1 += plds[wv][1][k] * vv;
        }
        const size_t o0off = base + (size_t)qr0 * kH + hoff + lane;
        const size_t o1off = base + (size_t)qr1 * kH + hoff + lane;
        outp[o0off] = resid[o0off] + o0 / ps0;
        outp[o1off] = resid[o1off] + o1 / ps1;
    }
}

// ---------------------------------------------------------------------------
extern "C" void kernel_launch(void* const* d_in, const int* in_sizes, int n_in,
                              void* d_out, int out_size, void* d_ws, size_t ws_size,
                              hipStream_t stream)
{
    const int* ids_o = (const int*)d_in[0];
    const int* ids_x = (const int*)d_in[1];
    const int* ids_y = (const int*)d_in[2];
    const int* pos_o = (const int*)d_in[3];
    const int* pos_x = (const int*)d_in[4];
    const int* pos_y = (const int*)d_in[5];
    const int* tm_o  = (const int*)d_in[6];
    const int* tm_x  = (const int*)d_in[7];
    const int* tm_y  = (const int*)d_in[8];
    const int* itv_x = (const int*)d_in[9];
    const int* itv_y = (const int*)d_in[10];
    const int* itv_o = (const int*)d_in[11];
    const float* embX = (const float*)d_in[12];
    const float* embY = (const float*)d_in[13];
    const float* embO = (const float*)d_in[14];
    const float* time_table = (const float*)d_in[15];
    const float* interval_table = (const float*)d_in[16];
    const int* adj_idx  = (const int*)d_in[17];
    const float* adj_val = (const float*)d_in[18];
    const int* adjs_idx  = (const int*)d_in[19];
    const float* adjs_val = (const float*)d_in[20];
    const float* mlp_W1 = (const float*)d_in[21];
    const float* mlp_b1 = (const float*)d_in[22];
    const float* mlp_W2 = (const float*)d_in[23];
    const float* mlp_b2 = (const float*)d_in[24];
    const float* mlp_lng = (const float*)d_in[25];
    const float* mlp_lnb = (const float*)d_in[26];
    const float* pos_emb = (const float*)d_in[27];
    const float* gate_W = (const float*)d_in[28];
    const float* gate_b = (const float*)d_in[29];
    const float* aln_g = (const float*)d_in[30];
    const float* aln_b = (const float*)d_in[31];
    const float* qW = (const float*)d_in[32];
    const float* kW = (const float*)d_in[33];
    const float* vW = (const float*)d_in[34];
    const float* c1W = (const float*)d_in[35];
    const float* c2W = (const float*)d_in[36];
    const float* qb = (const float*)d_in[37];
    const float* kb = (const float*)d_in[38];
    const float* vb = (const float*)d_in[39];
    const float* c1b = (const float*)d_in[40];
    const float* c2b = (const float*)d_in[41];
    const float* fln_g = (const float*)d_in[42];
    const float* fln_b = (const float*)d_in[43];
    const float* lln_g = (const float*)d_in[44];
    const float* lln_b = (const float*)d_in[45];

    float* out = (float*)d_out;
    float* ws = (float*)d_ws;

    // workspace layout (floats)
    const size_t SZ_TOK = (size_t)kM * kH;       // 3,276,800
    float* BIG  = ws;                             // acc 12.8M / hidden 13.1072M
    float* XBUF = BIG  + 13107200;                // also serves as QP + FFN hidden
    float* TEMB = XBUF + SZ_TOK;
    float* SEQS = TEMB + SZ_TOK;
    float* QBUF = SEQS + SZ_TOK;
    float* KP   = QBUF + SZ_TOK;
    float* VP   = KP   + SZ_TOK;
    float* GATES = VP  + SZ_TOK;                  // 51,200 floats (flags overlay)
    unsigned char* FLAGS = (unsigned char*)GATES; // 100,000 B <= 204,800 B
    short* WT = (short*)(GATES + 51200);          // 884,736 bf16
    short* qWT = WT;                              // 6 x 128x128
    short* kWT = qWT + 6 * 16384;
    short* vWT = kWT + 6 * 16384;
    short* c1WT = vWT + 6 * 16384;
    short* c2WT = c1WT + 6 * 16384;
    short* w1T = c2WT + 6 * 16384;                // 3 x 512x128
    short* w2T = w1T + 3 * 65536;                 // 3 x 128x512
    const size_t needed = ((size_t)(13107200) + 6 * SZ_TOK + 51200) * 4
                          + 884736 * 2;
    if (ws_size < needed) return;

    // ---- one-time-per-call weight transpose/convert ----
    wt_kernel<<<6 * 16384 / 256, 256, 0, stream>>>(qW, qWT, 7, 7);
    wt_kernel<<<6 * 16384 / 256, 256, 0, stream>>>(kW, kWT, 7, 7);
    wt_kernel<<<6 * 16384 / 256, 256, 0, stream>>>(vW, vWT, 7, 7);
    wt_kernel<<<6 * 16384 / 256, 256, 0, stream>>>(c1W, c1WT, 7, 7);
    wt_kernel<<<6 * 16384 / 256, 256, 0, stream>>>(c2W, c2WT, 7, 7);
    wt_kernel<<<3 * 65536 / 256, 256, 0, stream>>>(mlp_W1, w1T, 7, 9);  // K=128,N=512
    wt_kernel<<<3 * 65536 / 256, 256, 0, stream>>>(mlp_W2, w2T, 9, 7);  // K=512,N=128

    struct Enc {
        const int* ids; const int* pos; const int* tm; const int* itv;
        const float* emb; const int* a_idx; const float* a_val; int mi;
    };
    const Enc encs[3] = {
        { ids_o, pos_o, tm_o, itv_o, embO, adj_idx,  adj_val,  2 },
        { ids_x, pos_x, tm_x, itv_x, embX, adjs_idx, adjs_val, 0 },
        { ids_y, pos_y, tm_y, itv_y, embY, adjs_idx, adjs_val, 1 },
    };

    const int nEl = kM * kH / 256;   // elementwise grid = 12800

    for (int e = 0; e < 3; ++e) {
        const Enc& E = encs[e];
        // ---- embedding smoothing (row-filtered spmm) ----
        hipMemsetAsync(BIG, 0, (size_t)kITEMS * kH * sizeof(float), stream);
        hipMemsetAsync(FLAGS, 0, kITEMS, stream);
        flag_kernel<<<kM / 256, 256, 0, stream>>>(E.ids, FLAGS);
        spmm_kernel<<<kNNZ / 4, 256, 0, stream>>>(E.a_idx, E.a_val, E.emb, BIG, FLAGS, kNNZ);
        gather_seq_kernel<<<kM, 128, 0, stream>>>(E.ids, E.emb, BIG, SEQS);
        // ---- temb = LN(MLP(interval_emb + time_emb)) ----
        build_x_kernel<<<kM / 2, 256, 0, stream>>>(E.itv, E.tm, interval_table, time_table, XBUF);
        gemm_bf16<<<dim3(4, kM / 128), 256, 0, stream>>>(
            XBUF, nullptr, w1T + (size_t)E.mi * 65536, mlp_b1 + E.mi * 512, BIG,
            kM, 512, kH, 1, 0);
        gemm_bf16<<<dim3(1, kM / 128), 256, 0, stream>>>(
            BIG, nullptr, w2T + (size_t)E.mi * 65536, mlp_b2 + E.mi * kH, TEMB,
            kM, kH, 512, 0, 0);
        ln_kernel<<<kM, 128, 0, stream>>>(TEMB, TEMB, mlp_lng + E.mi * kH, mlp_lnb + E.mi * kH, 1e-5f);
        // ---- +pos, gates, keep-mask ----
        posadd_kernel<<<kM / 2, 256, 0, stream>>>(E.pos, pos_emb + (size_t)e * kT * kH, SEQS, TEMB);
        gates_kernel<<<kM / 4, 256, 0, stream>>>(TEMB, gate_W + e * kH * 2, gate_b + e * 2, GATES);
        mask_kernel<<<nEl, 256, 0, stream>>>(SEQS, E.ids);
        // ---- 2 attention blocks ----
        for (int i = 0; i < 2; ++i) {
            const int wo = e * 2 + i;
            ln_kernel<<<kM, 128, 0, stream>>>(SEQS, QBUF, aln_g + wo * kH, aln_b + wo * kH, 1e-8f);
            gemm_bf16<<<dim3(1, kM / 128), 256, 0, stream>>>(
                QBUF, nullptr, qWT + (size_t)wo * 16384, qb + wo * kH, XBUF, kM, kH, kH, 0, 0);
            gemm_bf16<<<dim3(1, kM / 128), 256, 0, stream>>>(
                TEMB, nullptr, kWT + (size_t)wo * 16384, kb + wo * kH, KP, kM, kH, kH, 0, 0);
            gemm_bf16<<<dim3(1, kM / 128), 256, 0, stream>>>(
                SEQS, TEMB, vWT + (size_t)wo * 16384, vb + wo * kH, VP, kM, kH, kH, 0, 0);
            attn_kernel<<<kBATCH * 2, 256, 0, stream>>>(XBUF, KP, VP, GATES, i, QBUF, SEQS);
            ln_kernel<<<kM, 128, 0, stream>>>(SEQS, SEQS, fln_g + wo * kH, fln_b + wo * kH, 1e-8f);
            gemm_bf16<<<dim3(1, kM / 128), 256, 0, stream>>>(
                SEQS, nullptr, c1WT + (size_t)wo * 16384, c1b + wo * kH, XBUF, kM, kH, kH, 1, 0);
            gemm_bf16<<<dim3(1, kM / 128), 256, 0, stream>>>(
                XBUF, nullptr, c2WT + (size_t)wo * 16384, c2b + wo * kH, SEQS, kM, kH, kH, 0, 1);
            mask_kernel<<<nEl, 256, 0, stream>>>(SEQS, E.ids);
        }
        ln_kernel<<<kM, 128, 0, stream>>>(SEQS, out + (size_t)e * kM * kH, lln_g + e * kH, lln_b + e * kH, 1e-8f);
    }
}

// Round 3
// 1877.922 us; speedup vs baseline: 2.6855x; 1.4419x over previous
//
#include <hip/hip_runtime.h>
#include <math.h>

// ---------------------------------------------------------------------------
// TACDSR forward — round 3: CSR-based spmm (no atomics RMW), attention
// occupancy fix (2 q-chunks, V from L2), QKV merged dispatch, fusions.
// ---------------------------------------------------------------------------

#define kH 128
#define kT 200
#define kBATCH 128
#define kM (kBATCH * kT)         // 25600 tokens
#define kITEMS 100000
#define kROWS 100000
#define kNNZ 1600000
#define kNEG_INF (-__builtin_huge_valf())

typedef short s16x8 __attribute__((ext_vector_type(8)));
typedef __bf16 b16x8 __attribute__((ext_vector_type(8)));
typedef float f32x4 __attribute__((ext_vector_type(4)));

static __device__ __forceinline__ short f2bf(float f) {
    unsigned u = __float_as_uint(f);
    unsigned r = (u + 0x7FFFu + ((u >> 16) & 1u)) >> 16;
    return (short)r;
}
static __device__ __forceinline__ f32x4 mfma16(s16x8 a, s16x8 b, f32x4 c) {
    return __builtin_amdgcn_mfma_f32_16x16x32_bf16(
        __builtin_bit_cast(b16x8, a), __builtin_bit_cast(b16x8, b), c, 0, 0, 0);
}

// ======================= CSR build + smooth ================================
__global__ void flag_kernel(const int* __restrict__ ids, unsigned char* __restrict__ flags)
{
    flags[ids[blockIdx.x * 256 + threadIdx.x]] = 1;
}

__global__ void count_kernel(const int* __restrict__ idx,
                             const unsigned char* __restrict__ flags,
                             int* __restrict__ counts)
{
    const int j = blockIdx.x * 256 + threadIdx.x;
    const int row = idx[j];
    if (flags[row]) atomicAdd(&counts[row], 1);
}

// exclusive scan of counts[100000] -> offsets, cursor (3 passes, chunk=1024)
__global__ __launch_bounds__(256) void scan_pass1(const int* __restrict__ counts,
                                                  int* __restrict__ partial)
{
    const int t = threadIdx.x;
    const int base = blockIdx.x * 1024;
    int s = 0;
#pragma unroll
    for (int i = 0; i < 4; ++i) {
        const int g = base + t + i * 256;
        if (g < kROWS) s += counts[g];
    }
    __shared__ int sd[256];
    sd[t] = s; __syncthreads();
    for (int off = 128; off > 0; off >>= 1) {
        if (t < off) sd[t] += sd[t + off];
        __syncthreads();
    }
    if (t == 0) partial[blockIdx.x] = sd[0];
}

__global__ void scan_pass2(int* __restrict__ partial, int nblk)
{
    const int t = threadIdx.x;          // 128 threads
    __shared__ int sd[128];
    const int v = (t < nblk) ? partial[t] : 0;
    sd[t] = v; __syncthreads();
    for (int off = 1; off < 128; off <<= 1) {
        const int a = (t >= off) ? sd[t - off] : 0;
        __syncthreads();
        sd[t] += a;
        __syncthreads();
    }
    if (t < nblk) partial[t] = sd[t] - v;   // exclusive
}

__global__ __launch_bounds__(256) void scan_pass3(const int* __restrict__ counts,
                                                  const int* __restrict__ partial,
                                                  int* __restrict__ offsets,
                                                  int* __restrict__ cursor)
{
    const int t = threadIdx.x;
    const int base = blockIdx.x * 1024;
    int c[4]; int s = 0;
#pragma unroll
    for (int i = 0; i < 4; ++i) {
        const int g = base + t * 4 + i;
        c[i] = (g < kROWS) ? counts[g] : 0;
        s += c[i];
    }
    __shared__ int sd[256];
    sd[t] = s; __syncthreads();
    for (int off = 1; off < 256; off <<= 1) {
        const int a = (t >= off) ? sd[t - off] : 0;
        __syncthreads();
        sd[t] += a;
        __syncthreads();
    }
    int run = partial[blockIdx.x] + sd[t] - s;
#pragma unroll
    for (int i = 0; i < 4; ++i) {
        const int g = base + t * 4 + i;
        if (g < kROWS) {
            offsets[g] = run;
            cursor[g] = run;
            run += c[i];
            if (g == kROWS - 1) offsets[kROWS] = run;
        }
    }
}

__global__ void scatter_kernel(const int* __restrict__ idx, const float* __restrict__ val,
                               const unsigned char* __restrict__ flags,
                               int* __restrict__ cursor, int2* __restrict__ edges, int nnz)
{
    const int j = blockIdx.x * 256 + threadIdx.x;
    const int row = idx[j];
    if (!flags[row]) return;
    const int pos = atomicAdd(&cursor[row], 1);
    edges[pos] = make_int2(idx[nnz + j], __float_as_int(val[j]));
}

// per flagged row: acc = sum val*emb[col]; sm = 1.5*emb[row] + 0.5*l2n(acc)
__global__ __launch_bounds__(256) void smooth_kernel(
    const int2* __restrict__ edges, const int* __restrict__ offsets,
    const unsigned char* __restrict__ flags, const float* __restrict__ emb,
    float* __restrict__ sm)
{
    const int row = blockIdx.x * 4 + (threadIdx.x >> 6);
    const int lane = threadIdx.x & 63;
    if (row >= kROWS || !flags[row]) return;
    const int lo = offsets[row], hi = offsets[row + 1];
    float a0 = 0.f, a1 = 0.f;
    for (int e = lo; e < hi; ++e) {
        const int2 ed = edges[e];
        const float v = __int_as_float(ed.y);
        const float* er = &emb[(size_t)ed.x * kH];
        a0 = fmaf(v, er[lane], a0);
        a1 = fmaf(v, er[64 + lane], a1);
    }
    float s = a0 * a0 + a1 * a1;
#pragma unroll
    for (int off = 1; off < 64; off <<= 1) s += __shfl_xor(s, off);
    const float inv = 0.5f / fmaxf(sqrtf(s), 1e-12f);
    const float* mr = &emb[(size_t)row * kH];
    sm[(size_t)row * kH + lane]      = 1.5f * mr[lane]      + a0 * inv;
    sm[(size_t)row * kH + 64 + lane] = 1.5f * mr[64 + lane] + a1 * inv;
}

// seqs[tok] = SMOOTH[ids[tok]]
__global__ void gather_kernel(const int* __restrict__ ids, const float* __restrict__ sm,
                              float* __restrict__ seqs)
{
    const int tok = blockIdx.x * 2 + (threadIdx.x >> 7);
    const int c = threadIdx.x & 127;
    seqs[(size_t)tok * kH + c] = sm[(size_t)ids[tok] * kH + c];
}

// temb += pos_emb[pos]; seqs = keep ? seqs + pos_emb[pos] : 0
__global__ void pos_mask_kernel(const int* __restrict__ ids, const int* __restrict__ pos,
                                const float* __restrict__ pemb,
                                float* __restrict__ seqs, float* __restrict__ temb)
{
    const int tok = blockIdx.x * 2 + (threadIdx.x >> 7);
    const int c = threadIdx.x & 127;
    const float p = pemb[(size_t)pos[tok] * kH + c];
    temb[(size_t)tok * kH + c] += p;
    const size_t off = (size_t)tok * kH + c;
    seqs[off] = (ids[tok] == kITEMS - 1) ? 0.f : seqs[off] + p;
}

// ======================= misc small kernels ================================
__global__ void build_x_kernel(
    const int* __restrict__ itv, const int* __restrict__ tt,
    const float* __restrict__ interval_table, const float* __restrict__ time_table,
    float* __restrict__ x)
{
    const int tok = blockIdx.x * 2 + (threadIdx.x >> 7);
    const int c = threadIdx.x & 127;
    const int t = itv[tok];
    int idx = (int)floorf(log2f((float)t + 1.0f));
    idx = idx < 0 ? 0 : (idx > 30 ? 30 : idx);
    x[(size_t)tok * kH + c] = interval_table[idx * kH + c] + time_table[(size_t)tt[tok] * kH + c];
}

__global__ void wt_kernel(const float* __restrict__ in, short* __restrict__ out,
                          int kLog, int nLog)
{
    const int i = blockIdx.x * 256 + threadIdx.x;
    const int knLog = kLog + nLog;
    const int b = i >> knLog;
    const int rem = i & ((1 << knLog) - 1);
    const int n = rem >> kLog;
    const int k = rem & ((1 << kLog) - 1);
    out[i] = f2bf(in[((size_t)b << knLog) + ((size_t)k << nLog) + n]);
}

// wave-per-token LayerNorm (in may equal out)
__global__ __launch_bounds__(256) void ln_wave(
    const float* __restrict__ in, float* __restrict__ out,
    const float* __restrict__ g, const float* __restrict__ bb, float eps)
{
    const int tok = blockIdx.x * 4 + (threadIdx.x >> 6);
    const int lane = threadIdx.x & 63;
    const float x0 = in[(size_t)tok * kH + lane];
    const float x1 = in[(size_t)tok * kH + 64 + lane];
    float s1 = x0 + x1, s2 = x0 * x0 + x1 * x1;
#pragma unroll
    for (int off = 1; off < 64; off <<= 1) {
        s1 += __shfl_xor(s1, off);
        s2 += __shfl_xor(s2, off);
    }
    const float mean = s1 * (1.f / 128.f);
    float var = s2 * (1.f / 128.f) - mean * mean;
    var = fmaxf(var, 0.f);
    const float r = rsqrtf(var + eps);
    out[(size_t)tok * kH + lane]      = (x0 - mean) * r * g[lane]      + bb[lane];
    out[(size_t)tok * kH + 64 + lane] = (x1 - mean) * r * g[64 + lane] + bb[64 + lane];
}

__global__ void gates_kernel(
    const float* __restrict__ temb, const float* __restrict__ gW,
    const float* __restrict__ gb, float* __restrict__ gates)
{
    const int wv = threadIdx.x >> 6;
    const int lane = threadIdx.x & 63;
    const int tok = blockIdx.x * 4 + wv;
    const float t0 = temb[(size_t)tok * kH + lane];
    const float t1 = temb[(size_t)tok * kH + 64 + lane];
#pragma unroll
    for (int i = 0; i < 2; ++i) {
        float p = t0 * gW[lane * 2 + i] + t1 * gW[(64 + lane) * 2 + i];
#pragma unroll
        for (int off = 1; off < 64; off <<= 1) p += __shfl_xor(p, off);
        if (lane == 0) gates[tok * 2 + i] = 1.f / (1.f + expf(-(p + gb[i])));
    }
}

// ======================= bf16 MFMA GEMM ====================================
// A: MxK f32 row-major (+optional A2), BT: NxK bf16. 128x128 tile, 4 waves.
static __device__ __forceinline__ void gemm_body(
    const float* __restrict__ A, const float* __restrict__ A2,
    const short* __restrict__ BT, const float* __restrict__ bias,
    float* __restrict__ C, int M, int N, int K, int relu, int accum,
    const int* __restrict__ mask_ids)
{
    __shared__ short As[128 * 128];
    __shared__ short Bs[128 * 128];
    const int tid = threadIdx.x;
    const int lane = tid & 63;
    const int w = tid >> 6;
    const int rowBase = blockIdx.y * 128;
    const int colBase = blockIdx.x * 128;
    f32x4 acc[2][8] = {};

    for (int k0 = 0; k0 < K; k0 += 128) {
#pragma unroll
        for (int p = 0; p < 8; ++p) {
            const int chunk = p * 256 + tid;
            const int r = chunk >> 4;
            const int kc = chunk & 15;
            const int byteoff = (r * 256 + kc * 16) ^ ((r & 7) << 4);
            {
                const float* src = &A[(size_t)(rowBase + r) * K + k0 + kc * 8];
                float4 a0 = *reinterpret_cast<const float4*>(src);
                float4 a1 = *reinterpret_cast<const float4*>(src + 4);
                if (A2) {
                    const float* s2 = &A2[(size_t)(rowBase + r) * K + k0 + kc * 8];
                    float4 b0 = *reinterpret_cast<const float4*>(s2);
                    float4 b1 = *reinterpret_cast<const float4*>(s2 + 4);
                    a0.x += b0.x; a0.y += b0.y; a0.z += b0.z; a0.w += b0.w;
                    a1.x += b1.x; a1.y += b1.y; a1.z += b1.z; a1.w += b1.w;
                }
                s16x8 v;
                v[0] = f2bf(a0.x); v[1] = f2bf(a0.y); v[2] = f2bf(a0.z); v[3] = f2bf(a0.w);
                v[4] = f2bf(a1.x); v[5] = f2bf(a1.y); v[6] = f2bf(a1.z); v[7] = f2bf(a1.w);
                *reinterpret_cast<s16x8*>(reinterpret_cast<char*>(As) + byteoff) = v;
            }
            {
                const s16x8 v = *reinterpret_cast<const s16x8*>(
                    &BT[(size_t)(colBase + r) * K + k0 + kc * 8]);
                *reinterpret_cast<s16x8*>(reinterpret_cast<char*>(Bs) + byteoff) = v;
            }
        }
        __syncthreads();
#pragma unroll
        for (int kk = 0; kk < 4; ++kk) {
            const int kb = (kk * 32 + (lane >> 4) * 8) * 2;
            s16x8 af[2];
#pragma unroll
            for (int mi = 0; mi < 2; ++mi) {
                const int r = w * 32 + mi * 16 + (lane & 15);
                af[mi] = *reinterpret_cast<const s16x8*>(
                    reinterpret_cast<const char*>(As) + ((r * 256 + kb) ^ ((r & 7) << 4)));
            }
#pragma unroll
            for (int nj = 0; nj < 8; ++nj) {
                const int r = nj * 16 + (lane & 15);
                const s16x8 bf = *reinterpret_cast<const s16x8*>(
                    reinterpret_cast<const char*>(Bs) + ((r * 256 + kb) ^ ((r & 7) << 4)));
#pragma unroll
                for (int mi = 0; mi < 2; ++mi)
                    acc[mi][nj] = mfma16(af[mi], bf, acc[mi][nj]);
            }
        }
        __syncthreads();
    }
#pragma unroll
    for (int mi = 0; mi < 2; ++mi) {
        const int rowb = rowBase + w * 32 + mi * 16 + (lane >> 4) * 4;
#pragma unroll
        for (int nj = 0; nj < 8; ++nj) {
            const int col = colBase + nj * 16 + (lane & 15);
            const float bc = bias[col];
            f32x4 v = acc[mi][nj];
#pragma unroll
            for (int r = 0; r < 4; ++r) {
                const int row = rowb + r;
                float x = v[r] + bc;
                if (relu) x = fmaxf(x, 0.f);
                const size_t off = (size_t)row * N + col;
                if (accum) x += C[off];
                if (mask_ids && mask_ids[row] == kITEMS - 1) x = 0.f;
                C[off] = x;
            }
        }
    }
}

__global__ __launch_bounds__(256) void gemm_bf16(
    const float* __restrict__ A, const float* __restrict__ A2,
    const short* __restrict__ BT, const float* __restrict__ bias,
    float* __restrict__ C, int M, int N, int K, int relu, int accum,
    const int* __restrict__ mask_ids)
{
    gemm_body(A, A2, BT, bias, C, M, N, K, relu, accum, mask_ids);
}

// z=0: Q = QBUF @ qW; z=1: K = TEMB @ kW; z=2: V = (SEQS+TEMB) @ vW
__global__ __launch_bounds__(256) void gemm_qkv(
    const float* __restrict__ Aq, const float* __restrict__ Ak,
    const float* __restrict__ Av, const float* __restrict__ Av2,
    const short* __restrict__ WT, int wo,
    const float* __restrict__ bq, const float* __restrict__ bk, const float* __restrict__ bv,
    float* __restrict__ Cq, float* __restrict__ Ck, float* __restrict__ Cv)
{
    const int z = blockIdx.z;
    const float* A  = (z == 0) ? Aq : (z == 1) ? Ak : Av;
    const float* A2 = (z == 2) ? Av2 : nullptr;
    const short* B  = WT + (size_t)z * 6 * 16384 + (size_t)wo * 16384;
    const float* bias = (z == 0) ? bq : (z == 1) ? bk : bv;
    float* C = (z == 0) ? Cq : (z == 1) ? Ck : Cv;
    gemm_body(A, A2, B, bias, C, kM, kH, kH, 0, 0, nullptr);
}

// ======================= fused gated causal attention ======================
// grid: (b, h, qchunk) = 128*2*2 = 512 blocks; K staged in LDS, V from L2.
__global__ __launch_bounds__(256) void attn_kernel(
    const float* __restrict__ qp, const float* __restrict__ kp,
    const float* __restrict__ vp, const float* __restrict__ gates,
    const int gi, const float* __restrict__ resid, float* __restrict__ outp)
{
    __shared__ float klds[kT * 65];
    __shared__ float glds[kT];
    __shared__ __align__(16) float qlds[4][2][64];
    __shared__ float plds[4][2][kT];
    const int bid = (int)blockIdx.x;
    const int b = bid >> 2;
    const int h = (bid >> 1) & 1;
    const int chunk = bid & 1;
    const int qstart = chunk * 100;
    const int qend = qstart + 100;
    const int hoff = h * 64;
    const int tid = threadIdx.x;
    const size_t base = (size_t)b * kT * kH;
    for (int i = tid; i < qend * 64; i += 256) {
        const int r = i >> 6, d = i & 63;
        klds[r * 65 + d] = kp[base + (size_t)r * kH + hoff + d];
    }
    for (int i = tid; i < qend; i += 256) glds[i] = gates[(b * kT + i) * 2 + gi];
    __syncthreads();
    const int wv = tid >> 6;
    const int lane = tid & 63;
    const float scale = 0.125f;

    for (int qr0 = qstart + wv * 2; qr0 < qend; qr0 += 8) {
        const int qr1 = qr0 + 1;
        qlds[wv][0][lane] = qp[base + (size_t)qr0 * kH + hoff + lane];
        qlds[wv][1][lane] = qp[base + (size_t)qr1 * kH + hoff + lane];
        const float gq0 = glds[qr0];
        const float gq1 = glds[qr1];
        const int kcMax = qr1 >> 6;           // causal clip
        float sc0[4], sc1[4];
#pragma unroll
        for (int kc = 0; kc < 4; ++kc) { sc0[kc] = kNEG_INF; sc1[kc] = kNEG_INF; }
        for (int kc = 0; kc <= kcMax; ++kc) {
            const int kidx = kc * 64 + lane;
            float v0 = kNEG_INF, v1 = kNEG_INF;
            if (kidx < kT) {
                const float* kr = &klds[kidx * 65];
                float s0 = 0.f, s1 = 0.f;
#pragma unroll
                for (int d = 0; d < 64; d += 4) {
                    const float4 q0 = *reinterpret_cast<const float4*>(&qlds[wv][0][d]);
                    const float4 q1 = *reinterpret_cast<const float4*>(&qlds[wv][1][d]);
                    const float k0 = kr[d], k1 = kr[d + 1], k2 = kr[d + 2], k3 = kr[d + 3];
                    s0 += q0.x * k0 + q0.y * k1 + q0.z * k2 + q0.w * k3;
                    s1 += q1.x * k0 + q1.y * k1 + q1.z * k2 + q1.w * k3;
                }
                const float gk = glds[kidx];
                if (kidx <= qr0) v0 = s0 * scale * gq0 * gk;
                if (kidx <= qr1) v1 = s1 * scale * gq1 * gk;
            }
            sc0[kc] = v0; sc1[kc] = v1;
        }
        float m0 = fmaxf(fmaxf(sc0[0], sc0[1]), fmaxf(sc0[2], sc0[3]));
        float m1 = fmaxf(fmaxf(sc1[0], sc1[1]), fmaxf(sc1[2], sc1[3]));
#pragma unroll
        for (int off = 1; off < 64; off <<= 1) {
            m0 = fmaxf(m0, __shfl_xor(m0, off));
            m1 = fmaxf(m1, __shfl_xor(m1, off));
        }
        float ps0 = 0.f, ps1 = 0.f;
        for (int kc = 0; kc <= kcMax; ++kc) {
            const int kidx = kc * 64 + lane;
            const float p0 = expf(sc0[kc] - m0);
            const float p1 = expf(sc1[kc] - m1);
            ps0 += p0; ps1 += p1;
            if (kidx < kT) { plds[wv][0][kidx] = p0; plds[wv][1][kidx] = p1; }
        }
#pragma unroll
        for (int off = 1; off < 64; off <<= 1) {
            ps0 += __shfl_xor(ps0, off);
            ps1 += __shfl_xor(ps1, off);
        }
        float o0 = 0.f, o1 = 0.f;
        const float* vrow = &vp[base + hoff + lane];
        for (int k = 0; k <= qr1; ++k) {
            const float vv = vrow[(size_t)k * kH];
            o0 += plds[wv][0][k] * vv;
            o1 += plds[wv][1][k] * vv;
        }
        const size_t o0off = base + (size_t)qr0 * kH + hoff + lane;
        const size_t o1off = base + (size_t)qr1 * kH + hoff + lane;
        outp[o0off] = resid[o0off] + o0 / ps0;
        outp[o1off] = resid[o1off] + o1 / ps1;
    }
}

// ---------------------------------------------------------------------------
extern "C" void kernel_launch(void* const* d_in, const int* in_sizes, int n_in,
                              void* d_out, int out_size, void* d_ws, size_t ws_size,
                              hipStream_t stream)
{
    const int* ids_o = (const int*)d_in[0];
    const int* ids_x = (const int*)d_in[1];
    const int* ids_y = (const int*)d_in[2];
    const int* pos_o = (const int*)d_in[3];
    const int* pos_x = (const int*)d_in[4];
    const int* pos_y = (const int*)d_in[5];
    const int* tm_o  = (const int*)d_in[6];
    const int* tm_x  = (const int*)d_in[7];
    const int* tm_y  = (const int*)d_in[8];
    const int* itv_x = (const int*)d_in[9];
    const int* itv_y = (const int*)d_in[10];
    const int* itv_o = (const int*)d_in[11];
    const float* embX = (const float*)d_in[12];
    const float* embY = (const float*)d_in[13];
    const float* embO = (const float*)d_in[14];
    const float* time_table = (const float*)d_in[15];
    const float* interval_table = (const float*)d_in[16];
    const int* adj_idx  = (const int*)d_in[17];
    const float* adj_val = (const float*)d_in[18];
    const int* adjs_idx  = (const int*)d_in[19];
    const float* adjs_val = (const float*)d_in[20];
    const float* mlp_W1 = (const float*)d_in[21];
    const float* mlp_b1 = (const float*)d_in[22];
    const float* mlp_W2 = (const float*)d_in[23];
    const float* mlp_b2 = (const float*)d_in[24];
    const float* mlp_lng = (const float*)d_in[25];
    const float* mlp_lnb = (const float*)d_in[26];
    const float* pos_emb = (const float*)d_in[27];
    const float* gate_W = (const float*)d_in[28];
    const float* gate_b = (const float*)d_in[29];
    const float* aln_g = (const float*)d_in[30];
    const float* aln_b = (const float*)d_in[31];
    const float* qW = (const float*)d_in[32];
    const float* kW = (const float*)d_in[33];
    const float* vW = (const float*)d_in[34];
    const float* c1W = (const float*)d_in[35];
    const float* c2W = (const float*)d_in[36];
    const float* qb = (const float*)d_in[37];
    const float* kb = (const float*)d_in[38];
    const float* vb = (const float*)d_in[39];
    const float* c1b = (const float*)d_in[40];
    const float* c2b = (const float*)d_in[41];
    const float* fln_g = (const float*)d_in[42];
    const float* fln_b = (const float*)d_in[43];
    const float* lln_g = (const float*)d_in[44];
    const float* lln_b = (const float*)d_in[45];

    float* out = (float*)d_out;
    float* ws = (float*)d_ws;

    // ---- workspace layout (floats) ----
    const size_t SZ_TOK = (size_t)kM * kH;        // 3,276,800
    float* BIG  = ws;                              // SMOOTH (12.8M) / hidden (13.1M)
    float* XBUF = BIG  + 13107200;                 // QP / FFN hidden / build_x
    float* TEMB = XBUF + SZ_TOK;
    float* SEQS = TEMB + SZ_TOK;
    float* QBUF = SEQS + SZ_TOK;
    float* KP   = QBUF + SZ_TOK;                   // aliased: EDGES during CSR phase
    float* VP   = KP   + SZ_TOK;
    float* GATES = VP  + SZ_TOK;                   // 51,200 floats
    short* WT = (short*)(GATES + 51200);           // 884,736 bf16
    short* qWT = WT;
    short* c1WT = WT + 3 * 6 * 16384;              // after q,k,v blocks
    short* c2WT = c1WT + 6 * 16384;
    short* w1T = c2WT + 6 * 16384;                 // 3 x 512x128
    short* w2T = w1T + 3 * 65536;                  // 3 x 128x512
    int* COUNTS = (int*)(WT + 884736);
    int* OFFS   = COUNTS + kROWS;                  // kROWS+1
    int* CURS   = OFFS + kROWS + 1;
    int* PART   = CURS + kROWS;                    // 256
    unsigned char* FLAGS = (unsigned char*)(PART + 256);  // 100,000 B
    int2* EDGES = (int2*)KP;                       // 1.6M int2 = 12.8MB <= 13.1MB

    const size_t needed = (size_t)(13107200 + 7 * 3276800 + 51200) * 4
                        + (size_t)884736 * 2
                        + (size_t)(3 * kROWS + 257) * 4 + kROWS + 64;
    if (ws_size < needed) return;

    // ---- one-time weight transpose/convert ----
    wt_kernel<<<6 * 16384 / 256, 256, 0, stream>>>(qW, qWT, 7, 7);
    wt_kernel<<<6 * 16384 / 256, 256, 0, stream>>>(kW, qWT + 6 * 16384, 7, 7);
    wt_kernel<<<6 * 16384 / 256, 256, 0, stream>>>(vW, qWT + 12 * 16384, 7, 7);
    wt_kernel<<<6 * 16384 / 256, 256, 0, stream>>>(c1W, c1WT, 7, 7);
    wt_kernel<<<6 * 16384 / 256, 256, 0, stream>>>(c2W, c2WT, 7, 7);
    wt_kernel<<<3 * 65536 / 256, 256, 0, stream>>>(mlp_W1, w1T, 7, 9);
    wt_kernel<<<3 * 65536 / 256, 256, 0, stream>>>(mlp_W2, w2T, 9, 7);

    struct Enc {
        const int* ids; const int* pos; const int* tm; const int* itv;
        const float* emb; const int* a_idx; const float* a_val; int mi;
    };
    const Enc encs[3] = {
        { ids_o, pos_o, tm_o, itv_o, embO, adj_idx,  adj_val,  2 },
        { ids_x, pos_x, tm_x, itv_x, embX, adjs_idx, adjs_val, 0 },
        { ids_y, pos_y, tm_y, itv_y, embY, adjs_idx, adjs_val, 1 },
    };

    for (int e = 0; e < 3; ++e) {
        const Enc& E = encs[e];
        // ---- CSR build + smoothed embedding rows ----
        hipMemsetAsync(FLAGS, 0, kROWS, stream);
        hipMemsetAsync(COUNTS, 0, kROWS * sizeof(int), stream);
        flag_kernel<<<kM / 256, 256, 0, stream>>>(E.ids, FLAGS);
        count_kernel<<<kNNZ / 256, 256, 0, stream>>>(E.a_idx, FLAGS, COUNTS);
        scan_pass1<<<98, 256, 0, stream>>>(COUNTS, PART);
        scan_pass2<<<1, 128, 0, stream>>>(PART, 98);
        scan_pass3<<<98, 256, 0, stream>>>(COUNTS, PART, OFFS, CURS);
        scatter_kernel<<<kNNZ / 256, 256, 0, stream>>>(E.a_idx, E.a_val, FLAGS, CURS, EDGES, kNNZ);
        smooth_kernel<<<25000, 256, 0, stream>>>(EDGES, OFFS, FLAGS, E.emb, BIG);
        gather_kernel<<<kM / 2, 256, 0, stream>>>(E.ids, BIG, SEQS);
        // ---- temb = LN(MLP(interval_emb + time_emb)) ----
        build_x_kernel<<<kM / 2, 256, 0, stream>>>(E.itv, E.tm, interval_table, time_table, XBUF);
        gemm_bf16<<<dim3(4, kM / 128), 256, 0, stream>>>(
            XBUF, nullptr, w1T + (size_t)E.mi * 65536, mlp_b1 + E.mi * 512, BIG,
            kM, 512, kH, 1, 0, nullptr);
        gemm_bf16<<<dim3(1, kM / 128), 256, 0, stream>>>(
            BIG, nullptr, w2T + (size_t)E.mi * 65536, mlp_b2 + E.mi * kH, TEMB,
            kM, kH, 512, 0, 0, nullptr);
        ln_wave<<<kM / 4, 256, 0, stream>>>(TEMB, TEMB, mlp_lng + E.mi * kH, mlp_lnb + E.mi * kH, 1e-5f);
        // ---- +pos / mask / gates ----
        pos_mask_kernel<<<kM / 2, 256, 0, stream>>>(E.ids, E.pos, pos_emb + (size_t)e * kT * kH, SEQS, TEMB);
        gates_kernel<<<kM / 4, 256, 0, stream>>>(TEMB, gate_W + e * kH * 2, gate_b + e * 2, GATES);
        // ---- 2 attention blocks ----
        for (int i = 0; i < 2; ++i) {
            const int wo = e * 2 + i;
            ln_wave<<<kM / 4, 256, 0, stream>>>(SEQS, QBUF, aln_g + wo * kH, aln_b + wo * kH, 1e-8f);
            gemm_qkv<<<dim3(1, kM / 128, 3), 256, 0, stream>>>(
                QBUF, TEMB, SEQS, TEMB, qWT, wo,
                qb + wo * kH, kb + wo * kH, vb + wo * kH,
                XBUF, KP, VP);
            attn_kernel<<<kBATCH * 4, 256, 0, stream>>>(XBUF, KP, VP, GATES, i, QBUF, SEQS);
            ln_wave<<<kM / 4, 256, 0, stream>>>(SEQS, SEQS, fln_g + wo * kH, fln_b + wo * kH, 1e-8f);
            gemm_bf16<<<dim3(1, kM / 128), 256, 0, stream>>>(
                SEQS, nullptr, c1WT + (size_t)wo * 16384, c1b + wo * kH, XBUF, kM, kH, kH, 1, 0, nullptr);
            gemm_bf16<<<dim3(1, kM / 128), 256, 0, stream>>>(
                XBUF, nullptr, c2WT + (size_t)wo * 16384, c2b + wo * kH, SEQS, kM, kH, kH, 0, 1, E.ids);
        }
        ln_wave<<<kM / 4, 256, 0, stream>>>(SEQS, out + (size_t)e * kM * kH, lln_g + e * kH, lln_b + e * kH, 1e-8f);
    }
}

// Round 4
// 1357.882 us; speedup vs baseline: 3.7140x; 1.3830x over previous
//
#include <hip/hip_runtime.h>
#include <math.h>

// ---------------------------------------------------------------------------
// TACDSR forward — round 4: MFMA flash attention (K swizzled in LDS, V
// transposed in LDS, P via per-wave LDS buffer). CSR spmm + bf16 GEMMs kept.
// ---------------------------------------------------------------------------

#define kH 128
#define kT 200
#define kBATCH 128
#define kM (kBATCH * kT)         // 25600 tokens
#define kITEMS 100000
#define kROWS 100000
#define kNNZ 1600000
#define kNEG_INF (-__builtin_huge_valf())

typedef short s16x8 __attribute__((ext_vector_type(8)));
typedef __bf16 b16x8 __attribute__((ext_vector_type(8)));
typedef float f32x4 __attribute__((ext_vector_type(4)));

static __device__ __forceinline__ short f2bf(float f) {
    unsigned u = __float_as_uint(f);
    unsigned r = (u + 0x7FFFu + ((u >> 16) & 1u)) >> 16;
    return (short)r;
}
static __device__ __forceinline__ f32x4 mfma16(s16x8 a, s16x8 b, f32x4 c) {
    return __builtin_amdgcn_mfma_f32_16x16x32_bf16(
        __builtin_bit_cast(b16x8, a), __builtin_bit_cast(b16x8, b), c, 0, 0, 0);
}

// ======================= CSR build + smooth ================================
__global__ void flag_kernel(const int* __restrict__ ids, unsigned char* __restrict__ flags)
{
    flags[ids[blockIdx.x * 256 + threadIdx.x]] = 1;
}

__global__ void count_kernel(const int* __restrict__ idx,
                             const unsigned char* __restrict__ flags,
                             int* __restrict__ counts)
{
    const int j = blockIdx.x * 256 + threadIdx.x;
    const int row = idx[j];
    if (flags[row]) atomicAdd(&counts[row], 1);
}

__global__ __launch_bounds__(256) void scan_pass1(const int* __restrict__ counts,
                                                  int* __restrict__ partial)
{
    const int t = threadIdx.x;
    const int base = blockIdx.x * 1024;
    int s = 0;
#pragma unroll
    for (int i = 0; i < 4; ++i) {
        const int g = base + t + i * 256;
        if (g < kROWS) s += counts[g];
    }
    __shared__ int sd[256];
    sd[t] = s; __syncthreads();
    for (int off = 128; off > 0; off >>= 1) {
        if (t < off) sd[t] += sd[t + off];
        __syncthreads();
    }
    if (t == 0) partial[blockIdx.x] = sd[0];
}

__global__ void scan_pass2(int* __restrict__ partial, int nblk)
{
    const int t = threadIdx.x;          // 128 threads
    __shared__ int sd[128];
    const int v = (t < nblk) ? partial[t] : 0;
    sd[t] = v; __syncthreads();
    for (int off = 1; off < 128; off <<= 1) {
        const int a = (t >= off) ? sd[t - off] : 0;
        __syncthreads();
        sd[t] += a;
        __syncthreads();
    }
    if (t < nblk) partial[t] = sd[t] - v;   // exclusive
}

__global__ __launch_bounds__(256) void scan_pass3(const int* __restrict__ counts,
                                                  const int* __restrict__ partial,
                                                  int* __restrict__ offsets,
                                                  int* __restrict__ cursor)
{
    const int t = threadIdx.x;
    const int base = blockIdx.x * 1024;
    int c[4]; int s = 0;
#pragma unroll
    for (int i = 0; i < 4; ++i) {
        const int g = base + t * 4 + i;
        c[i] = (g < kROWS) ? counts[g] : 0;
        s += c[i];
    }
    __shared__ int sd[256];
    sd[t] = s; __syncthreads();
    for (int off = 1; off < 256; off <<= 1) {
        const int a = (t >= off) ? sd[t - off] : 0;
        __syncthreads();
        sd[t] += a;
        __syncthreads();
    }
    int run = partial[blockIdx.x] + sd[t] - s;
#pragma unroll
    for (int i = 0; i < 4; ++i) {
        const int g = base + t * 4 + i;
        if (g < kROWS) {
            offsets[g] = run;
            cursor[g] = run;
            run += c[i];
            if (g == kROWS - 1) offsets[kROWS] = run;
        }
    }
}

__global__ void scatter_kernel(const int* __restrict__ idx, const float* __restrict__ val,
                               const unsigned char* __restrict__ flags,
                               int* __restrict__ cursor, int2* __restrict__ edges, int nnz)
{
    const int j = blockIdx.x * 256 + threadIdx.x;
    const int row = idx[j];
    if (!flags[row]) return;
    const int pos = atomicAdd(&cursor[row], 1);
    edges[pos] = make_int2(idx[nnz + j], __float_as_int(val[j]));
}

__global__ __launch_bounds__(256) void smooth_kernel(
    const int2* __restrict__ edges, const int* __restrict__ offsets,
    const unsigned char* __restrict__ flags, const float* __restrict__ emb,
    float* __restrict__ sm)
{
    const int row = blockIdx.x * 4 + (threadIdx.x >> 6);
    const int lane = threadIdx.x & 63;
    if (row >= kROWS || !flags[row]) return;
    const int lo = offsets[row], hi = offsets[row + 1];
    float a0 = 0.f, a1 = 0.f;
    for (int e = lo; e < hi; ++e) {
        const int2 ed = edges[e];
        const float v = __int_as_float(ed.y);
        const float* er = &emb[(size_t)ed.x * kH];
        a0 = fmaf(v, er[lane], a0);
        a1 = fmaf(v, er[64 + lane], a1);
    }
    float s = a0 * a0 + a1 * a1;
#pragma unroll
    for (int off = 1; off < 64; off <<= 1) s += __shfl_xor(s, off);
    const float inv = 0.5f / fmaxf(sqrtf(s), 1e-12f);
    const float* mr = &emb[(size_t)row * kH];
    sm[(size_t)row * kH + lane]      = 1.5f * mr[lane]      + a0 * inv;
    sm[(size_t)row * kH + 64 + lane] = 1.5f * mr[64 + lane] + a1 * inv;
}

__global__ void gather_kernel(const int* __restrict__ ids, const float* __restrict__ sm,
                              float* __restrict__ seqs)
{
    const int tok = blockIdx.x * 2 + (threadIdx.x >> 7);
    const int c = threadIdx.x & 127;
    seqs[(size_t)tok * kH + c] = sm[(size_t)ids[tok] * kH + c];
}

__global__ void pos_mask_kernel(const int* __restrict__ ids, const int* __restrict__ pos,
                                const float* __restrict__ pemb,
                                float* __restrict__ seqs, float* __restrict__ temb)
{
    const int tok = blockIdx.x * 2 + (threadIdx.x >> 7);
    const int c = threadIdx.x & 127;
    const float p = pemb[(size_t)pos[tok] * kH + c];
    temb[(size_t)tok * kH + c] += p;
    const size_t off = (size_t)tok * kH + c;
    seqs[off] = (ids[tok] == kITEMS - 1) ? 0.f : seqs[off] + p;
}

// ======================= misc small kernels ================================
__global__ void build_x_kernel(
    const int* __restrict__ itv, const int* __restrict__ tt,
    const float* __restrict__ interval_table, const float* __restrict__ time_table,
    float* __restrict__ x)
{
    const int tok = blockIdx.x * 2 + (threadIdx.x >> 7);
    const int c = threadIdx.x & 127;
    const int t = itv[tok];
    int idx = (int)floorf(log2f((float)t + 1.0f));
    idx = idx < 0 ? 0 : (idx > 30 ? 30 : idx);
    x[(size_t)tok * kH + c] = interval_table[idx * kH + c] + time_table[(size_t)tt[tok] * kH + c];
}

__global__ void wt_kernel(const float* __restrict__ in, short* __restrict__ out,
                          int kLog, int nLog)
{
    const int i = blockIdx.x * 256 + threadIdx.x;
    const int knLog = kLog + nLog;
    const int b = i >> knLog;
    const int rem = i & ((1 << knLog) - 1);
    const int n = rem >> kLog;
    const int k = rem & ((1 << kLog) - 1);
    out[i] = f2bf(in[((size_t)b << knLog) + ((size_t)k << nLog) + n]);
}

__global__ __launch_bounds__(256) void ln_wave(
    const float* __restrict__ in, float* __restrict__ out,
    const float* __restrict__ g, const float* __restrict__ bb, float eps)
{
    const int tok = blockIdx.x * 4 + (threadIdx.x >> 6);
    const int lane = threadIdx.x & 63;
    const float x0 = in[(size_t)tok * kH + lane];
    const float x1 = in[(size_t)tok * kH + 64 + lane];
    float s1 = x0 + x1, s2 = x0 * x0 + x1 * x1;
#pragma unroll
    for (int off = 1; off < 64; off <<= 1) {
        s1 += __shfl_xor(s1, off);
        s2 += __shfl_xor(s2, off);
    }
    const float mean = s1 * (1.f / 128.f);
    float var = s2 * (1.f / 128.f) - mean * mean;
    var = fmaxf(var, 0.f);
    const float r = rsqrtf(var + eps);
    out[(size_t)tok * kH + lane]      = (x0 - mean) * r * g[lane]      + bb[lane];
    out[(size_t)tok * kH + 64 + lane] = (x1 - mean) * r * g[64 + lane] + bb[64 + lane];
}

__global__ void gates_kernel(
    const float* __restrict__ temb, const float* __restrict__ gW,
    const float* __restrict__ gb, float* __restrict__ gates)
{
    const int wv = threadIdx.x >> 6;
    const int lane = threadIdx.x & 63;
    const int tok = blockIdx.x * 4 + wv;
    const float t0 = temb[(size_t)tok * kH + lane];
    const float t1 = temb[(size_t)tok * kH + 64 + lane];
#pragma unroll
    for (int i = 0; i < 2; ++i) {
        float p = t0 * gW[lane * 2 + i] + t1 * gW[(64 + lane) * 2 + i];
#pragma unroll
        for (int off = 1; off < 64; off <<= 1) p += __shfl_xor(p, off);
        if (lane == 0) gates[tok * 2 + i] = 1.f / (1.f + expf(-(p + gb[i])));
    }
}

// ======================= bf16 MFMA GEMM ====================================
static __device__ __forceinline__ void gemm_body(
    const float* __restrict__ A, const float* __restrict__ A2,
    const short* __restrict__ BT, const float* __restrict__ bias,
    float* __restrict__ C, int M, int N, int K, int relu, int accum,
    const int* __restrict__ mask_ids)
{
    __shared__ short As[128 * 128];
    __shared__ short Bs[128 * 128];
    const int tid = threadIdx.x;
    const int lane = tid & 63;
    const int w = tid >> 6;
    const int rowBase = blockIdx.y * 128;
    const int colBase = blockIdx.x * 128;
    f32x4 acc[2][8] = {};

    for (int k0 = 0; k0 < K; k0 += 128) {
#pragma unroll
        for (int p = 0; p < 8; ++p) {
            const int chunk = p * 256 + tid;
            const int r = chunk >> 4;
            const int kc = chunk & 15;
            const int byteoff = (r * 256 + kc * 16) ^ ((r & 7) << 4);
            {
                const float* src = &A[(size_t)(rowBase + r) * K + k0 + kc * 8];
                float4 a0 = *reinterpret_cast<const float4*>(src);
                float4 a1 = *reinterpret_cast<const float4*>(src + 4);
                if (A2) {
                    const float* s2 = &A2[(size_t)(rowBase + r) * K + k0 + kc * 8];
                    float4 b0 = *reinterpret_cast<const float4*>(s2);
                    float4 b1 = *reinterpret_cast<const float4*>(s2 + 4);
                    a0.x += b0.x; a0.y += b0.y; a0.z += b0.z; a0.w += b0.w;
                    a1.x += b1.x; a1.y += b1.y; a1.z += b1.z; a1.w += b1.w;
                }
                s16x8 v;
                v[0] = f2bf(a0.x); v[1] = f2bf(a0.y); v[2] = f2bf(a0.z); v[3] = f2bf(a0.w);
                v[4] = f2bf(a1.x); v[5] = f2bf(a1.y); v[6] = f2bf(a1.z); v[7] = f2bf(a1.w);
                *reinterpret_cast<s16x8*>(reinterpret_cast<char*>(As) + byteoff) = v;
            }
            {
                const s16x8 v = *reinterpret_cast<const s16x8*>(
                    &BT[(size_t)(colBase + r) * K + k0 + kc * 8]);
                *reinterpret_cast<s16x8*>(reinterpret_cast<char*>(Bs) + byteoff) = v;
            }
        }
        __syncthreads();
#pragma unroll
        for (int kk = 0; kk < 4; ++kk) {
            const int kb = (kk * 32 + (lane >> 4) * 8) * 2;
            s16x8 af[2];
#pragma unroll
            for (int mi = 0; mi < 2; ++mi) {
                const int r = w * 32 + mi * 16 + (lane & 15);
                af[mi] = *reinterpret_cast<const s16x8*>(
                    reinterpret_cast<const char*>(As) + ((r * 256 + kb) ^ ((r & 7) << 4)));
            }
#pragma unroll
            for (int nj = 0; nj < 8; ++nj) {
                const int r = nj * 16 + (lane & 15);
                const s16x8 bf = *reinterpret_cast<const s16x8*>(
                    reinterpret_cast<const char*>(Bs) + ((r * 256 + kb) ^ ((r & 7) << 4)));
#pragma unroll
                for (int mi = 0; mi < 2; ++mi)
                    acc[mi][nj] = mfma16(af[mi], bf, acc[mi][nj]);
            }
        }
        __syncthreads();
    }
#pragma unroll
    for (int mi = 0; mi < 2; ++mi) {
        const int rowb = rowBase + w * 32 + mi * 16 + (lane >> 4) * 4;
#pragma unroll
        for (int nj = 0; nj < 8; ++nj) {
            const int col = colBase + nj * 16 + (lane & 15);
            const float bc = bias[col];
            f32x4 v = acc[mi][nj];
#pragma unroll
            for (int r = 0; r < 4; ++r) {
                const int row = rowb + r;
                float x = v[r] + bc;
                if (relu) x = fmaxf(x, 0.f);
                const size_t off = (size_t)row * N + col;
                if (accum) x += C[off];
                if (mask_ids && mask_ids[row] == kITEMS - 1) x = 0.f;
                C[off] = x;
            }
        }
    }
}

__global__ __launch_bounds__(256) void gemm_bf16(
    const float* __restrict__ A, const float* __restrict__ A2,
    const short* __restrict__ BT, const float* __restrict__ bias,
    float* __restrict__ C, int M, int N, int K, int relu, int accum,
    const int* __restrict__ mask_ids)
{
    gemm_body(A, A2, BT, bias, C, M, N, K, relu, accum, mask_ids);
}

__global__ __launch_bounds__(256) void gemm_qkv(
    const float* __restrict__ Aq, const float* __restrict__ Ak,
    const float* __restrict__ Av, const float* __restrict__ Av2,
    const short* __restrict__ WT, int wo,
    const float* __restrict__ bq, const float* __restrict__ bk, const float* __restrict__ bv,
    float* __restrict__ Cq, float* __restrict__ Ck, float* __restrict__ Cv)
{
    const int z = blockIdx.z;
    const float* A  = (z == 0) ? Aq : (z == 1) ? Ak : Av;
    const float* A2 = (z == 2) ? Av2 : nullptr;
    const short* B  = WT + (size_t)z * 6 * 16384 + (size_t)wo * 16384;
    const float* bias = (z == 0) ? bq : (z == 1) ? bk : bv;
    float* C = (z == 0) ? Cq : (z == 1) ? Ck : Cv;
    gemm_body(A, A2, B, bias, C, kM, kH, kH, 0, 0, nullptr);
}

// ======================= MFMA flash attention ==============================
// 1 block per (b,h), 4 waves; each wave owns q-tiles wv, wv+4, ... (13 tiles).
// K: bf16 LDS, XOR-swizzled rows. V: bf16 LDS transposed Vt[d][k] (stride 232).
// P: per-wave bf16 LDS [16][232], pre-zeroed. out = resid + (P@V)/rowsum.
#define aNT 13            // 16-row tiles covering 200 (pad 208)
#define aVS 232           // Vt / P row stride in bf16 (16B-aligned, 2-way reads)

__global__ __launch_bounds__(256) void attn_mfma(
    const float* __restrict__ qp, const float* __restrict__ kp,
    const float* __restrict__ vp, const float* __restrict__ gates,
    const int gi, const float* __restrict__ resid, float* __restrict__ outp)
{
    __shared__ short klds[200 * 64];         // 25600 B, swizzled
    __shared__ short vt[64 * aVS];           // 29696 B
    __shared__ short pl[4][16 * aVS];        // 29696 B
    __shared__ float glds[224];
    const int bid = (int)blockIdx.x;
    const int b = bid >> 1, h = bid & 1, hoff = h * 64;
    const int tid = threadIdx.x, lane = tid & 63, wv = tid >> 6;
    const size_t base = (size_t)b * kT * kH;

    // ---- stage K (bf16, swizzled): 200 rows x 8 chunks of 8 ----
    for (int i = tid; i < 1600; i += 256) {
        const int r = i >> 3, c8 = i & 7;
        const float* src = &kp[base + (size_t)r * kH + hoff + c8 * 8];
        const float4 a0 = *reinterpret_cast<const float4*>(src);
        const float4 a1 = *reinterpret_cast<const float4*>(src + 4);
        s16x8 v;
        v[0] = f2bf(a0.x); v[1] = f2bf(a0.y); v[2] = f2bf(a0.z); v[3] = f2bf(a0.w);
        v[4] = f2bf(a1.x); v[5] = f2bf(a1.y); v[6] = f2bf(a1.z); v[7] = f2bf(a1.w);
        *reinterpret_cast<s16x8*>(reinterpret_cast<char*>(klds) +
            ((r * 128 + c8 * 16) ^ ((r & 7) << 4))) = v;
    }
    // ---- stage Vt (transposed, packed pairs of k) ----
    for (int i = tid; i < 6400; i += 256) {       // 100 k-pairs x 64 d
        const int k2 = i >> 6, d = i & 63;
        const float v0 = vp[base + (size_t)(2 * k2) * kH + hoff + d];
        const float v1 = vp[base + (size_t)(2 * k2 + 1) * kH + hoff + d];
        const unsigned pk = (unsigned)(unsigned short)f2bf(v0)
                          | ((unsigned)(unsigned short)f2bf(v1) << 16);
        *reinterpret_cast<unsigned*>(reinterpret_cast<char*>(vt) + d * (aVS * 2) + k2 * 4) = pk;
    }
    // zero Vt pad k = 200..231
    for (int i = tid; i < 1024; i += 256) {       // 64 d x 16 k-pairs
        const int d = i >> 4, k2 = 100 + (i & 15);
        *reinterpret_cast<unsigned*>(reinterpret_cast<char*>(vt) + d * (aVS * 2) + k2 * 4) = 0;
    }
    if (tid < 224) glds[tid] = (tid < 200) ? gates[(b * kT + tid) * 2 + gi] : 0.f;
    // zero own P buffer (covers never-written upper tiles)
    for (int i = lane; i < 16 * aVS / 2; i += 64)
        reinterpret_cast<unsigned*>(pl[wv])[i] = 0u;
    __syncthreads();

    const int c = lane & 15, hi = lane >> 4;
    const float scale = 0.125f;

    for (int qt = wv; qt < aNT; qt += 4) {
        // ---- Q A-frags (2 halves of d) from global f32 ----
        s16x8 aq0, aq1;
        {
            const float* s0 = &qp[base + (size_t)(qt * 16 + c) * kH + hoff + hi * 8];
            const float4 a0 = *reinterpret_cast<const float4*>(s0);
            const float4 a1 = *reinterpret_cast<const float4*>(s0 + 4);
            const float4 b0 = *reinterpret_cast<const float4*>(s0 + 32);
            const float4 b1 = *reinterpret_cast<const float4*>(s0 + 36);
            aq0[0] = f2bf(a0.x); aq0[1] = f2bf(a0.y); aq0[2] = f2bf(a0.z); aq0[3] = f2bf(a0.w);
            aq0[4] = f2bf(a1.x); aq0[5] = f2bf(a1.y); aq0[6] = f2bf(a1.z); aq0[7] = f2bf(a1.w);
            aq1[0] = f2bf(b0.x); aq1[1] = f2bf(b0.y); aq1[2] = f2bf(b0.z); aq1[3] = f2bf(b0.w);
            aq1[4] = f2bf(b1.x); aq1[5] = f2bf(b1.y); aq1[6] = f2bf(b1.z); aq1[7] = f2bf(b1.w);
        }
        // ---- S = Q@K^T per k-tile ----
        f32x4 sc[aNT];
#pragma unroll
        for (int kt = 0; kt < aNT; ++kt) {
            if (kt > qt) continue;                 // wave-uniform skip
            const int krow = kt * 16 + c;
            const int sw = (krow & 7) << 4;
            const s16x8 bk0 = *reinterpret_cast<const s16x8*>(
                reinterpret_cast<const char*>(klds) + ((krow * 128 + hi * 16) ^ sw));
            const s16x8 bk1 = *reinterpret_cast<const s16x8*>(
                reinterpret_cast<const char*>(klds) + ((krow * 128 + 64 + hi * 16) ^ sw));
            f32x4 s = {0.f, 0.f, 0.f, 0.f};
            s = mfma16(aq0, bk0, s);
            s = mfma16(aq1, bk1, s);
            sc[kt] = s;
        }
        // ---- mask + gate + row max ----
        float gq[4], m[4], ps[4];
#pragma unroll
        for (int r = 0; r < 4; ++r) {
            gq[r] = glds[qt * 16 + hi * 4 + r];
            m[r] = kNEG_INF; ps[r] = 0.f;
        }
#pragma unroll
        for (int kt = 0; kt < aNT; ++kt) {
            if (kt > qt) continue;
            const int col = kt * 16 + c;
            const float gk = glds[col] * scale;
#pragma unroll
            for (int r = 0; r < 4; ++r) {
                const int row = qt * 16 + hi * 4 + r;
                const float v = (col <= row && col < 200) ? sc[kt][r] * gq[r] * gk : kNEG_INF;
                sc[kt][r] = v;
                m[r] = fmaxf(m[r], v);
            }
        }
#pragma unroll
        for (int r = 0; r < 4; ++r)
#pragma unroll
            for (int off = 1; off < 16; off <<= 1)
                m[r] = fmaxf(m[r], __shfl_xor(m[r], off));
        // ---- P = exp(S-m), write bf16 to per-wave LDS, accumulate rowsum ----
#pragma unroll
        for (int kt = 0; kt < aNT; ++kt) {
            if (kt > qt) continue;
#pragma unroll
            for (int r = 0; r < 4; ++r) {
                const float p = __expf(sc[kt][r] - m[r]);
                ps[r] += p;
                *reinterpret_cast<short*>(reinterpret_cast<char*>(pl[wv]) +
                    ((hi * 4 + r) * aVS + kt * 16 + c) * 2) = f2bf(p);
            }
        }
#pragma unroll
        for (int r = 0; r < 4; ++r)
#pragma unroll
            for (int off = 1; off < 16; off <<= 1)
                ps[r] += __shfl_xor(ps[r], off);
        // ---- O = P@V ----
        f32x4 oacc[4] = {};
        const int nch = (qt + 2) >> 1;             // 32-wide k chunks
#pragma unroll
        for (int ks = 0; ks < 7; ++ks) {
            if (ks >= nch) continue;
            const s16x8 pa = *reinterpret_cast<const s16x8*>(
                reinterpret_cast<const char*>(pl[wv]) + (c * aVS + ks * 32 + hi * 8) * 2);
#pragma unroll
            for (int n = 0; n < 4; ++n) {
                const s16x8 bv = *reinterpret_cast<const s16x8*>(
                    reinterpret_cast<const char*>(vt) + ((n * 16 + c) * aVS + ks * 32 + hi * 8) * 2);
                oacc[n] = mfma16(pa, bv, oacc[n]);
            }
        }
        // ---- epilogue: out = resid + O/rowsum ----
#pragma unroll
        for (int r = 0; r < 4; ++r) {
            const int row = qt * 16 + hi * 4 + r;
            if (row < 200) {
                const float inv = 1.f / ps[r];
#pragma unroll
                for (int n = 0; n < 4; ++n) {
                    const size_t off = base + (size_t)row * kH + hoff + n * 16 + c;
                    outp[off] = resid[off] + oacc[n][r] * inv;
                }
            }
        }
    }
}

// ---------------------------------------------------------------------------
extern "C" void kernel_launch(void* const* d_in, const int* in_sizes, int n_in,
                              void* d_out, int out_size, void* d_ws, size_t ws_size,
                              hipStream_t stream)
{
    const int* ids_o = (const int*)d_in[0];
    const int* ids_x = (const int*)d_in[1];
    const int* ids_y = (const int*)d_in[2];
    const int* pos_o = (const int*)d_in[3];
    const int* pos_x = (const int*)d_in[4];
    const int* pos_y = (const int*)d_in[5];
    const int* tm_o  = (const int*)d_in[6];
    const int* tm_x  = (const int*)d_in[7];
    const int* tm_y  = (const int*)d_in[8];
    const int* itv_x = (const int*)d_in[9];
    const int* itv_y = (const int*)d_in[10];
    const int* itv_o = (const int*)d_in[11];
    const float* embX = (const float*)d_in[12];
    const float* embY = (const float*)d_in[13];
    const float* embO = (const float*)d_in[14];
    const float* time_table = (const float*)d_in[15];
    const float* interval_table = (const float*)d_in[16];
    const int* adj_idx  = (const int*)d_in[17];
    const float* adj_val = (const float*)d_in[18];
    const int* adjs_idx  = (const int*)d_in[19];
    const float* adjs_val = (const float*)d_in[20];
    const float* mlp_W1 = (const float*)d_in[21];
    const float* mlp_b1 = (const float*)d_in[22];
    const float* mlp_W2 = (const float*)d_in[23];
    const float* mlp_b2 = (const float*)d_in[24];
    const float* mlp_lng = (const float*)d_in[25];
    const float* mlp_lnb = (const float*)d_in[26];
    const float* pos_emb = (const float*)d_in[27];
    const float* gate_W = (const float*)d_in[28];
    const float* gate_b = (const float*)d_in[29];
    const float* aln_g = (const float*)d_in[30];
    const float* aln_b = (const float*)d_in[31];
    const float* qW = (const float*)d_in[32];
    const float* kW = (const float*)d_in[33];
    const float* vW = (const float*)d_in[34];
    const float* c1W = (const float*)d_in[35];
    const float* c2W = (const float*)d_in[36];
    const float* qb = (const float*)d_in[37];
    const float* kb = (const float*)d_in[38];
    const float* vb = (const float*)d_in[39];
    const float* c1b = (const float*)d_in[40];
    const float* c2b = (const float*)d_in[41];
    const float* fln_g = (const float*)d_in[42];
    const float* fln_b = (const float*)d_in[43];
    const float* lln_g = (const float*)d_in[44];
    const float* lln_b = (const float*)d_in[45];

    float* out = (float*)d_out;
    float* ws = (float*)d_ws;

    // ---- workspace layout (floats) ----
    const size_t SZ_TOK = (size_t)kM * kH;        // 3,276,800
    float* BIG  = ws;                              // SMOOTH (12.8M) / hidden (13.1M)
    float* XBUF = BIG  + 13107200;                 // QP / FFN hidden / build_x
    float* TEMB = XBUF + SZ_TOK;
    float* SEQS = TEMB + SZ_TOK;
    float* QBUF = SEQS + SZ_TOK;
    float* KP   = QBUF + SZ_TOK;                   // aliased: EDGES during CSR phase
    float* VP   = KP   + SZ_TOK;
    float* GATES = VP  + SZ_TOK;                   // 51,200 floats
    short* WT = (short*)(GATES + 51200);           // 884,736 bf16
    short* qWT = WT;
    short* c1WT = WT + 3 * 6 * 16384;              // after q,k,v blocks
    short* c2WT = c1WT + 6 * 16384;
    short* w1T = c2WT + 6 * 16384;                 // 3 x 512x128
    short* w2T = w1T + 3 * 65536;                  // 3 x 128x512
    int* COUNTS = (int*)(WT + 884736);
    int* OFFS   = COUNTS + kROWS;                  // kROWS+1
    int* CURS   = OFFS + kROWS + 1;
    int* PART   = CURS + kROWS;                    // 256
    unsigned char* FLAGS = (unsigned char*)(PART + 256);  // 100,000 B
    int2* EDGES = (int2*)KP;                       // 1.6M int2 = 12.8MB <= 13.1MB

    const size_t needed = (size_t)(13107200 + 7 * 3276800 + 51200) * 4
                        + (size_t)884736 * 2
                        + (size_t)(3 * kROWS + 257) * 4 + kROWS + 64;
    if (ws_size < needed) return;

    // ---- one-time weight transpose/convert ----
    wt_kernel<<<6 * 16384 / 256, 256, 0, stream>>>(qW, qWT, 7, 7);
    wt_kernel<<<6 * 16384 / 256, 256, 0, stream>>>(kW, qWT + 6 * 16384, 7, 7);
    wt_kernel<<<6 * 16384 / 256, 256, 0, stream>>>(vW, qWT + 12 * 16384, 7, 7);
    wt_kernel<<<6 * 16384 / 256, 256, 0, stream>>>(c1W, c1WT, 7, 7);
    wt_kernel<<<6 * 16384 / 256, 256, 0, stream>>>(c2W, c2WT, 7, 7);
    wt_kernel<<<3 * 65536 / 256, 256, 0, stream>>>(mlp_W1, w1T, 7, 9);
    wt_kernel<<<3 * 65536 / 256, 256, 0, stream>>>(mlp_W2, w2T, 9, 7);

    struct Enc {
        const int* ids; const int* pos; const int* tm; const int* itv;
        const float* emb; const int* a_idx; const float* a_val; int mi;
    };
    const Enc encs[3] = {
        { ids_o, pos_o, tm_o, itv_o, embO, adj_idx,  adj_val,  2 },
        { ids_x, pos_x, tm_x, itv_x, embX, adjs_idx, adjs_val, 0 },
        { ids_y, pos_y, tm_y, itv_y, embY, adjs_idx, adjs_val, 1 },
    };

    for (int e = 0; e < 3; ++e) {
        const Enc& E = encs[e];
        // ---- CSR build + smoothed embedding rows ----
        hipMemsetAsync(FLAGS, 0, kROWS, stream);
        hipMemsetAsync(COUNTS, 0, kROWS * sizeof(int), stream);
        flag_kernel<<<kM / 256, 256, 0, stream>>>(E.ids, FLAGS);
        count_kernel<<<kNNZ / 256, 256, 0, stream>>>(E.a_idx, FLAGS, COUNTS);
        scan_pass1<<<98, 256, 0, stream>>>(COUNTS, PART);
        scan_pass2<<<1, 128, 0, stream>>>(PART, 98);
        scan_pass3<<<98, 256, 0, stream>>>(COUNTS, PART, OFFS, CURS);
        scatter_kernel<<<kNNZ / 256, 256, 0, stream>>>(E.a_idx, E.a_val, FLAGS, CURS, EDGES, kNNZ);
        smooth_kernel<<<25000, 256, 0, stream>>>(EDGES, OFFS, FLAGS, E.emb, BIG);
        gather_kernel<<<kM / 2, 256, 0, stream>>>(E.ids, BIG, SEQS);
        // ---- temb = LN(MLP(interval_emb + time_emb)) ----
        build_x_kernel<<<kM / 2, 256, 0, stream>>>(E.itv, E.tm, interval_table, time_table, XBUF);
        gemm_bf16<<<dim3(4, kM / 128), 256, 0, stream>>>(
            XBUF, nullptr, w1T + (size_t)E.mi * 65536, mlp_b1 + E.mi * 512, BIG,
            kM, 512, kH, 1, 0, nullptr);
        gemm_bf16<<<dim3(1, kM / 128), 256, 0, stream>>>(
            BIG, nullptr, w2T + (size_t)E.mi * 65536, mlp_b2 + E.mi * kH, TEMB,
            kM, kH, 512, 0, 0, nullptr);
        ln_wave<<<kM / 4, 256, 0, stream>>>(TEMB, TEMB, mlp_lng + E.mi * kH, mlp_lnb + E.mi * kH, 1e-5f);
        // ---- +pos / mask / gates ----
        pos_mask_kernel<<<kM / 2, 256, 0, stream>>>(E.ids, E.pos, pos_emb + (size_t)e * kT * kH, SEQS, TEMB);
        gates_kernel<<<kM / 4, 256, 0, stream>>>(TEMB, gate_W + e * kH * 2, gate_b + e * 2, GATES);
        // ---- 2 attention blocks ----
        for (int i = 0; i < 2; ++i) {
            const int wo = e * 2 + i;
            ln_wave<<<kM / 4, 256, 0, stream>>>(SEQS, QBUF, aln_g + wo * kH, aln_b + wo * kH, 1e-8f);
            gemm_qkv<<<dim3(1, kM / 128, 3), 256, 0, stream>>>(
                QBUF, TEMB, SEQS, TEMB, qWT, wo,
                qb + wo * kH, kb + wo * kH, vb + wo * kH,
                XBUF, KP, VP);
            attn_mfma<<<kBATCH * 2, 256, 0, stream>>>(XBUF, KP, VP, GATES, i, QBUF, SEQS);
            ln_wave<<<kM / 4, 256, 0, stream>>>(SEQS, SEQS, fln_g + wo * kH, fln_b + wo * kH, 1e-8f);
            gemm_bf16<<<dim3(1, kM / 128), 256, 0, stream>>>(
                SEQS, nullptr, c1WT + (size_t)wo * 16384, c1b + wo * kH, XBUF, kM, kH, kH, 1, 0, nullptr);
            gemm_bf16<<<dim3(1, kM / 128), 256, 0, stream>>>(
                XBUF, nullptr, c2WT + (size_t)wo * 16384, c2b + wo * kH, SEQS, kM, kH, kH, 0, 1, E.ids);
        }
        ln_wave<<<kM / 4, 256, 0, stream>>>(SEQS, out + (size_t)e * kM * kH, lln_g + e * kH, lln_b + e * kH, 1e-8f);
    }
}

// Round 7
// 1303.439 us; speedup vs baseline: 3.8691x; 1.0418x over previous
//
#include <hip/hip_runtime.h>
#include <math.h>

// ---------------------------------------------------------------------------
// TACDSR forward — round 7: round-4 proven compute path (separate ln_wave,
// plain MFMA GEMMs, separate build_x) + verified CSR/smooth improvements
// (compacted rowlist, f32 float2 edge loads, vectorized count/scatter) and
// merged pos+mask+gates. Bisect: r5's GEMM-side LN fusions are suspect.
// ---------------------------------------------------------------------------

#define kH 128
#define kT 200
#define kBATCH 128
#define kM (kBATCH * kT)         // 25600 tokens
#define kITEMS 100000
#define kROWS 100000
#define kNNZ 1600000
#define kNEG_INF (-__builtin_huge_valf())

typedef short s16x8 __attribute__((ext_vector_type(8)));
typedef __bf16 b16x8 __attribute__((ext_vector_type(8)));
typedef float f32x4 __attribute__((ext_vector_type(4)));

static __device__ __forceinline__ short f2bf(float f) {
    unsigned u = __float_as_uint(f);
    unsigned r = (u + 0x7FFFu + ((u >> 16) & 1u)) >> 16;
    return (short)r;
}
static __device__ __forceinline__ f32x4 mfma16(s16x8 a, s16x8 b, f32x4 c) {
    return __builtin_amdgcn_mfma_f32_16x16x32_bf16(
        __builtin_bit_cast(b16x8, a), __builtin_bit_cast(b16x8, b), c, 0, 0, 0);
}

// ======================= CSR build + smooth ================================
__global__ void flag_kernel(const int* __restrict__ ids, unsigned char* __restrict__ flags)
{
    flags[ids[blockIdx.x * 256 + threadIdx.x]] = 1;
}

__global__ void rowlist_kernel(const unsigned char* __restrict__ flags,
                               int* __restrict__ rowlist, int* __restrict__ nflag)
{
    const int r = blockIdx.x * 256 + threadIdx.x;
    if (r < kROWS && flags[r]) rowlist[atomicAdd(nflag, 1)] = r;
}

__global__ void count4_kernel(const int* __restrict__ idx,
                              const unsigned char* __restrict__ flags,
                              int* __restrict__ counts)
{
    const int j4 = (blockIdx.x * 256 + threadIdx.x) * 4;
    if (j4 >= kNNZ) return;
    const int4 r = *reinterpret_cast<const int4*>(&idx[j4]);
    if (flags[r.x]) atomicAdd(&counts[r.x], 1);
    if (flags[r.y]) atomicAdd(&counts[r.y], 1);
    if (flags[r.z]) atomicAdd(&counts[r.z], 1);
    if (flags[r.w]) atomicAdd(&counts[r.w], 1);
}

__global__ __launch_bounds__(256) void scan_pass1(const int* __restrict__ counts,
                                                  int* __restrict__ partial)
{
    const int t = threadIdx.x;
    const int base = blockIdx.x * 1024;
    int s = 0;
#pragma unroll
    for (int i = 0; i < 4; ++i) {
        const int g = base + t + i * 256;
        if (g < kROWS) s += counts[g];
    }
    __shared__ int sd[256];
    sd[t] = s; __syncthreads();
    for (int off = 128; off > 0; off >>= 1) {
        if (t < off) sd[t] += sd[t + off];
        __syncthreads();
    }
    if (t == 0) partial[blockIdx.x] = sd[0];
}

__global__ void scan_pass2(int* __restrict__ partial, int nblk)
{
    const int t = threadIdx.x;          // 128 threads
    __shared__ int sd[128];
    const int v = (t < nblk) ? partial[t] : 0;
    sd[t] = v; __syncthreads();
    for (int off = 1; off < 128; off <<= 1) {
        const int a = (t >= off) ? sd[t - off] : 0;
        __syncthreads();
        sd[t] += a;
        __syncthreads();
    }
    if (t < nblk) partial[t] = sd[t] - v;   // exclusive
}

__global__ __launch_bounds__(256) void scan_pass3(const int* __restrict__ counts,
                                                  const int* __restrict__ partial,
                                                  int* __restrict__ offsets,
                                                  int* __restrict__ cursor)
{
    const int t = threadIdx.x;
    const int base = blockIdx.x * 1024;
    int c[4]; int s = 0;
#pragma unroll
    for (int i = 0; i < 4; ++i) {
        const int g = base + t * 4 + i;
        c[i] = (g < kROWS) ? counts[g] : 0;
        s += c[i];
    }
    __shared__ int sd[256];
    sd[t] = s; __syncthreads();
    for (int off = 1; off < 256; off <<= 1) {
        const int a = (t >= off) ? sd[t - off] : 0;
        __syncthreads();
        sd[t] += a;
        __syncthreads();
    }
    int run = partial[blockIdx.x] + sd[t] - s;
#pragma unroll
    for (int i = 0; i < 4; ++i) {
        const int g = base + t * 4 + i;
        if (g < kROWS) {
            offsets[g] = run;
            cursor[g] = run;
            run += c[i];
            if (g == kROWS - 1) offsets[kROWS] = run;
        }
    }
}

__global__ void scatter4_kernel(const int* __restrict__ idx, const float* __restrict__ val,
                                const unsigned char* __restrict__ flags,
                                int* __restrict__ cursor, int2* __restrict__ edges)
{
    const int j4 = (blockIdx.x * 256 + threadIdx.x) * 4;
    if (j4 >= kNNZ) return;
    const int4 r = *reinterpret_cast<const int4*>(&idx[j4]);
    const int4 c = *reinterpret_cast<const int4*>(&idx[kNNZ + j4]);
    const float4 v = *reinterpret_cast<const float4*>(&val[j4]);
    if (flags[r.x]) edges[atomicAdd(&cursor[r.x], 1)] = make_int2(c.x, __float_as_int(v.x));
    if (flags[r.y]) edges[atomicAdd(&cursor[r.y], 1)] = make_int2(c.y, __float_as_int(v.y));
    if (flags[r.z]) edges[atomicAdd(&cursor[r.z], 1)] = make_int2(c.z, __float_as_int(v.z));
    if (flags[r.w]) edges[atomicAdd(&cursor[r.w], 1)] = make_int2(c.w, __float_as_int(v.w));
}

// per flagged row (compacted list): acc = sum val*emb[col]; sm = 1.5*emb + l2n(acc)/2
__global__ __launch_bounds__(256) void smooth_kernel(
    const int2* __restrict__ edges, const int* __restrict__ offsets,
    const int* __restrict__ rowlist, const int* __restrict__ nflag,
    const float* __restrict__ emb, float* __restrict__ sm)
{
    const int ri = blockIdx.x * 4 + (threadIdx.x >> 6);
    const int lane = threadIdx.x & 63;
    if (ri >= nflag[0]) return;
    const int row = rowlist[ri];
    const int lo = offsets[row], hi = offsets[row + 1];
    float a0 = 0.f, a1 = 0.f;
    int e = lo;
    for (; e + 4 <= hi; e += 4) {
        const int2 e0 = edges[e],     e1 = edges[e + 1];
        const int2 e2 = edges[e + 2], e3 = edges[e + 3];
        const float2 u0 = *reinterpret_cast<const float2*>(&emb[(size_t)e0.x * kH + 2 * lane]);
        const float2 u1 = *reinterpret_cast<const float2*>(&emb[(size_t)e1.x * kH + 2 * lane]);
        const float2 u2 = *reinterpret_cast<const float2*>(&emb[(size_t)e2.x * kH + 2 * lane]);
        const float2 u3 = *reinterpret_cast<const float2*>(&emb[(size_t)e3.x * kH + 2 * lane]);
        const float v0 = __int_as_float(e0.y), v1 = __int_as_float(e1.y);
        const float v2 = __int_as_float(e2.y), v3 = __int_as_float(e3.y);
        a0 = fmaf(v0, u0.x, a0); a1 = fmaf(v0, u0.y, a1);
        a0 = fmaf(v1, u1.x, a0); a1 = fmaf(v1, u1.y, a1);
        a0 = fmaf(v2, u2.x, a0); a1 = fmaf(v2, u2.y, a1);
        a0 = fmaf(v3, u3.x, a0); a1 = fmaf(v3, u3.y, a1);
    }
    for (; e < hi; ++e) {
        const int2 ed = edges[e];
        const float2 u = *reinterpret_cast<const float2*>(&emb[(size_t)ed.x * kH + 2 * lane]);
        const float v = __int_as_float(ed.y);
        a0 = fmaf(v, u.x, a0); a1 = fmaf(v, u.y, a1);
    }
    float s = a0 * a0 + a1 * a1;
#pragma unroll
    for (int off = 1; off < 64; off <<= 1) s += __shfl_xor(s, off);
    const float inv = 0.5f / fmaxf(sqrtf(s), 1e-12f);
    const float2 us = *reinterpret_cast<const float2*>(&emb[(size_t)row * kH + 2 * lane]);
    float2 o;
    o.x = 1.5f * us.x + a0 * inv;
    o.y = 1.5f * us.y + a1 * inv;
    *reinterpret_cast<float2*>(&sm[(size_t)row * kH + 2 * lane]) = o;
}

__global__ void gather_kernel(const int* __restrict__ ids, const float* __restrict__ sm,
                              float* __restrict__ seqs)
{
    const int tok = blockIdx.x * 2 + (threadIdx.x >> 7);
    const int c = threadIdx.x & 127;
    seqs[(size_t)tok * kH + c] = sm[(size_t)ids[tok] * kH + c];
}

// temb += p; seqs = keep ? seqs+p : 0; gates = sigmoid(temb@gW + gb). 1 wave/token.
__global__ __launch_bounds__(256) void posmg_kernel(
    const int* __restrict__ ids, const int* __restrict__ pos,
    const float* __restrict__ pemb, const float* __restrict__ gW,
    const float* __restrict__ gb, float* __restrict__ seqs,
    float* __restrict__ temb, float* __restrict__ gates)
{
    const int tok = blockIdx.x * 4 + (threadIdx.x >> 6);
    const int lane = threadIdx.x & 63;
    const int pp = pos[tok];
    const float p0 = pemb[(size_t)pp * kH + lane];
    const float p1 = pemb[(size_t)pp * kH + 64 + lane];
    const size_t o = (size_t)tok * kH;
    const float t0 = temb[o + lane] + p0;
    const float t1 = temb[o + 64 + lane] + p1;
    temb[o + lane] = t0;
    temb[o + 64 + lane] = t1;
    const bool keep = ids[tok] != kITEMS - 1;
    seqs[o + lane]      = keep ? seqs[o + lane] + p0      : 0.f;
    seqs[o + 64 + lane] = keep ? seqs[o + 64 + lane] + p1 : 0.f;
#pragma unroll
    for (int i = 0; i < 2; ++i) {
        float g = t0 * gW[lane * 2 + i] + t1 * gW[(64 + lane) * 2 + i];
#pragma unroll
        for (int off = 1; off < 64; off <<= 1) g += __shfl_xor(g, off);
        if (lane == 0) gates[tok * 2 + i] = 1.f / (1.f + expf(-(g + gb[i])));
    }
}

// ======================= misc small kernels ================================
__global__ void build_x_kernel(
    const int* __restrict__ itv, const int* __restrict__ tt,
    const float* __restrict__ interval_table, const float* __restrict__ time_table,
    float* __restrict__ x)
{
    const int tok = blockIdx.x * 2 + (threadIdx.x >> 7);
    const int c = threadIdx.x & 127;
    const int t = itv[tok];
    int idx = (int)floorf(log2f((float)t + 1.0f));
    idx = idx < 0 ? 0 : (idx > 30 ? 30 : idx);
    x[(size_t)tok * kH + c] = interval_table[idx * kH + c] + time_table[(size_t)tt[tok] * kH + c];
}

__global__ void wt_kernel(const float* __restrict__ in, short* __restrict__ out,
                          int kLog, int nLog)
{
    const int i = blockIdx.x * 256 + threadIdx.x;
    const int knLog = kLog + nLog;
    const int b = i >> knLog;
    const int rem = i & ((1 << knLog) - 1);
    const int n = rem >> kLog;
    const int k = rem & ((1 << kLog) - 1);
    out[i] = f2bf(in[((size_t)b << knLog) + ((size_t)k << nLog) + n]);
}

__global__ __launch_bounds__(256) void ln_wave(
    const float* __restrict__ in, float* __restrict__ out,
    const float* __restrict__ g, const float* __restrict__ bb, float eps)
{
    const int tok = blockIdx.x * 4 + (threadIdx.x >> 6);
    const int lane = threadIdx.x & 63;
    const float x0 = in[(size_t)tok * kH + lane];
    const float x1 = in[(size_t)tok * kH + 64 + lane];
    float s1 = x0 + x1, s2 = x0 * x0 + x1 * x1;
#pragma unroll
    for (int off = 1; off < 64; off <<= 1) {
        s1 += __shfl_xor(s1, off);
        s2 += __shfl_xor(s2, off);
    }
    const float mean = s1 * (1.f / 128.f);
    float var = s2 * (1.f / 128.f) - mean * mean;
    var = fmaxf(var, 0.f);
    const float r = rsqrtf(var + eps);
    out[(size_t)tok * kH + lane]      = (x0 - mean) * r * g[lane]      + bb[lane];
    out[(size_t)tok * kH + 64 + lane] = (x1 - mean) * r * g[64 + lane] + bb[64 + lane];
}

// ======================= bf16 MFMA GEMM (round-4 proven) ===================
static __device__ __forceinline__ void gemm_body(
    const float* __restrict__ A, const float* __restrict__ A2,
    const short* __restrict__ BT, const float* __restrict__ bias,
    float* __restrict__ C, int M, int N, int K, int relu, int accum,
    const int* __restrict__ mask_ids)
{
    __shared__ short As[128 * 128];
    __shared__ short Bs[128 * 128];
    const int tid = threadIdx.x;
    const int lane = tid & 63;
    const int w = tid >> 6;
    const int rowBase = blockIdx.y * 128;
    const int colBase = blockIdx.x * 128;
    f32x4 acc[2][8] = {};

    for (int k0 = 0; k0 < K; k0 += 128) {
#pragma unroll
        for (int p = 0; p < 8; ++p) {
            const int chunk = p * 256 + tid;
            const int r = chunk >> 4;
            const int kc = chunk & 15;
            const int byteoff = (r * 256 + kc * 16) ^ ((r & 7) << 4);
            {
                const float* src = &A[(size_t)(rowBase + r) * K + k0 + kc * 8];
                float4 a0 = *reinterpret_cast<const float4*>(src);
                float4 a1 = *reinterpret_cast<const float4*>(src + 4);
                if (A2) {
                    const float* s2 = &A2[(size_t)(rowBase + r) * K + k0 + kc * 8];
                    float4 b0 = *reinterpret_cast<const float4*>(s2);
                    float4 b1 = *reinterpret_cast<const float4*>(s2 + 4);
                    a0.x += b0.x; a0.y += b0.y; a0.z += b0.z; a0.w += b0.w;
                    a1.x += b1.x; a1.y += b1.y; a1.z += b1.z; a1.w += b1.w;
                }
                s16x8 v;
                v[0] = f2bf(a0.x); v[1] = f2bf(a0.y); v[2] = f2bf(a0.z); v[3] = f2bf(a0.w);
                v[4] = f2bf(a1.x); v[5] = f2bf(a1.y); v[6] = f2bf(a1.z); v[7] = f2bf(a1.w);
                *reinterpret_cast<s16x8*>(reinterpret_cast<char*>(As) + byteoff) = v;
            }
            {
                const s16x8 v = *reinterpret_cast<const s16x8*>(
                    &BT[(size_t)(colBase + r) * K + k0 + kc * 8]);
                *reinterpret_cast<s16x8*>(reinterpret_cast<char*>(Bs) + byteoff) = v;
            }
        }
        __syncthreads();
#pragma unroll
        for (int kk = 0; kk < 4; ++kk) {
            const int kb = (kk * 32 + (lane >> 4) * 8) * 2;
            s16x8 af[2];
#pragma unroll
            for (int mi = 0; mi < 2; ++mi) {
                const int r = w * 32 + mi * 16 + (lane & 15);
                af[mi] = *reinterpret_cast<const s16x8*>(
                    reinterpret_cast<const char*>(As) + ((r * 256 + kb) ^ ((r & 7) << 4)));
            }
#pragma unroll
            for (int nj = 0; nj < 8; ++nj) {
                const int r = nj * 16 + (lane & 15);
                const s16x8 bf = *reinterpret_cast<const s16x8*>(
                    reinterpret_cast<const char*>(Bs) + ((r * 256 + kb) ^ ((r & 7) << 4)));
#pragma unroll
                for (int mi = 0; mi < 2; ++mi)
                    acc[mi][nj] = mfma16(af[mi], bf, acc[mi][nj]);
            }
        }
        __syncthreads();
    }
#pragma unroll
    for (int mi = 0; mi < 2; ++mi) {
        const int rowb = rowBase + w * 32 + mi * 16 + (lane >> 4) * 4;
#pragma unroll
        for (int nj = 0; nj < 8; ++nj) {
            const int col = colBase + nj * 16 + (lane & 15);
            const float bc = bias[col];
            f32x4 v = acc[mi][nj];
#pragma unroll
            for (int r = 0; r < 4; ++r) {
                const int row = rowb + r;
                float x = v[r] + bc;
                if (relu) x = fmaxf(x, 0.f);
                const size_t off = (size_t)row * N + col;
                if (accum) x += C[off];
                if (mask_ids && mask_ids[row] == kITEMS - 1) x = 0.f;
                C[off] = x;
            }
        }
    }
}

__global__ __launch_bounds__(256) void gemm_bf16(
    const float* __restrict__ A, const float* __restrict__ A2,
    const short* __restrict__ BT, const float* __restrict__ bias,
    float* __restrict__ C, int M, int N, int K, int relu, int accum,
    const int* __restrict__ mask_ids)
{
    gemm_body(A, A2, BT, bias, C, M, N, K, relu, accum, mask_ids);
}

__global__ __launch_bounds__(256) void gemm_qkv(
    const float* __restrict__ Aq, const float* __restrict__ Ak,
    const float* __restrict__ Av, const float* __restrict__ Av2,
    const short* __restrict__ WT, int wo,
    const float* __restrict__ bq, const float* __restrict__ bk, const float* __restrict__ bv,
    float* __restrict__ Cq, float* __restrict__ Ck, float* __restrict__ Cv)
{
    const int z = blockIdx.z;
    const float* A  = (z == 0) ? Aq : (z == 1) ? Ak : Av;
    const float* A2 = (z == 2) ? Av2 : nullptr;
    const short* B  = WT + (size_t)z * 6 * 16384 + (size_t)wo * 16384;
    const float* bias = (z == 0) ? bq : (z == 1) ? bk : bv;
    float* C = (z == 0) ? Cq : (z == 1) ? Ck : Cv;
    gemm_body(A, A2, B, bias, C, kM, kH, kH, 0, 0, nullptr);
}

// ======================= MFMA flash attention (round-4 proven) =============
#define aNT 13            // 16-row tiles covering 200 (pad 208)
#define aVS 232           // Vt / P row stride in bf16

__global__ __launch_bounds__(256) void attn_mfma(
    const float* __restrict__ qp, const float* __restrict__ kp,
    const float* __restrict__ vp, const float* __restrict__ gates,
    const int gi, const float* __restrict__ resid, float* __restrict__ outp)
{
    __shared__ short klds[200 * 64];
    __shared__ short vt[64 * aVS];
    __shared__ short pl[4][16 * aVS];
    __shared__ float glds[224];
    const int bid = (int)blockIdx.x;
    const int b = bid >> 1, h = bid & 1, hoff = h * 64;
    const int tid = threadIdx.x, lane = tid & 63, wv = tid >> 6;
    const size_t base = (size_t)b * kT * kH;

    for (int i = tid; i < 1600; i += 256) {
        const int r = i >> 3, c8 = i & 7;
        const float* src = &kp[base + (size_t)r * kH + hoff + c8 * 8];
        const float4 a0 = *reinterpret_cast<const float4*>(src);
        const float4 a1 = *reinterpret_cast<const float4*>(src + 4);
        s16x8 v;
        v[0] = f2bf(a0.x); v[1] = f2bf(a0.y); v[2] = f2bf(a0.z); v[3] = f2bf(a0.w);
        v[4] = f2bf(a1.x); v[5] = f2bf(a1.y); v[6] = f2bf(a1.z); v[7] = f2bf(a1.w);
        *reinterpret_cast<s16x8*>(reinterpret_cast<char*>(klds) +
            ((r * 128 + c8 * 16) ^ ((r & 7) << 4))) = v;
    }
    for (int i = tid; i < 6400; i += 256) {
        const int k2 = i >> 6, d = i & 63;
        const float v0 = vp[base + (size_t)(2 * k2) * kH + hoff + d];
        const float v1 = vp[base + (size_t)(2 * k2 + 1) * kH + hoff + d];
        const unsigned pk = (unsigned)(unsigned short)f2bf(v0)
                          | ((unsigned)(unsigned short)f2bf(v1) << 16);
        *reinterpret_cast<unsigned*>(reinterpret_cast<char*>(vt) + d * (aVS * 2) + k2 * 4) = pk;
    }
    for (int i = tid; i < 1024; i += 256) {
        const int d = i >> 4, k2 = 100 + (i & 15);
        *reinterpret_cast<unsigned*>(reinterpret_cast<char*>(vt) + d * (aVS * 2) + k2 * 4) = 0;
    }
    if (tid < 224) glds[tid] = (tid < 200) ? gates[(b * kT + tid) * 2 + gi] : 0.f;
    for (int i = lane; i < 16 * aVS / 2; i += 64)
        reinterpret_cast<unsigned*>(pl[wv])[i] = 0u;
    __syncthreads();

    const int c = lane & 15, hi = lane >> 4;
    const float scale = 0.125f;

    for (int qt = wv; qt < aNT; qt += 4) {
        s16x8 aq0, aq1;
        {
            const float* s0 = &qp[base + (size_t)(qt * 16 + c) * kH + hoff + hi * 8];
            const float4 a0 = *reinterpret_cast<const float4*>(s0);
            const float4 a1 = *reinterpret_cast<const float4*>(s0 + 4);
            const float4 b0 = *reinterpret_cast<const float4*>(s0 + 32);
            const float4 b1 = *reinterpret_cast<const float4*>(s0 + 36);
            aq0[0] = f2bf(a0.x); aq0[1] = f2bf(a0.y); aq0[2] = f2bf(a0.z); aq0[3] = f2bf(a0.w);
            aq0[4] = f2bf(a1.x); aq0[5] = f2bf(a1.y); aq0[6] = f2bf(a1.z); aq0[7] = f2bf(a1.w);
            aq1[0] = f2bf(b0.x); aq1[1] = f2bf(b0.y); aq1[2] = f2bf(b0.z); aq1[3] = f2bf(b0.w);
            aq1[4] = f2bf(b1.x); aq1[5] = f2bf(b1.y); aq1[6] = f2bf(b1.z); aq1[7] = f2bf(b1.w);
        }
        f32x4 sc[aNT];
#pragma unroll
        for (int kt = 0; kt < aNT; ++kt) {
            if (kt > qt) continue;
            const int krow = kt * 16 + c;
            const int sw = (krow & 7) << 4;
            const s16x8 bk0 = *reinterpret_cast<const s16x8*>(
                reinterpret_cast<const char*>(klds) + ((krow * 128 + hi * 16) ^ sw));
            const s16x8 bk1 = *reinterpret_cast<const s16x8*>(
                reinterpret_cast<const char*>(klds) + ((krow * 128 + 64 + hi * 16) ^ sw));
            f32x4 s = {0.f, 0.f, 0.f, 0.f};
            s = mfma16(aq0, bk0, s);
            s = mfma16(aq1, bk1, s);
            sc[kt] = s;
        }
        float gq[4], m[4], ps[4];
#pragma unroll
        for (int r = 0; r < 4; ++r) {
            gq[r] = glds[qt * 16 + hi * 4 + r];
            m[r] = kNEG_INF; ps[r] = 0.f;
        }
#pragma unroll
        for (int kt = 0; kt < aNT; ++kt) {
            if (kt > qt) continue;
            const int col = kt * 16 + c;
            const float gk = glds[col] * scale;
#pragma unroll
            for (int r = 0; r < 4; ++r) {
                const int row = qt * 16 + hi * 4 + r;
                const float v = (col <= row && col < 200) ? sc[kt][r] * gq[r] * gk : kNEG_INF;
                sc[kt][r] = v;
                m[r] = fmaxf(m[r], v);
            }
        }
#pragma unroll
        for (int r = 0; r < 4; ++r)
#pragma unroll
            for (int off = 1; off < 16; off <<= 1)
                m[r] = fmaxf(m[r], __shfl_xor(m[r], off));
#pragma unroll
        for (int kt = 0; kt < aNT; ++kt) {
            if (kt > qt) continue;
#pragma unroll
            for (int r = 0; r < 4; ++r) {
                const float p = __expf(sc[kt][r] - m[r]);
                ps[r] += p;
                *reinterpret_cast<short*>(reinterpret_cast<char*>(pl[wv]) +
                    ((hi * 4 + r) * aVS + kt * 16 + c) * 2) = f2bf(p);
            }
        }
#pragma unroll
        for (int r = 0; r < 4; ++r)
#pragma unroll
            for (int off = 1; off < 16; off <<= 1)
                ps[r] += __shfl_xor(ps[r], off);
        f32x4 oacc[4] = {};
        const int nch = (qt + 2) >> 1;
#pragma unroll
        for (int ks = 0; ks < 7; ++ks) {
            if (ks >= nch) continue;
            const s16x8 pa = *reinterpret_cast<const s16x8*>(
                reinterpret_cast<const char*>(pl[wv]) + (c * aVS + ks * 32 + hi * 8) * 2);
#pragma unroll
            for (int n = 0; n < 4; ++n) {
                const s16x8 bv = *reinterpret_cast<const s16x8*>(
                    reinterpret_cast<const char*>(vt) + ((n * 16 + c) * aVS + ks * 32 + hi * 8) * 2);
                oacc[n] = mfma16(pa, bv, oacc[n]);
            }
        }
#pragma unroll
        for (int r = 0; r < 4; ++r) {
            const int row = qt * 16 + hi * 4 + r;
            if (row < 200) {
                const float inv = 1.f / ps[r];
#pragma unroll
                for (int n = 0; n < 4; ++n) {
                    const size_t off = base + (size_t)row * kH + hoff + n * 16 + c;
                    outp[off] = resid[off] + oacc[n][r] * inv;
                }
            }
        }
    }
}

// ---------------------------------------------------------------------------
extern "C" void kernel_launch(void* const* d_in, const int* in_sizes, int n_in,
                              void* d_out, int out_size, void* d_ws, size_t ws_size,
                              hipStream_t stream)
{
    const int* ids_o = (const int*)d_in[0];
    const int* ids_x = (const int*)d_in[1];
    const int* ids_y = (const int*)d_in[2];
    const int* pos_o = (const int*)d_in[3];
    const int* pos_x = (const int*)d_in[4];
    const int* pos_y = (const int*)d_in[5];
    const int* tm_o  = (const int*)d_in[6];
    const int* tm_x  = (const int*)d_in[7];
    const int* tm_y  = (const int*)d_in[8];
    const int* itv_x = (const int*)d_in[9];
    const int* itv_y = (const int*)d_in[10];
    const int* itv_o = (const int*)d_in[11];
    const float* embX = (const float*)d_in[12];
    const float* embY = (const float*)d_in[13];
    const float* embO = (const float*)d_in[14];
    const float* time_table = (const float*)d_in[15];
    const float* interval_table = (const float*)d_in[16];
    const int* adj_idx  = (const int*)d_in[17];
    const float* adj_val = (const float*)d_in[18];
    const int* adjs_idx  = (const int*)d_in[19];
    const float* adjs_val = (const float*)d_in[20];
    const float* mlp_W1 = (const float*)d_in[21];
    const float* mlp_b1 = (const float*)d_in[22];
    const float* mlp_W2 = (const float*)d_in[23];
    const float* mlp_b2 = (const float*)d_in[24];
    const float* mlp_lng = (const float*)d_in[25];
    const float* mlp_lnb = (const float*)d_in[26];
    const float* pos_emb = (const float*)d_in[27];
    const float* gate_W = (const float*)d_in[28];
    const float* gate_b = (const float*)d_in[29];
    const float* aln_g = (const float*)d_in[30];
    const float* aln_b = (const float*)d_in[31];
    const float* qW = (const float*)d_in[32];
    const float* kW = (const float*)d_in[33];
    const float* vW = (const float*)d_in[34];
    const float* c1W = (const float*)d_in[35];
    const float* c2W = (const float*)d_in[36];
    const float* qb = (const float*)d_in[37];
    const float* kb = (const float*)d_in[38];
    const float* vb = (const float*)d_in[39];
    const float* c1b = (const float*)d_in[40];
    const float* c2b = (const float*)d_in[41];
    const float* fln_g = (const float*)d_in[42];
    const float* fln_b = (const float*)d_in[43];
    const float* lln_g = (const float*)d_in[44];
    const float* lln_b = (const float*)d_in[45];

    float* out = (float*)d_out;
    float* ws = (float*)d_ws;

    // ---- workspace layout (floats) ----
    const size_t SZ_TOK = (size_t)kM * kH;        // 3,276,800
    float* BIG  = ws;                              // SMOOTH (12.8M) / hidden (13.1M)
    float* XBUF = BIG  + 13107200;                 // build_x / Q / FFN hidden
    float* TEMB = XBUF + SZ_TOK;
    float* SEQS = TEMB + SZ_TOK;
    float* QBUF = SEQS + SZ_TOK;
    float* KP   = QBUF + SZ_TOK;                   // aliased: EDGES during CSR phase
    float* VP   = KP   + SZ_TOK;
    float* GATES = VP  + SZ_TOK;                   // 51,200 floats
    short* WT = (short*)(GATES + 51200);           // 884,736 bf16
    short* qWT = WT;
    short* c1WT = WT + 3 * 6 * 16384;
    short* c2WT = c1WT + 6 * 16384;
    short* w1T = c2WT + 6 * 16384;                 // 3 x 512x128
    short* w2T = w1T + 3 * 65536;                  // 3 x 128x512
    int* COUNTS = (int*)(WT + 884736);
    int* OFFS   = COUNTS + kROWS;                  // kROWS+1
    int* CURS   = OFFS + kROWS + 1;
    int* PART   = CURS + kROWS;                    // 256
    int* ROWLIST = PART + 256;                     // 25600
    int* NFLAG  = ROWLIST + 25600;                 // 16 (1 used)
    unsigned char* FLAGS = (unsigned char*)(NFLAG + 16);   // 100,000 B
    int2* EDGES = (int2*)KP;                       // flagged edges <= 12.8MB

    const size_t needed = (size_t)(13107200 + 7 * 3276800 + 51200) * 4
                        + (size_t)884736 * 2
                        + (size_t)(3 * kROWS + 1 + 256 + 25600 + 16) * 4
                        + kROWS + 4096;
    if (ws_size < needed) return;

    // ---- one-time weight transpose/convert ----
    wt_kernel<<<6 * 16384 / 256, 256, 0, stream>>>(qW, qWT, 7, 7);
    wt_kernel<<<6 * 16384 / 256, 256, 0, stream>>>(kW, qWT + 6 * 16384, 7, 7);
    wt_kernel<<<6 * 16384 / 256, 256, 0, stream>>>(vW, qWT + 12 * 16384, 7, 7);
    wt_kernel<<<6 * 16384 / 256, 256, 0, stream>>>(c1W, c1WT, 7, 7);
    wt_kernel<<<6 * 16384 / 256, 256, 0, stream>>>(c2W, c2WT, 7, 7);
    wt_kernel<<<3 * 65536 / 256, 256, 0, stream>>>(mlp_W1, w1T, 7, 9);
    wt_kernel<<<3 * 65536 / 256, 256, 0, stream>>>(mlp_W2, w2T, 9, 7);

    struct Enc {
        const int* ids; const int* pos; const int* tm; const int* itv;
        const float* emb; const int* a_idx; const float* a_val; int mi;
    };
    const Enc encs[3] = {
        { ids_o, pos_o, tm_o, itv_o, embO, adj_idx,  adj_val,  2 },
        { ids_x, pos_x, tm_x, itv_x, embX, adjs_idx, adjs_val, 0 },
        { ids_y, pos_y, tm_y, itv_y, embY, adjs_idx, adjs_val, 1 },
    };

    const int g4 = (kNNZ / 4 + 255) / 256;   // 1563

    for (int e = 0; e < 3; ++e) {
        const Enc& E = encs[e];
        // ---- CSR build + smoothed rows (compacted, f32) ----
        hipMemsetAsync(FLAGS, 0, kROWS, stream);
        hipMemsetAsync(COUNTS, 0, kROWS * sizeof(int), stream);
        hipMemsetAsync(NFLAG, 0, sizeof(int), stream);
        flag_kernel<<<kM / 256, 256, 0, stream>>>(E.ids, FLAGS);
        rowlist_kernel<<<(kROWS + 255) / 256, 256, 0, stream>>>(FLAGS, ROWLIST, NFLAG);
        count4_kernel<<<g4, 256, 0, stream>>>(E.a_idx, FLAGS, COUNTS);
        scan_pass1<<<98, 256, 0, stream>>>(COUNTS, PART);
        scan_pass2<<<1, 128, 0, stream>>>(PART, 98);
        scan_pass3<<<98, 256, 0, stream>>>(COUNTS, PART, OFFS, CURS);
        scatter4_kernel<<<g4, 256, 0, stream>>>(E.a_idx, E.a_val, FLAGS, CURS, EDGES);
        smooth_kernel<<<6400, 256, 0, stream>>>(EDGES, OFFS, ROWLIST, NFLAG, E.emb, BIG);
        gather_kernel<<<kM / 2, 256, 0, stream>>>(E.ids, BIG, SEQS);
        // ---- temb = LN(MLP(interval_emb + time_emb)) (round-4 path) ----
        build_x_kernel<<<kM / 2, 256, 0, stream>>>(E.itv, E.tm, interval_table, time_table, XBUF);
        gemm_bf16<<<dim3(4, kM / 128), 256, 0, stream>>>(
            XBUF, nullptr, w1T + (size_t)E.mi * 65536, mlp_b1 + E.mi * 512, BIG,
            kM, 512, kH, 1, 0, nullptr);
        gemm_bf16<<<dim3(1, kM / 128), 256, 0, stream>>>(
            BIG, nullptr, w2T + (size_t)E.mi * 65536, mlp_b2 + E.mi * kH, TEMB,
            kM, kH, 512, 0, 0, nullptr);
        ln_wave<<<kM / 4, 256, 0, stream>>>(TEMB, TEMB, mlp_lng + E.mi * kH, mlp_lnb + E.mi * kH, 1e-5f);
        // ---- +pos / mask / gates (merged) ----
        posmg_kernel<<<kM / 4, 256, 0, stream>>>(
            E.ids, E.pos, pos_emb + (size_t)e * kT * kH,
            gate_W + e * kH * 2, gate_b + e * 2, SEQS, TEMB, GATES);
        // ---- 2 attention blocks (round-4 path) ----
        for (int i = 0; i < 2; ++i) {
            const int wo = e * 2 + i;
            ln_wave<<<kM / 4, 256, 0, stream>>>(SEQS, QBUF, aln_g + wo * kH, aln_b + wo * kH, 1e-8f);
            gemm_qkv<<<dim3(1, kM / 128, 3), 256, 0, stream>>>(
                QBUF, TEMB, SEQS, TEMB, qWT, wo,
                qb + wo * kH, kb + wo * kH, vb + wo * kH,
                XBUF, KP, VP);
            attn_mfma<<<kBATCH * 2, 256, 0, stream>>>(XBUF, KP, VP, GATES, i, QBUF, SEQS);
            ln_wave<<<kM / 4, 256, 0, stream>>>(SEQS, SEQS, fln_g + wo * kH, fln_b + wo * kH, 1e-8f);
            gemm_bf16<<<dim3(1, kM / 128), 256, 0, stream>>>(
                SEQS, nullptr, c1WT + (size_t)wo * 16384, c1b + wo * kH, XBUF, kM, kH, kH, 1, 0, nullptr);
            gemm_bf16<<<dim3(1, kM / 128), 256, 0, stream>>>(
                XBUF, nullptr, c2WT + (size_t)wo * 16384, c2b + wo * kH, SEQS, kM, kH, kH, 0, 1, E.ids);
        }
        ln_wave<<<kM / 4, 256, 0, stream>>>(SEQS, out + (size_t)e * SZ_TOK, lln_g + e * kH, lln_b + e * kH, 1e-8f);
    }
}

// Round 9
// 1250.681 us; speedup vs baseline: 4.0323x; 1.0422x over previous
//
#include <hip/hip_runtime.h>
#include <math.h>

// ---------------------------------------------------------------------------
// TACDSR forward — round 9: r8's epilogue-LN fusions with the BIG-clobber bug
// fixed (gather restored before W1 reuses BIG as the MLP hidden buffer).
// ---------------------------------------------------------------------------

#define kH 128
#define kT 200
#define kBATCH 128
#define kM (kBATCH * kT)         // 25600 tokens
#define kITEMS 100000
#define kROWS 100000
#define kNNZ 1600000
#define kNEG_INF (-__builtin_huge_valf())

typedef short s16x8 __attribute__((ext_vector_type(8)));
typedef __bf16 b16x8 __attribute__((ext_vector_type(8)));
typedef float f32x4 __attribute__((ext_vector_type(4)));

static __device__ __forceinline__ short f2bf(float f) {
    unsigned u = __float_as_uint(f);
    unsigned r = (u + 0x7FFFu + ((u >> 16) & 1u)) >> 16;
    return (short)r;
}
static __device__ __forceinline__ f32x4 mfma16(s16x8 a, s16x8 b, f32x4 c) {
    return __builtin_amdgcn_mfma_f32_16x16x32_bf16(
        __builtin_bit_cast(b16x8, a), __builtin_bit_cast(b16x8, b), c, 0, 0, 0);
}

// ======================= CSR build + smooth ================================
__global__ void flag_kernel(const int* __restrict__ ids, unsigned char* __restrict__ flags)
{
    flags[ids[blockIdx.x * 256 + threadIdx.x]] = 1;
}

__global__ void rowlist_kernel(const unsigned char* __restrict__ flags,
                               int* __restrict__ rowlist, int* __restrict__ nflag)
{
    const int r = blockIdx.x * 256 + threadIdx.x;
    if (r < kROWS && flags[r]) rowlist[atomicAdd(nflag, 1)] = r;
}

__global__ void count4_kernel(const int* __restrict__ idx,
                              const unsigned char* __restrict__ flags,
                              int* __restrict__ counts)
{
    const int j4 = (blockIdx.x * 256 + threadIdx.x) * 4;
    if (j4 >= kNNZ) return;
    const int4 r = *reinterpret_cast<const int4*>(&idx[j4]);
    if (flags[r.x]) atomicAdd(&counts[r.x], 1);
    if (flags[r.y]) atomicAdd(&counts[r.y], 1);
    if (flags[r.z]) atomicAdd(&counts[r.z], 1);
    if (flags[r.w]) atomicAdd(&counts[r.w], 1);
}

__global__ __launch_bounds__(256) void scan_pass1(const int* __restrict__ counts,
                                                  int* __restrict__ partial)
{
    const int t = threadIdx.x;
    const int base = blockIdx.x * 1024;
    int s = 0;
#pragma unroll
    for (int i = 0; i < 4; ++i) {
        const int g = base + t + i * 256;
        if (g < kROWS) s += counts[g];
    }
    __shared__ int sd[256];
    sd[t] = s; __syncthreads();
    for (int off = 128; off > 0; off >>= 1) {
        if (t < off) sd[t] += sd[t + off];
        __syncthreads();
    }
    if (t == 0) partial[blockIdx.x] = sd[0];
}

__global__ void scan_pass2(int* __restrict__ partial, int nblk)
{
    const int t = threadIdx.x;          // 128 threads
    __shared__ int sd[128];
    const int v = (t < nblk) ? partial[t] : 0;
    sd[t] = v; __syncthreads();
    for (int off = 1; off < 128; off <<= 1) {
        const int a = (t >= off) ? sd[t - off] : 0;
        __syncthreads();
        sd[t] += a;
        __syncthreads();
    }
    if (t < nblk) partial[t] = sd[t] - v;   // exclusive
}

__global__ __launch_bounds__(256) void scan_pass3(const int* __restrict__ counts,
                                                  const int* __restrict__ partial,
                                                  int* __restrict__ offsets,
                                                  int* __restrict__ cursor)
{
    const int t = threadIdx.x;
    const int base = blockIdx.x * 1024;
    int c[4]; int s = 0;
#pragma unroll
    for (int i = 0; i < 4; ++i) {
        const int g = base + t * 4 + i;
        c[i] = (g < kROWS) ? counts[g] : 0;
        s += c[i];
    }
    __shared__ int sd[256];
    sd[t] = s; __syncthreads();
    for (int off = 1; off < 256; off <<= 1) {
        const int a = (t >= off) ? sd[t - off] : 0;
        __syncthreads();
        sd[t] += a;
        __syncthreads();
    }
    int run = partial[blockIdx.x] + sd[t] - s;
#pragma unroll
    for (int i = 0; i < 4; ++i) {
        const int g = base + t * 4 + i;
        if (g < kROWS) {
            offsets[g] = run;
            cursor[g] = run;
            run += c[i];
            if (g == kROWS - 1) offsets[kROWS] = run;
        }
    }
}

__global__ void scatter4_kernel(const int* __restrict__ idx, const float* __restrict__ val,
                                const unsigned char* __restrict__ flags,
                                int* __restrict__ cursor, int2* __restrict__ edges)
{
    const int j4 = (blockIdx.x * 256 + threadIdx.x) * 4;
    if (j4 >= kNNZ) return;
    const int4 r = *reinterpret_cast<const int4*>(&idx[j4]);
    const int4 c = *reinterpret_cast<const int4*>(&idx[kNNZ + j4]);
    const float4 v = *reinterpret_cast<const float4*>(&val[j4]);
    if (flags[r.x]) edges[atomicAdd(&cursor[r.x], 1)] = make_int2(c.x, __float_as_int(v.x));
    if (flags[r.y]) edges[atomicAdd(&cursor[r.y], 1)] = make_int2(c.y, __float_as_int(v.y));
    if (flags[r.z]) edges[atomicAdd(&cursor[r.z], 1)] = make_int2(c.z, __float_as_int(v.z));
    if (flags[r.w]) edges[atomicAdd(&cursor[r.w], 1)] = make_int2(c.w, __float_as_int(v.w));
}

// per flagged row (compacted list): acc = sum val*emb[col]; sm = 1.5*emb + l2n(acc)/2
__global__ __launch_bounds__(256) void smooth_kernel(
    const int2* __restrict__ edges, const int* __restrict__ offsets,
    const int* __restrict__ rowlist, const int* __restrict__ nflag,
    const float* __restrict__ emb, float* __restrict__ sm)
{
    const int ri = blockIdx.x * 4 + (threadIdx.x >> 6);
    const int lane = threadIdx.x & 63;
    if (ri >= nflag[0]) return;
    const int row = rowlist[ri];
    const int lo = offsets[row], hi = offsets[row + 1];
    float a0 = 0.f, a1 = 0.f;
    int e = lo;
    for (; e + 4 <= hi; e += 4) {
        const int2 e0 = edges[e],     e1 = edges[e + 1];
        const int2 e2 = edges[e + 2], e3 = edges[e + 3];
        const float2 u0 = *reinterpret_cast<const float2*>(&emb[(size_t)e0.x * kH + 2 * lane]);
        const float2 u1 = *reinterpret_cast<const float2*>(&emb[(size_t)e1.x * kH + 2 * lane]);
        const float2 u2 = *reinterpret_cast<const float2*>(&emb[(size_t)e2.x * kH + 2 * lane]);
        const float2 u3 = *reinterpret_cast<const float2*>(&emb[(size_t)e3.x * kH + 2 * lane]);
        const float v0 = __int_as_float(e0.y), v1 = __int_as_float(e1.y);
        const float v2 = __int_as_float(e2.y), v3 = __int_as_float(e3.y);
        a0 = fmaf(v0, u0.x, a0); a1 = fmaf(v0, u0.y, a1);
        a0 = fmaf(v1, u1.x, a0); a1 = fmaf(v1, u1.y, a1);
        a0 = fmaf(v2, u2.x, a0); a1 = fmaf(v2, u2.y, a1);
        a0 = fmaf(v3, u3.x, a0); a1 = fmaf(v3, u3.y, a1);
    }
    for (; e < hi; ++e) {
        const int2 ed = edges[e];
        const float2 u = *reinterpret_cast<const float2*>(&emb[(size_t)ed.x * kH + 2 * lane]);
        const float v = __int_as_float(ed.y);
        a0 = fmaf(v, u.x, a0); a1 = fmaf(v, u.y, a1);
    }
    float s = a0 * a0 + a1 * a1;
#pragma unroll
    for (int off = 1; off < 64; off <<= 1) s += __shfl_xor(s, off);
    const float inv = 0.5f / fmaxf(sqrtf(s), 1e-12f);
    const float2 us = *reinterpret_cast<const float2*>(&emb[(size_t)row * kH + 2 * lane]);
    float2 o;
    o.x = 1.5f * us.x + a0 * inv;
    o.y = 1.5f * us.y + a1 * inv;
    *reinterpret_cast<float2*>(&sm[(size_t)row * kH + 2 * lane]) = o;
}

// seqs[tok] = sm[ids[tok]]  (MUST run before BIG is reused as MLP hidden)
__global__ void gather_kernel(const int* __restrict__ ids, const float* __restrict__ sm,
                              float* __restrict__ seqs)
{
    const int tok = blockIdx.x * 2 + (threadIdx.x >> 7);
    const int c = threadIdx.x & 127;
    seqs[(size_t)tok * kH + c] = sm[(size_t)ids[tok] * kH + c];
}

// posmg v3: temb += p; seqs = keep ? seqs+p : 0; gates; QBUF = aln0_LN(seqs)
__global__ __launch_bounds__(256) void posmg_kernel(
    const int* __restrict__ ids, const int* __restrict__ pos,
    const float* __restrict__ pemb, const float* __restrict__ gW,
    const float* __restrict__ gb,
    float* __restrict__ seqs, float* __restrict__ temb, float* __restrict__ gates,
    const float* __restrict__ alng, const float* __restrict__ alnb,
    float* __restrict__ qbuf)
{
    const int tok = blockIdx.x * 4 + (threadIdx.x >> 6);
    const int lane = threadIdx.x & 63;
    const int pp = pos[tok];
    const float p0 = pemb[(size_t)pp * kH + lane];
    const float p1 = pemb[(size_t)pp * kH + 64 + lane];
    const size_t o = (size_t)tok * kH;
    const float t0 = temb[o + lane] + p0;
    const float t1 = temb[o + 64 + lane] + p1;
    temb[o + lane] = t0;
    temb[o + 64 + lane] = t1;
    const bool keep = ids[tok] != kITEMS - 1;
    const float q0 = keep ? seqs[o + lane] + p0 : 0.f;
    const float q1 = keep ? seqs[o + 64 + lane] + p1 : 0.f;
    seqs[o + lane] = q0;
    seqs[o + 64 + lane] = q1;
#pragma unroll
    for (int i = 0; i < 2; ++i) {
        float g = t0 * gW[lane * 2 + i] + t1 * gW[(64 + lane) * 2 + i];
#pragma unroll
        for (int off = 1; off < 64; off <<= 1) g += __shfl_xor(g, off);
        if (lane == 0) gates[tok * 2 + i] = 1.f / (1.f + expf(-(g + gb[i])));
    }
    // aln0 LN of (q0,q1) across the wave (full 128-elem row)
    float s1 = q0 + q1, s2 = q0 * q0 + q1 * q1;
#pragma unroll
    for (int off = 1; off < 64; off <<= 1) {
        s1 += __shfl_xor(s1, off);
        s2 += __shfl_xor(s2, off);
    }
    const float mean = s1 * (1.f / 128.f);
    float var = s2 * (1.f / 128.f) - mean * mean;
    var = fmaxf(var, 0.f);
    const float rr = rsqrtf(var + 1e-8f);
    qbuf[o + lane]      = (q0 - mean) * rr * alng[lane]      + alnb[lane];
    qbuf[o + 64 + lane] = (q1 - mean) * rr * alng[64 + lane] + alnb[64 + lane];
}

// ======================= misc small kernels ================================
__global__ void build_x_kernel(
    const int* __restrict__ itv, const int* __restrict__ tt,
    const float* __restrict__ interval_table, const float* __restrict__ time_table,
    float* __restrict__ x)
{
    const int tok = blockIdx.x * 2 + (threadIdx.x >> 7);
    const int c = threadIdx.x & 127;
    const int t = itv[tok];
    int idx = (int)floorf(log2f((float)t + 1.0f));
    idx = idx < 0 ? 0 : (idx > 30 ? 30 : idx);
    x[(size_t)tok * kH + c] = interval_table[idx * kH + c] + time_table[(size_t)tt[tok] * kH + c];
}

__global__ void wt_kernel(const float* __restrict__ in, short* __restrict__ out,
                          int kLog, int nLog)
{
    const int i = blockIdx.x * 256 + threadIdx.x;
    const int knLog = kLog + nLog;
    const int b = i >> knLog;
    const int rem = i & ((1 << knLog) - 1);
    const int n = rem >> kLog;
    const int k = rem & ((1 << kLog) - 1);
    out[i] = f2bf(in[((size_t)b << knLog) + ((size_t)k << nLog) + n]);
}

__global__ __launch_bounds__(256) void ln_wave(
    const float* __restrict__ in, float* __restrict__ out,
    const float* __restrict__ g, const float* __restrict__ bb, float eps)
{
    const int tok = blockIdx.x * 4 + (threadIdx.x >> 6);
    const int lane = threadIdx.x & 63;
    const float x0 = in[(size_t)tok * kH + lane];
    const float x1 = in[(size_t)tok * kH + 64 + lane];
    float s1 = x0 + x1, s2 = x0 * x0 + x1 * x1;
#pragma unroll
    for (int off = 1; off < 64; off <<= 1) {
        s1 += __shfl_xor(s1, off);
        s2 += __shfl_xor(s2, off);
    }
    const float mean = s1 * (1.f / 128.f);
    float var = s2 * (1.f / 128.f) - mean * mean;
    var = fmaxf(var, 0.f);
    const float r = rsqrtf(var + eps);
    out[(size_t)tok * kH + lane]      = (x0 - mean) * r * g[lane]      + bb[lane];
    out[(size_t)tok * kH + 64 + lane] = (x1 - mean) * r * g[64 + lane] + bb[64 + lane];
}

// ======================= bf16 MFMA GEMM ====================================
// A: MxK f32 (+A2). BT: NxK bf16. 128x128 tile, 4 waves.
// Epilogue: x = [relu](acc+bias) [+resid] [mask->0]; Craw?store;
// lnOg? LN over row (N==128, gridDim.x==1) -> Cln.
static __device__ __forceinline__ void gemm_body(
    const float* __restrict__ A, const float* __restrict__ A2,
    const short* __restrict__ BT, const float* __restrict__ bias,
    float* __restrict__ Craw, float* __restrict__ Cln,
    const float* __restrict__ resid,
    int N, int K, int relu, const int* __restrict__ mask_ids,
    const float* __restrict__ lnOg, const float* __restrict__ lnOb, float lnOeps)
{
    __shared__ short As[128 * 128];
    __shared__ short Bs[128 * 128];
    const int tid = threadIdx.x;
    const int lane = tid & 63;
    const int w = tid >> 6;
    const int rowBase = blockIdx.y * 128;
    const int colBase = blockIdx.x * 128;
    f32x4 acc[2][8] = {};

    for (int k0 = 0; k0 < K; k0 += 128) {
#pragma unroll
        for (int p = 0; p < 8; ++p) {
            const int chunk = p * 256 + tid;
            const int r = chunk >> 4;
            const int kc = chunk & 15;
            const int byteoff = (r * 256 + kc * 16) ^ ((r & 7) << 4);
            {
                const float* src = &A[(size_t)(rowBase + r) * K + k0 + kc * 8];
                float4 a0 = *reinterpret_cast<const float4*>(src);
                float4 a1 = *reinterpret_cast<const float4*>(src + 4);
                if (A2) {
                    const float* s2 = &A2[(size_t)(rowBase + r) * K + k0 + kc * 8];
                    float4 b0 = *reinterpret_cast<const float4*>(s2);
                    float4 b1 = *reinterpret_cast<const float4*>(s2 + 4);
                    a0.x += b0.x; a0.y += b0.y; a0.z += b0.z; a0.w += b0.w;
                    a1.x += b1.x; a1.y += b1.y; a1.z += b1.z; a1.w += b1.w;
                }
                s16x8 v;
                v[0] = f2bf(a0.x); v[1] = f2bf(a0.y); v[2] = f2bf(a0.z); v[3] = f2bf(a0.w);
                v[4] = f2bf(a1.x); v[5] = f2bf(a1.y); v[6] = f2bf(a1.z); v[7] = f2bf(a1.w);
                *reinterpret_cast<s16x8*>(reinterpret_cast<char*>(As) + byteoff) = v;
            }
            {
                const s16x8 v = *reinterpret_cast<const s16x8*>(
                    &BT[(size_t)(colBase + r) * K + k0 + kc * 8]);
                *reinterpret_cast<s16x8*>(reinterpret_cast<char*>(Bs) + byteoff) = v;
            }
        }
        __syncthreads();
#pragma unroll
        for (int kk = 0; kk < 4; ++kk) {
            const int kb = (kk * 32 + (lane >> 4) * 8) * 2;
            s16x8 af[2];
#pragma unroll
            for (int mi = 0; mi < 2; ++mi) {
                const int r = w * 32 + mi * 16 + (lane & 15);
                af[mi] = *reinterpret_cast<const s16x8*>(
                    reinterpret_cast<const char*>(As) + ((r * 256 + kb) ^ ((r & 7) << 4)));
            }
#pragma unroll
            for (int nj = 0; nj < 8; ++nj) {
                const int r = nj * 16 + (lane & 15);
                const s16x8 bf = *reinterpret_cast<const s16x8*>(
                    reinterpret_cast<const char*>(Bs) + ((r * 256 + kb) ^ ((r & 7) << 4)));
#pragma unroll
                for (int mi = 0; mi < 2; ++mi)
                    acc[mi][nj] = mfma16(af[mi], bf, acc[mi][nj]);
            }
        }
        __syncthreads();
    }
    // epilogue: C/D layout col=lane&15, row=(lane>>4)*4+reg
    const int c = lane & 15, hi = lane >> 4;
#pragma unroll
    for (int mi = 0; mi < 2; ++mi) {
#pragma unroll
        for (int r = 0; r < 4; ++r) {
            const int row = rowBase + w * 32 + mi * 16 + hi * 4 + r;
            float x[8];
#pragma unroll
            for (int nj = 0; nj < 8; ++nj) {
                const int col = colBase + nj * 16 + c;
                x[nj] = acc[mi][nj][r] + bias[col];
                if (relu) x[nj] = fmaxf(x[nj], 0.f);
                if (resid) x[nj] += resid[(size_t)row * N + col];
            }
            if (mask_ids && mask_ids[row] == kITEMS - 1) {
#pragma unroll
                for (int nj = 0; nj < 8; ++nj) x[nj] = 0.f;
            }
            if (Craw) {
#pragma unroll
                for (int nj = 0; nj < 8; ++nj)
                    Craw[(size_t)row * N + colBase + nj * 16 + c] = x[nj];
            }
            if (lnOg) {   // LN across 16 c-lanes x 8 regs (N==128, gridDim.x==1)
                float s1 = 0.f, s2 = 0.f;
#pragma unroll
                for (int nj = 0; nj < 8; ++nj) { s1 += x[nj]; s2 += x[nj] * x[nj]; }
#pragma unroll
                for (int off = 1; off < 16; off <<= 1) {
                    s1 += __shfl_xor(s1, off);
                    s2 += __shfl_xor(s2, off);
                }
                const float mean = s1 * (1.f / 128.f);
                float var = s2 * (1.f / 128.f) - mean * mean;
                var = fmaxf(var, 0.f);
                const float rr = rsqrtf(var + lnOeps);
#pragma unroll
                for (int nj = 0; nj < 8; ++nj) {
                    const int col = nj * 16 + c;
                    Cln[(size_t)row * N + col] = (x[nj] - mean) * rr * lnOg[col] + lnOb[col];
                }
            }
        }
    }
}

__global__ __launch_bounds__(256) void gemm_k(
    const float* __restrict__ A, const float* __restrict__ A2,
    const short* __restrict__ BT, const float* __restrict__ bias,
    float* __restrict__ Craw, float* __restrict__ Cln,
    const float* __restrict__ resid,
    int N, int K, int relu, const int* __restrict__ mask_ids,
    const float* __restrict__ lnOg, const float* __restrict__ lnOb, float lnOeps)
{
    gemm_body(A, A2, BT, bias, Craw, Cln, resid, N, K, relu, mask_ids,
              lnOg, lnOb, lnOeps);
}

__global__ __launch_bounds__(256) void gemm_qkv(
    const float* __restrict__ Aq, const float* __restrict__ Ak,
    const float* __restrict__ Av, const float* __restrict__ Av2,
    const short* __restrict__ WT, int wo,
    const float* __restrict__ bq, const float* __restrict__ bk, const float* __restrict__ bv,
    float* __restrict__ Cq, float* __restrict__ Ck, float* __restrict__ Cv)
{
    const int z = blockIdx.z;
    const float* A  = (z == 0) ? Aq : (z == 1) ? Ak : Av;
    const float* A2 = (z == 2) ? Av2 : nullptr;
    const short* B  = WT + (size_t)z * 6 * 16384 + (size_t)wo * 16384;
    const float* bias = (z == 0) ? bq : (z == 1) ? bk : bv;
    float* C = (z == 0) ? Cq : (z == 1) ? Ck : Cv;
    gemm_body(A, A2, B, bias, C, nullptr, nullptr, kH, kH, 0, nullptr,
              nullptr, nullptr, 0.f);
}

// ======================= MFMA flash attention (round-4 proven) =============
#define aNT 13            // 16-row tiles covering 200 (pad 208)
#define aVS 232           // Vt / P row stride in bf16

__global__ __launch_bounds__(256) void attn_mfma(
    const float* __restrict__ qp, const float* __restrict__ kp,
    const float* __restrict__ vp, const float* __restrict__ gates,
    const int gi, const float* __restrict__ resid, float* __restrict__ outp)
{
    __shared__ short klds[200 * 64];
    __shared__ short vt[64 * aVS];
    __shared__ short pl[4][16 * aVS];
    __shared__ float glds[224];
    const int bid = (int)blockIdx.x;
    const int b = bid >> 1, h = bid & 1, hoff = h * 64;
    const int tid = threadIdx.x, lane = tid & 63, wv = tid >> 6;
    const size_t base = (size_t)b * kT * kH;

    for (int i = tid; i < 1600; i += 256) {
        const int r = i >> 3, c8 = i & 7;
        const float* src = &kp[base + (size_t)r * kH + hoff + c8 * 8];
        const float4 a0 = *reinterpret_cast<const float4*>(src);
        const float4 a1 = *reinterpret_cast<const float4*>(src + 4);
        s16x8 v;
        v[0] = f2bf(a0.x); v[1] = f2bf(a0.y); v[2] = f2bf(a0.z); v[3] = f2bf(a0.w);
        v[4] = f2bf(a1.x); v[5] = f2bf(a1.y); v[6] = f2bf(a1.z); v[7] = f2bf(a1.w);
        *reinterpret_cast<s16x8*>(reinterpret_cast<char*>(klds) +
            ((r * 128 + c8 * 16) ^ ((r & 7) << 4))) = v;
    }
    for (int i = tid; i < 6400; i += 256) {
        const int k2 = i >> 6, d = i & 63;
        const float v0 = vp[base + (size_t)(2 * k2) * kH + hoff + d];
        const float v1 = vp[base + (size_t)(2 * k2 + 1) * kH + hoff + d];
        const unsigned pk = (unsigned)(unsigned short)f2bf(v0)
                          | ((unsigned)(unsigned short)f2bf(v1) << 16);
        *reinterpret_cast<unsigned*>(reinterpret_cast<char*>(vt) + d * (aVS * 2) + k2 * 4) = pk;
    }
    for (int i = tid; i < 1024; i += 256) {
        const int d = i >> 4, k2 = 100 + (i & 15);
        *reinterpret_cast<unsigned*>(reinterpret_cast<char*>(vt) + d * (aVS * 2) + k2 * 4) = 0;
    }
    if (tid < 224) glds[tid] = (tid < 200) ? gates[(b * kT + tid) * 2 + gi] : 0.f;
    for (int i = lane; i < 16 * aVS / 2; i += 64)
        reinterpret_cast<unsigned*>(pl[wv])[i] = 0u;
    __syncthreads();

    const int c = lane & 15, hi = lane >> 4;
    const float scale = 0.125f;

    for (int qt = wv; qt < aNT; qt += 4) {
        s16x8 aq0, aq1;
        {
            const float* s0 = &qp[base + (size_t)(qt * 16 + c) * kH + hoff + hi * 8];
            const float4 a0 = *reinterpret_cast<const float4*>(s0);
            const float4 a1 = *reinterpret_cast<const float4*>(s0 + 4);
            const float4 b0 = *reinterpret_cast<const float4*>(s0 + 32);
            const float4 b1 = *reinterpret_cast<const float4*>(s0 + 36);
            aq0[0] = f2bf(a0.x); aq0[1] = f2bf(a0.y); aq0[2] = f2bf(a0.z); aq0[3] = f2bf(a0.w);
            aq0[4] = f2bf(a1.x); aq0[5] = f2bf(a1.y); aq0[6] = f2bf(a1.z); aq0[7] = f2bf(a1.w);
            aq1[0] = f2bf(b0.x); aq1[1] = f2bf(b0.y); aq1[2] = f2bf(b0.z); aq1[3] = f2bf(b0.w);
            aq1[4] = f2bf(b1.x); aq1[5] = f2bf(b1.y); aq1[6] = f2bf(b1.z); aq1[7] = f2bf(b1.w);
        }
        f32x4 sc[aNT];
#pragma unroll
        for (int kt = 0; kt < aNT; ++kt) {
            if (kt > qt) continue;
            const int krow = kt * 16 + c;
            const int sw = (krow & 7) << 4;
            const s16x8 bk0 = *reinterpret_cast<const s16x8*>(
                reinterpret_cast<const char*>(klds) + ((krow * 128 + hi * 16) ^ sw));
            const s16x8 bk1 = *reinterpret_cast<const s16x8*>(
                reinterpret_cast<const char*>(klds) + ((krow * 128 + 64 + hi * 16) ^ sw));
            f32x4 s = {0.f, 0.f, 0.f, 0.f};
            s = mfma16(aq0, bk0, s);
            s = mfma16(aq1, bk1, s);
            sc[kt] = s;
        }
        float gq[4], m[4], ps[4];
#pragma unroll
        for (int r = 0; r < 4; ++r) {
            gq[r] = glds[qt * 16 + hi * 4 + r];
            m[r] = kNEG_INF; ps[r] = 0.f;
        }
#pragma unroll
        for (int kt = 0; kt < aNT; ++kt) {
            if (kt > qt) continue;
            const int col = kt * 16 + c;
            const float gk = glds[col] * scale;
#pragma unroll
            for (int r = 0; r < 4; ++r) {
                const int row = qt * 16 + hi * 4 + r;
                const float v = (col <= row && col < 200) ? sc[kt][r] * gq[r] * gk : kNEG_INF;
                sc[kt][r] = v;
                m[r] = fmaxf(m[r], v);
            }
        }
#pragma unroll
        for (int r = 0; r < 4; ++r)
#pragma unroll
            for (int off = 1; off < 16; off <<= 1)
                m[r] = fmaxf(m[r], __shfl_xor(m[r], off));
#pragma unroll
        for (int kt = 0; kt < aNT; ++kt) {
            if (kt > qt) continue;
#pragma unroll
            for (int r = 0; r < 4; ++r) {
                const float p = __expf(sc[kt][r] - m[r]);
                ps[r] += p;
                *reinterpret_cast<short*>(reinterpret_cast<char*>(pl[wv]) +
                    ((hi * 4 + r) * aVS + kt * 16 + c) * 2) = f2bf(p);
            }
        }
#pragma unroll
        for (int r = 0; r < 4; ++r)
#pragma unroll
            for (int off = 1; off < 16; off <<= 1)
                ps[r] += __shfl_xor(ps[r], off);
        f32x4 oacc[4] = {};
        const int nch = (qt + 2) >> 1;
#pragma unroll
        for (int ks = 0; ks < 7; ++ks) {
            if (ks >= nch) continue;
            const s16x8 pa = *reinterpret_cast<const s16x8*>(
                reinterpret_cast<const char*>(pl[wv]) + (c * aVS + ks * 32 + hi * 8) * 2);
#pragma unroll
            for (int n = 0; n < 4; ++n) {
                const s16x8 bv = *reinterpret_cast<const s16x8*>(
                    reinterpret_cast<const char*>(vt) + ((n * 16 + c) * aVS + ks * 32 + hi * 8) * 2);
                oacc[n] = mfma16(pa, bv, oacc[n]);
            }
        }
#pragma unroll
        for (int r = 0; r < 4; ++r) {
            const int row = qt * 16 + hi * 4 + r;
            if (row < 200) {
                const float inv = 1.f / ps[r];
#pragma unroll
                for (int n = 0; n < 4; ++n) {
                    const size_t off = base + (size_t)row * kH + hoff + n * 16 + c;
                    outp[off] = resid[off] + oacc[n][r] * inv;
                }
            }
        }
    }
}

// ---------------------------------------------------------------------------
extern "C" void kernel_launch(void* const* d_in, const int* in_sizes, int n_in,
                              void* d_out, int out_size, void* d_ws, size_t ws_size,
                              hipStream_t stream)
{
    const int* ids_o = (const int*)d_in[0];
    const int* ids_x = (const int*)d_in[1];
    const int* ids_y = (const int*)d_in[2];
    const int* pos_o = (const int*)d_in[3];
    const int* pos_x = (const int*)d_in[4];
    const int* pos_y = (const int*)d_in[5];
    const int* tm_o  = (const int*)d_in[6];
    const int* tm_x  = (const int*)d_in[7];
    const int* tm_y  = (const int*)d_in[8];
    const int* itv_x = (const int*)d_in[9];
    const int* itv_y = (const int*)d_in[10];
    const int* itv_o = (const int*)d_in[11];
    const float* embX = (const float*)d_in[12];
    const float* embY = (const float*)d_in[13];
    const float* embO = (const float*)d_in[14];
    const float* time_table = (const float*)d_in[15];
    const float* interval_table = (const float*)d_in[16];
    const int* adj_idx  = (const int*)d_in[17];
    const float* adj_val = (const float*)d_in[18];
    const int* adjs_idx  = (const int*)d_in[19];
    const float* adjs_val = (const float*)d_in[20];
    const float* mlp_W1 = (const float*)d_in[21];
    const float* mlp_b1 = (const float*)d_in[22];
    const float* mlp_W2 = (const float*)d_in[23];
    const float* mlp_b2 = (const float*)d_in[24];
    const float* mlp_lng = (const float*)d_in[25];
    const float* mlp_lnb = (const float*)d_in[26];
    const float* pos_emb = (const float*)d_in[27];
    const float* gate_W = (const float*)d_in[28];
    const float* gate_b = (const float*)d_in[29];
    const float* aln_g = (const float*)d_in[30];
    const float* aln_b = (const float*)d_in[31];
    const float* qW = (const float*)d_in[32];
    const float* kW = (const float*)d_in[33];
    const float* vW = (const float*)d_in[34];
    const float* c1W = (const float*)d_in[35];
    const float* c2W = (const float*)d_in[36];
    const float* qb = (const float*)d_in[37];
    const float* kb = (const float*)d_in[38];
    const float* vb = (const float*)d_in[39];
    const float* c1b = (const float*)d_in[40];
    const float* c2b = (const float*)d_in[41];
    const float* fln_g = (const float*)d_in[42];
    const float* fln_b = (const float*)d_in[43];
    const float* lln_g = (const float*)d_in[44];
    const float* lln_b = (const float*)d_in[45];

    float* out = (float*)d_out;
    float* ws = (float*)d_ws;

    // ---- workspace layout (floats) ----
    const size_t SZ_TOK = (size_t)kM * kH;        // 3,276,800
    float* BIG  = ws;                              // SMOOTH (12.8M) / hidden (13.1M)
    float* XBUF = BIG  + 13107200;                 // build_x / Q / FFN hidden
    float* TEMB = XBUF + SZ_TOK;
    float* SEQS = TEMB + SZ_TOK;
    float* QBUF = SEQS + SZ_TOK;
    float* KP   = QBUF + SZ_TOK;                   // aliased: EDGES during CSR phase
    float* VP   = KP   + SZ_TOK;
    float* GATES = VP  + SZ_TOK;                   // 51,200 floats
    short* WT = (short*)(GATES + 51200);           // 884,736 bf16
    short* qWT = WT;
    short* c1WT = WT + 3 * 6 * 16384;
    short* c2WT = c1WT + 6 * 16384;
    short* w1T = c2WT + 6 * 16384;                 // 3 x 512x128
    short* w2T = w1T + 3 * 65536;                  // 3 x 128x512
    int* COUNTS = (int*)(WT + 884736);
    int* OFFS   = COUNTS + kROWS;                  // kROWS+1
    int* CURS   = OFFS + kROWS + 1;
    int* PART   = CURS + kROWS;                    // 256
    int* ROWLIST = PART + 256;                     // 25600
    int* NFLAG  = ROWLIST + 25600;                 // 16 (1 used)
    unsigned char* FLAGS = (unsigned char*)(NFLAG + 16);   // 100,000 B
    int2* EDGES = (int2*)KP;                       // flagged edges <= 12.8MB

    const size_t needed = (size_t)(13107200 + 7 * 3276800 + 51200) * 4
                        + (size_t)884736 * 2
                        + (size_t)(3 * kROWS + 1 + 256 + 25600 + 16) * 4
                        + kROWS + 4096;
    if (ws_size < needed) return;

    // ---- one-time weight transpose/convert ----
    wt_kernel<<<6 * 16384 / 256, 256, 0, stream>>>(qW, qWT, 7, 7);
    wt_kernel<<<6 * 16384 / 256, 256, 0, stream>>>(kW, qWT + 6 * 16384, 7, 7);
    wt_kernel<<<6 * 16384 / 256, 256, 0, stream>>>(vW, qWT + 12 * 16384, 7, 7);
    wt_kernel<<<6 * 16384 / 256, 256, 0, stream>>>(c1W, c1WT, 7, 7);
    wt_kernel<<<6 * 16384 / 256, 256, 0, stream>>>(c2W, c2WT, 7, 7);
    wt_kernel<<<3 * 65536 / 256, 256, 0, stream>>>(mlp_W1, w1T, 7, 9);
    wt_kernel<<<3 * 65536 / 256, 256, 0, stream>>>(mlp_W2, w2T, 9, 7);

    struct Enc {
        const int* ids; const int* pos; const int* tm; const int* itv;
        const float* emb; const int* a_idx; const float* a_val; int mi;
    };
    const Enc encs[3] = {
        { ids_o, pos_o, tm_o, itv_o, embO, adj_idx,  adj_val,  2 },
        { ids_x, pos_x, tm_x, itv_x, embX, adjs_idx, adjs_val, 0 },
        { ids_y, pos_y, tm_y, itv_y, embY, adjs_idx, adjs_val, 1 },
    };

    const int g4 = (kNNZ / 4 + 255) / 256;   // 1563

    for (int e = 0; e < 3; ++e) {
        const Enc& E = encs[e];
        // ---- CSR build + smoothed rows (compacted, f32) ----
        hipMemsetAsync(FLAGS, 0, kROWS, stream);
        hipMemsetAsync(COUNTS, 0, kROWS * sizeof(int), stream);
        hipMemsetAsync(NFLAG, 0, sizeof(int), stream);
        flag_kernel<<<kM / 256, 256, 0, stream>>>(E.ids, FLAGS);
        rowlist_kernel<<<(kROWS + 255) / 256, 256, 0, stream>>>(FLAGS, ROWLIST, NFLAG);
        count4_kernel<<<g4, 256, 0, stream>>>(E.a_idx, FLAGS, COUNTS);
        scan_pass1<<<98, 256, 0, stream>>>(COUNTS, PART);
        scan_pass2<<<1, 128, 0, stream>>>(PART, 98);
        scan_pass3<<<98, 256, 0, stream>>>(COUNTS, PART, OFFS, CURS);
        scatter4_kernel<<<g4, 256, 0, stream>>>(E.a_idx, E.a_val, FLAGS, CURS, EDGES);
        smooth_kernel<<<6400, 256, 0, stream>>>(EDGES, OFFS, ROWLIST, NFLAG, E.emb, BIG);
        gather_kernel<<<kM / 2, 256, 0, stream>>>(E.ids, BIG, SEQS);   // consume BIG BEFORE W1 reuses it
        // ---- temb = LN(MLP(interval_emb + time_emb)); LN fused in W2 epi ----
        build_x_kernel<<<kM / 2, 256, 0, stream>>>(E.itv, E.tm, interval_table, time_table, XBUF);
        gemm_k<<<dim3(4, kM / 128), 256, 0, stream>>>(
            XBUF, nullptr, w1T + (size_t)E.mi * 65536, mlp_b1 + E.mi * 512,
            BIG, nullptr, nullptr, 512, 128, 1, nullptr, nullptr, nullptr, 0.f);
        gemm_k<<<dim3(1, kM / 128), 256, 0, stream>>>(
            BIG, nullptr, w2T + (size_t)E.mi * 65536, mlp_b2 + E.mi * kH,
            nullptr, TEMB, nullptr, 128, 512, 0, nullptr,
            mlp_lng + E.mi * kH, mlp_lnb + E.mi * kH, 1e-5f);
        // ---- pos + mask + gates + aln0 (one kernel) ----
        posmg_kernel<<<kM / 4, 256, 0, stream>>>(
            E.ids, E.pos, pos_emb + (size_t)e * kT * kH,
            gate_W + e * kH * 2, gate_b + e * 2, SEQS, TEMB, GATES,
            aln_g + (e * 2) * kH, aln_b + (e * 2) * kH, QBUF);
        // ---- 2 attention blocks ----
        for (int i = 0; i < 2; ++i) {
            const int wo = e * 2 + i;
            gemm_qkv<<<dim3(1, kM / 128, 3), 256, 0, stream>>>(
                QBUF, TEMB, SEQS, TEMB, qWT, wo,
                qb + wo * kH, kb + wo * kH, vb + wo * kH,
                XBUF, KP, VP);
            attn_mfma<<<kBATCH * 2, 256, 0, stream>>>(XBUF, KP, VP, GATES, i, QBUF, SEQS);
            ln_wave<<<kM / 4, 256, 0, stream>>>(SEQS, SEQS, fln_g + wo * kH, fln_b + wo * kH, 1e-8f);
            gemm_k<<<dim3(1, kM / 128), 256, 0, stream>>>(
                SEQS, nullptr, c1WT + (size_t)wo * 16384, c1b + wo * kH,
                XBUF, nullptr, nullptr, 128, 128, 1, nullptr, nullptr, nullptr, 0.f);
            if (i == 0) {
                // c2: SEQS = resid+mask (raw), QBUF = aln1_LN(SEQS)
                gemm_k<<<dim3(1, kM / 128), 256, 0, stream>>>(
                    XBUF, nullptr, c2WT + (size_t)wo * 16384, c2b + wo * kH,
                    SEQS, QBUF, SEQS, 128, 128, 0, E.ids,
                    aln_g + (e * 2 + 1) * kH, aln_b + (e * 2 + 1) * kH, 1e-8f);
            } else {
                // c2: out = lln_LN(resid+mask)
                gemm_k<<<dim3(1, kM / 128), 256, 0, stream>>>(
                    XBUF, nullptr, c2WT + (size_t)wo * 16384, c2b + wo * kH,
                    nullptr, out + (size_t)e * SZ_TOK, SEQS, 128, 128, 0, E.ids,
                    lln_g + e * kH, lln_b + e * kH, 1e-8f);
            }
        }
    }
}

// Round 10
// 1027.783 us; speedup vs baseline: 4.9068x; 1.2169x over previous
//
#include <hip/hip_runtime.h>
#include <math.h>

// ---------------------------------------------------------------------------
// TACDSR forward — round 10: encoder-merged phase-B dispatches (z=3) when the
// workspace allows (ws-branch, graph-safe), bf16 Q/K/V + bf16 hiddens (zero
// math change), compact smooth + RANK gather. r9 math preserved exactly.
// ---------------------------------------------------------------------------

#define kH 128
#define kT 200
#define kBATCH 128
#define kM (kBATCH * kT)         // 25600 tokens
#define kITEMS 100000
#define kROWS 100000
#define kNNZ 1600000
#define kNEG_INF (-__builtin_huge_valf())
#define kSZ ((size_t)kM * kH)    // 3,276,800 elements per token-matrix

typedef short s16x8 __attribute__((ext_vector_type(8)));
typedef __bf16 b16x8 __attribute__((ext_vector_type(8)));
typedef float f32x4 __attribute__((ext_vector_type(4)));

static __device__ __forceinline__ short f2bf(float f) {
    unsigned u = __float_as_uint(f);
    unsigned r = (u + 0x7FFFu + ((u >> 16) & 1u)) >> 16;
    return (short)r;
}
static __device__ __forceinline__ f32x4 mfma16(s16x8 a, s16x8 b, f32x4 c) {
    return __builtin_amdgcn_mfma_f32_16x16x32_bf16(
        __builtin_bit_cast(b16x8, a), __builtin_bit_cast(b16x8, b), c, 0, 0, 0);
}

struct P3 { const int* p[3]; };

// ======================= CSR build + smooth ================================
__global__ void flag_kernel(const int* __restrict__ ids, unsigned char* __restrict__ flags)
{
    flags[ids[blockIdx.x * 256 + threadIdx.x]] = 1;
}

__global__ void rowlist_kernel(const unsigned char* __restrict__ flags,
                               int* __restrict__ rowlist, int* __restrict__ rank,
                               int* __restrict__ nflag)
{
    const int r = blockIdx.x * 256 + threadIdx.x;
    if (r < kROWS && flags[r]) {
        const int pos = atomicAdd(nflag, 1);
        rowlist[pos] = r;
        rank[r] = pos;
    }
}

__global__ void count4_kernel(const int* __restrict__ idx,
                              const unsigned char* __restrict__ flags,
                              int* __restrict__ counts)
{
    const int j4 = (blockIdx.x * 256 + threadIdx.x) * 4;
    if (j4 >= kNNZ) return;
    const int4 r = *reinterpret_cast<const int4*>(&idx[j4]);
    if (flags[r.x]) atomicAdd(&counts[r.x], 1);
    if (flags[r.y]) atomicAdd(&counts[r.y], 1);
    if (flags[r.z]) atomicAdd(&counts[r.z], 1);
    if (flags[r.w]) atomicAdd(&counts[r.w], 1);
}

__global__ __launch_bounds__(256) void scan_pass1(const int* __restrict__ counts,
                                                  int* __restrict__ partial)
{
    const int t = threadIdx.x;
    const int base = blockIdx.x * 1024;
    int s = 0;
#pragma unroll
    for (int i = 0; i < 4; ++i) {
        const int g = base + t + i * 256;
        if (g < kROWS) s += counts[g];
    }
    __shared__ int sd[256];
    sd[t] = s; __syncthreads();
    for (int off = 128; off > 0; off >>= 1) {
        if (t < off) sd[t] += sd[t + off];
        __syncthreads();
    }
    if (t == 0) partial[blockIdx.x] = sd[0];
}

__global__ void scan_pass2(int* __restrict__ partial, int nblk)
{
    const int t = threadIdx.x;          // 128 threads
    __shared__ int sd[128];
    const int v = (t < nblk) ? partial[t] : 0;
    sd[t] = v; __syncthreads();
    for (int off = 1; off < 128; off <<= 1) {
        const int a = (t >= off) ? sd[t - off] : 0;
        __syncthreads();
        sd[t] += a;
        __syncthreads();
    }
    if (t < nblk) partial[t] = sd[t] - v;   // exclusive
}

__global__ __launch_bounds__(256) void scan_pass3(const int* __restrict__ counts,
                                                  const int* __restrict__ partial,
                                                  int* __restrict__ offsets,
                                                  int* __restrict__ cursor)
{
    const int t = threadIdx.x;
    const int base = blockIdx.x * 1024;
    int c[4]; int s = 0;
#pragma unroll
    for (int i = 0; i < 4; ++i) {
        const int g = base + t * 4 + i;
        c[i] = (g < kROWS) ? counts[g] : 0;
        s += c[i];
    }
    __shared__ int sd[256];
    sd[t] = s; __syncthreads();
    for (int off = 1; off < 256; off <<= 1) {
        const int a = (t >= off) ? sd[t - off] : 0;
        __syncthreads();
        sd[t] += a;
        __syncthreads();
    }
    int run = partial[blockIdx.x] + sd[t] - s;
#pragma unroll
    for (int i = 0; i < 4; ++i) {
        const int g = base + t * 4 + i;
        if (g < kROWS) {
            offsets[g] = run;
            cursor[g] = run;
            run += c[i];
            if (g == kROWS - 1) offsets[kROWS] = run;
        }
    }
}

__global__ void scatter4_kernel(const int* __restrict__ idx, const float* __restrict__ val,
                                const unsigned char* __restrict__ flags,
                                int* __restrict__ cursor, int2* __restrict__ edges)
{
    const int j4 = (blockIdx.x * 256 + threadIdx.x) * 4;
    if (j4 >= kNNZ) return;
    const int4 r = *reinterpret_cast<const int4*>(&idx[j4]);
    const int4 c = *reinterpret_cast<const int4*>(&idx[kNNZ + j4]);
    const float4 v = *reinterpret_cast<const float4*>(&val[j4]);
    if (flags[r.x]) edges[atomicAdd(&cursor[r.x], 1)] = make_int2(c.x, __float_as_int(v.x));
    if (flags[r.y]) edges[atomicAdd(&cursor[r.y], 1)] = make_int2(c.y, __float_as_int(v.y));
    if (flags[r.z]) edges[atomicAdd(&cursor[r.z], 1)] = make_int2(c.z, __float_as_int(v.z));
    if (flags[r.w]) edges[atomicAdd(&cursor[r.w], 1)] = make_int2(c.w, __float_as_int(v.w));
}

// per flagged row (compacted list): writes COMPACT row ri
__global__ __launch_bounds__(256) void smooth_kernel(
    const int2* __restrict__ edges, const int* __restrict__ offsets,
    const int* __restrict__ rowlist, const int* __restrict__ nflag,
    const float* __restrict__ emb, float* __restrict__ smc)
{
    const int ri = blockIdx.x * 4 + (threadIdx.x >> 6);
    const int lane = threadIdx.x & 63;
    if (ri >= nflag[0]) return;
    const int row = rowlist[ri];
    const int lo = offsets[row], hi = offsets[row + 1];
    float a0 = 0.f, a1 = 0.f;
    int e = lo;
    for (; e + 4 <= hi; e += 4) {
        const int2 e0 = edges[e],     e1 = edges[e + 1];
        const int2 e2 = edges[e + 2], e3 = edges[e + 3];
        const float2 u0 = *reinterpret_cast<const float2*>(&emb[(size_t)e0.x * kH + 2 * lane]);
        const float2 u1 = *reinterpret_cast<const float2*>(&emb[(size_t)e1.x * kH + 2 * lane]);
        const float2 u2 = *reinterpret_cast<const float2*>(&emb[(size_t)e2.x * kH + 2 * lane]);
        const float2 u3 = *reinterpret_cast<const float2*>(&emb[(size_t)e3.x * kH + 2 * lane]);
        const float v0 = __int_as_float(e0.y), v1 = __int_as_float(e1.y);
        const float v2 = __int_as_float(e2.y), v3 = __int_as_float(e3.y);
        a0 = fmaf(v0, u0.x, a0); a1 = fmaf(v0, u0.y, a1);
        a0 = fmaf(v1, u1.x, a0); a1 = fmaf(v1, u1.y, a1);
        a0 = fmaf(v2, u2.x, a0); a1 = fmaf(v2, u2.y, a1);
        a0 = fmaf(v3, u3.x, a0); a1 = fmaf(v3, u3.y, a1);
    }
    for (; e < hi; ++e) {
        const int2 ed = edges[e];
        const float2 u = *reinterpret_cast<const float2*>(&emb[(size_t)ed.x * kH + 2 * lane]);
        const float v = __int_as_float(ed.y);
        a0 = fmaf(v, u.x, a0); a1 = fmaf(v, u.y, a1);
    }
    float s = a0 * a0 + a1 * a1;
#pragma unroll
    for (int off = 1; off < 64; off <<= 1) s += __shfl_xor(s, off);
    const float inv = 0.5f / fmaxf(sqrtf(s), 1e-12f);
    const float2 us = *reinterpret_cast<const float2*>(&emb[(size_t)row * kH + 2 * lane]);
    float2 o;
    o.x = 1.5f * us.x + a0 * inv;
    o.y = 1.5f * us.y + a1 * inv;
    *reinterpret_cast<float2*>(&smc[(size_t)ri * kH + 2 * lane]) = o;
}

// seqs[tok] = smc[rank[ids[tok]]]
__global__ void gather_kernel(const int* __restrict__ ids, const int* __restrict__ rank,
                              const float* __restrict__ smc, float* __restrict__ seqs)
{
    const int tok = blockIdx.x * 2 + (threadIdx.x >> 7);
    const int c = threadIdx.x & 127;
    seqs[(size_t)tok * kH + c] = smc[(size_t)rank[ids[tok]] * kH + c];
}

// posmg: temb += p; seqs = keep ? seqs+p : 0; gates; qbuf = aln0_LN(seqs)
__global__ __launch_bounds__(256) void posmg_kernel(
    const int* __restrict__ ids, const int* __restrict__ pos,
    const float* __restrict__ pemb, const float* __restrict__ gW,
    const float* __restrict__ gb,
    float* __restrict__ seqs, float* __restrict__ temb, float* __restrict__ gates,
    const float* __restrict__ alng, const float* __restrict__ alnb,
    float* __restrict__ qbuf)
{
    const int tok = blockIdx.x * 4 + (threadIdx.x >> 6);
    const int lane = threadIdx.x & 63;
    const int pp = pos[tok];
    const float p0 = pemb[(size_t)pp * kH + lane];
    const float p1 = pemb[(size_t)pp * kH + 64 + lane];
    const size_t o = (size_t)tok * kH;
    const float t0 = temb[o + lane] + p0;
    const float t1 = temb[o + 64 + lane] + p1;
    temb[o + lane] = t0;
    temb[o + 64 + lane] = t1;
    const bool keep = ids[tok] != kITEMS - 1;
    const float q0 = keep ? seqs[o + lane] + p0 : 0.f;
    const float q1 = keep ? seqs[o + 64 + lane] + p1 : 0.f;
    seqs[o + lane] = q0;
    seqs[o + 64 + lane] = q1;
#pragma unroll
    for (int i = 0; i < 2; ++i) {
        float g = t0 * gW[lane * 2 + i] + t1 * gW[(64 + lane) * 2 + i];
#pragma unroll
        for (int off = 1; off < 64; off <<= 1) g += __shfl_xor(g, off);
        if (lane == 0) gates[tok * 2 + i] = 1.f / (1.f + expf(-(g + gb[i])));
    }
    float s1 = q0 + q1, s2 = q0 * q0 + q1 * q1;
#pragma unroll
    for (int off = 1; off < 64; off <<= 1) {
        s1 += __shfl_xor(s1, off);
        s2 += __shfl_xor(s2, off);
    }
    const float mean = s1 * (1.f / 128.f);
    float var = s2 * (1.f / 128.f) - mean * mean;
    var = fmaxf(var, 0.f);
    const float rr = rsqrtf(var + 1e-8f);
    qbuf[o + lane]      = (q0 - mean) * rr * alng[lane]      + alnb[lane];
    qbuf[o + 64 + lane] = (q1 - mean) * rr * alng[64 + lane] + alnb[64 + lane];
}

// ======================= misc small kernels ================================
__global__ void build_x_kernel(
    const int* __restrict__ itv, const int* __restrict__ tt,
    const float* __restrict__ interval_table, const float* __restrict__ time_table,
    float* __restrict__ x)
{
    const int tok = blockIdx.x * 2 + (threadIdx.x >> 7);
    const int c = threadIdx.x & 127;
    const int t = itv[tok];
    int idx = (int)floorf(log2f((float)t + 1.0f));
    idx = idx < 0 ? 0 : (idx > 30 ? 30 : idx);
    x[(size_t)tok * kH + c] = interval_table[idx * kH + c] + time_table[(size_t)tt[tok] * kH + c];
}

__global__ void wt_kernel(const float* __restrict__ in, short* __restrict__ out,
                          int kLog, int nLog)
{
    const int i = blockIdx.x * 256 + threadIdx.x;
    const int knLog = kLog + nLog;
    const int b = i >> knLog;
    const int rem = i & ((1 << knLog) - 1);
    const int n = rem >> kLog;
    const int k = rem & ((1 << kLog) - 1);
    out[i] = f2bf(in[((size_t)b << knLog) + ((size_t)k << nLog) + n]);
}

// fln LN, possibly merged across encoders (local enc from blockIdx)
__global__ __launch_bounds__(256) void ln_fln(
    float* __restrict__ seqs_b, const float* __restrict__ flng,
    const float* __restrict__ flnb, int enc0, int i)
{
    const int l = blockIdx.x / (kM / 4);
    const int blk = blockIdx.x % (kM / 4);
    const int wo = (enc0 + l) * 2 + i;
    float* seqs = seqs_b + (size_t)l * kSZ;
    const float* g = flng + wo * kH;
    const float* bb = flnb + wo * kH;
    const int tok = blk * 4 + (threadIdx.x >> 6);
    const int lane = threadIdx.x & 63;
    const float x0 = seqs[(size_t)tok * kH + lane];
    const float x1 = seqs[(size_t)tok * kH + 64 + lane];
    float s1 = x0 + x1, s2 = x0 * x0 + x1 * x1;
#pragma unroll
    for (int off = 1; off < 64; off <<= 1) {
        s1 += __shfl_xor(s1, off);
        s2 += __shfl_xor(s2, off);
    }
    const float mean = s1 * (1.f / 128.f);
    float var = s2 * (1.f / 128.f) - mean * mean;
    var = fmaxf(var, 0.f);
    const float r = rsqrtf(var + 1e-8f);
    seqs[(size_t)tok * kH + lane]      = (x0 - mean) * r * g[lane]      + bb[lane];
    seqs[(size_t)tok * kH + 64 + lane] = (x1 - mean) * r * g[64 + lane] + bb[64 + lane];
}

// ======================= bf16 MFMA GEMM core ===============================
// A: MxK (f32 [+A2] or bf16 via ABF). BT: NxK bf16. 128x128 tile, 4 waves.
// Epilogue: x = [relu](acc+bias) [+resid] [mask->0];
// Craw f32 / CrawB bf16 raw stores; lnOg -> LN over row (N==128) to Cln.
template <bool ABF>
static __device__ __forceinline__ void gemm_body(
    const void* __restrict__ Av, const float* __restrict__ A2,
    const short* __restrict__ BT, const float* __restrict__ bias,
    float* __restrict__ Craw, short* __restrict__ CrawB,
    float* __restrict__ Cln, const float* __restrict__ resid,
    int N, int K, int relu, const int* __restrict__ mask_ids,
    const float* __restrict__ lnOg, const float* __restrict__ lnOb, float lnOeps)
{
    __shared__ short As[128 * 128];
    __shared__ short Bs[128 * 128];
    const int tid = threadIdx.x;
    const int lane = tid & 63;
    const int w = tid >> 6;
    const int rowBase = blockIdx.y * 128;
    const int colBase = blockIdx.x * 128;
    f32x4 acc[2][8] = {};

    for (int k0 = 0; k0 < K; k0 += 128) {
#pragma unroll
        for (int p = 0; p < 8; ++p) {
            const int chunk = p * 256 + tid;
            const int r = chunk >> 4;
            const int kc = chunk & 15;
            const int byteoff = (r * 256 + kc * 16) ^ ((r & 7) << 4);
            if (ABF) {
                const short* A16 = (const short*)Av;
                const s16x8 v = *reinterpret_cast<const s16x8*>(
                    &A16[(size_t)(rowBase + r) * K + k0 + kc * 8]);
                *reinterpret_cast<s16x8*>(reinterpret_cast<char*>(As) + byteoff) = v;
            } else {
                const float* A = (const float*)Av;
                const float* src = &A[(size_t)(rowBase + r) * K + k0 + kc * 8];
                float4 a0 = *reinterpret_cast<const float4*>(src);
                float4 a1 = *reinterpret_cast<const float4*>(src + 4);
                if (A2) {
                    const float* s2 = &A2[(size_t)(rowBase + r) * K + k0 + kc * 8];
                    float4 b0 = *reinterpret_cast<const float4*>(s2);
                    float4 b1 = *reinterpret_cast<const float4*>(s2 + 4);
                    a0.x += b0.x; a0.y += b0.y; a0.z += b0.z; a0.w += b0.w;
                    a1.x += b1.x; a1.y += b1.y; a1.z += b1.z; a1.w += b1.w;
                }
                s16x8 v;
                v[0] = f2bf(a0.x); v[1] = f2bf(a0.y); v[2] = f2bf(a0.z); v[3] = f2bf(a0.w);
                v[4] = f2bf(a1.x); v[5] = f2bf(a1.y); v[6] = f2bf(a1.z); v[7] = f2bf(a1.w);
                *reinterpret_cast<s16x8*>(reinterpret_cast<char*>(As) + byteoff) = v;
            }
            {
                const s16x8 v = *reinterpret_cast<const s16x8*>(
                    &BT[(size_t)(colBase + r) * K + k0 + kc * 8]);
                *reinterpret_cast<s16x8*>(reinterpret_cast<char*>(Bs) + byteoff) = v;
            }
        }
        __syncthreads();
#pragma unroll
        for (int kk = 0; kk < 4; ++kk) {
            const int kb = (kk * 32 + (lane >> 4) * 8) * 2;
            s16x8 af[2];
#pragma unroll
            for (int mi = 0; mi < 2; ++mi) {
                const int r = w * 32 + mi * 16 + (lane & 15);
                af[mi] = *reinterpret_cast<const s16x8*>(
                    reinterpret_cast<const char*>(As) + ((r * 256 + kb) ^ ((r & 7) << 4)));
            }
#pragma unroll
            for (int nj = 0; nj < 8; ++nj) {
                const int r = nj * 16 + (lane & 15);
                const s16x8 bf = *reinterpret_cast<const s16x8*>(
                    reinterpret_cast<const char*>(Bs) + ((r * 256 + kb) ^ ((r & 7) << 4)));
#pragma unroll
                for (int mi = 0; mi < 2; ++mi)
                    acc[mi][nj] = mfma16(af[mi], bf, acc[mi][nj]);
            }
        }
        __syncthreads();
    }
    // epilogue: C/D layout col=lane&15, row=(lane>>4)*4+reg
    const int c = lane & 15, hi = lane >> 4;
#pragma unroll
    for (int mi = 0; mi < 2; ++mi) {
#pragma unroll
        for (int r = 0; r < 4; ++r) {
            const int row = rowBase + w * 32 + mi * 16 + hi * 4 + r;
            float x[8];
#pragma unroll
            for (int nj = 0; nj < 8; ++nj) {
                const int col = colBase + nj * 16 + c;
                x[nj] = acc[mi][nj][r] + bias[col];
                if (relu) x[nj] = fmaxf(x[nj], 0.f);
                if (resid) x[nj] += resid[(size_t)row * N + col];
            }
            if (mask_ids && mask_ids[row] == kITEMS - 1) {
#pragma unroll
                for (int nj = 0; nj < 8; ++nj) x[nj] = 0.f;
            }
            if (Craw) {
#pragma unroll
                for (int nj = 0; nj < 8; ++nj)
                    Craw[(size_t)row * N + colBase + nj * 16 + c] = x[nj];
            }
            if (CrawB) {
#pragma unroll
                for (int nj = 0; nj < 8; ++nj)
                    CrawB[(size_t)row * N + colBase + nj * 16 + c] = f2bf(x[nj]);
            }
            if (lnOg) {   // LN over full row (N==128, gridDim.x==1)
                float s1 = 0.f, s2 = 0.f;
#pragma unroll
                for (int nj = 0; nj < 8; ++nj) { s1 += x[nj]; s2 += x[nj] * x[nj]; }
#pragma unroll
                for (int off = 1; off < 16; off <<= 1) {
                    s1 += __shfl_xor(s1, off);
                    s2 += __shfl_xor(s2, off);
                }
                const float mean = s1 * (1.f / 128.f);
                float var = s2 * (1.f / 128.f) - mean * mean;
                var = fmaxf(var, 0.f);
                const float rr = rsqrtf(var + lnOeps);
#pragma unroll
                for (int nj = 0; nj < 8; ++nj) {
                    const int col = nj * 16 + c;
                    Cln[(size_t)row * kH + col] = (x[nj] - mean) * rr * lnOg[col] + lnOb[col];
                }
            }
        }
    }
}

// ---- W1: hid(bf16) = relu(X @ W1 + b1), grid (4, 200) ----
__global__ __launch_bounds__(256) void gemm_w1(
    const float* __restrict__ A, const short* __restrict__ BT,
    const float* __restrict__ bias, short* __restrict__ C)
{
    gemm_body<false>(A, nullptr, BT, bias, nullptr, C, nullptr, nullptr,
                     512, 128, 1, nullptr, nullptr, nullptr, 0.f);
}

// ---- W2: temb = mlpLN(hid @ W2 + b2), grid (1, 200) ----
__global__ __launch_bounds__(256) void gemm_w2(
    const short* __restrict__ A, const short* __restrict__ BT,
    const float* __restrict__ bias, float* __restrict__ Cln,
    const float* __restrict__ g, const float* __restrict__ b)
{
    gemm_body<true>(A, nullptr, BT, bias, nullptr, nullptr, Cln, nullptr,
                    128, 512, 0, nullptr, g, b, 1e-5f);
}

// ---- QKV: bf16 outputs, grid (1, 200, 3*nenc) ----
__global__ __launch_bounds__(256) void gemm_qkv(
    const float* __restrict__ qbuf_b, const float* __restrict__ temb_b,
    const float* __restrict__ seqs_b, short* __restrict__ qkv16,
    const short* __restrict__ WT, int enc0, int i,
    const float* __restrict__ qb, const float* __restrict__ kb,
    const float* __restrict__ vb)
{
    const int z = blockIdx.z;
    const int l = z / 3, m = z % 3;
    const int wo = (enc0 + l) * 2 + i;
    const float* A  = (m == 0) ? qbuf_b + (size_t)l * kSZ
                    : (m == 1) ? temb_b + (size_t)l * kSZ
                               : seqs_b + (size_t)l * kSZ;
    const float* A2 = (m == 2) ? temb_b + (size_t)l * kSZ : nullptr;
    const short* B  = WT + ((size_t)m * 6 + wo) * 16384;
    const float* bias = ((m == 0) ? qb : (m == 1) ? kb : vb) + wo * kH;
    short* C = qkv16 + (size_t)(l * 3 + m) * kSZ;
    gemm_body<false>(A, A2, B, bias, nullptr, C, nullptr, nullptr,
                     128, 128, 0, nullptr, nullptr, nullptr, 0.f);
}

// ---- c1: hidc(bf16, aliases QP) = relu(seqs @ c1W + b), grid (1,200,nenc) --
__global__ __launch_bounds__(256) void gemm_c1(
    const float* __restrict__ seqs_b, short* __restrict__ qkv16,
    const short* __restrict__ c1WT, const float* __restrict__ c1b,
    int enc0, int i)
{
    const int l = blockIdx.z;
    const int wo = (enc0 + l) * 2 + i;
    gemm_body<false>(seqs_b + (size_t)l * kSZ, nullptr,
                     c1WT + (size_t)wo * 16384, c1b + wo * kH,
                     nullptr, qkv16 + (size_t)(l * 3) * kSZ, nullptr, nullptr,
                     128, 128, 1, nullptr, nullptr, nullptr, 0.f);
}

// ---- c2: i0: seqs=resid+mask raw, qbuf=aln1LN; i1: out=llnLN. grid (1,200,nenc)
__global__ __launch_bounds__(256) void gemm_c2(
    const short* __restrict__ qkv16, float* __restrict__ seqs_b,
    float* __restrict__ qbuf_b, float* __restrict__ outp,
    const short* __restrict__ c2WT, const float* __restrict__ c2b,
    P3 ids, const float* __restrict__ alng, const float* __restrict__ alnb,
    const float* __restrict__ llng, const float* __restrict__ llnb,
    int enc0, int i)
{
    const int l = blockIdx.z;
    const int genc = enc0 + l;
    const int wo = genc * 2 + i;
    const short* A16 = qkv16 + (size_t)(l * 3) * kSZ;
    float* seqs = seqs_b + (size_t)l * kSZ;
    if (i == 0) {
        gemm_body<true>(A16, nullptr, c2WT + (size_t)wo * 16384, c2b + wo * kH,
                        seqs, nullptr, qbuf_b + (size_t)l * kSZ, seqs,
                        128, 128, 0, ids.p[genc],
                        alng + (genc * 2 + 1) * kH, alnb + (genc * 2 + 1) * kH, 1e-8f);
    } else {
        gemm_body<true>(A16, nullptr, c2WT + (size_t)wo * 16384, c2b + wo * kH,
                        nullptr, nullptr, outp + (size_t)genc * kSZ, seqs,
                        128, 128, 0, ids.p[genc],
                        llng + genc * kH, llnb + genc * kH, 1e-8f);
    }
}

// ======================= MFMA flash attention (bf16 QKV) ===================
#define aNT 13            // 16-row tiles covering 200 (pad 208)
#define aVS 232           // Vt / P row stride in bf16

__global__ __launch_bounds__(256) void attn_mfma(
    const short* __restrict__ qkv16, const float* __restrict__ gates_b,
    const int gi, const float* __restrict__ resid_b, float* __restrict__ out_b)
{
    __shared__ short klds[200 * 64];
    __shared__ short vt[64 * aVS];
    __shared__ short pl[4][16 * aVS];
    __shared__ float glds[224];
    const int bid = (int)blockIdx.x;
    const int l = bid >> 8;
    const int rb = bid & 255;
    const int b = rb >> 1, h = rb & 1, hoff = h * 64;
    const int tid = threadIdx.x, lane = tid & 63, wv = tid >> 6;
    const size_t base = (size_t)b * kT * kH;
    const short* qp16 = qkv16 + (size_t)(l * 3 + 0) * kSZ;
    const short* kp16 = qkv16 + (size_t)(l * 3 + 1) * kSZ;
    const short* vp16 = qkv16 + (size_t)(l * 3 + 2) * kSZ;
    const float* gates = gates_b + (size_t)l * (kM * 2);
    const float* resid = resid_b + (size_t)l * kSZ;
    float* outp = out_b + (size_t)l * kSZ;

    for (int i = tid; i < 1600; i += 256) {
        const int r = i >> 3, c8 = i & 7;
        const s16x8 v = *reinterpret_cast<const s16x8*>(
            &kp16[base + (size_t)r * kH + hoff + c8 * 8]);
        *reinterpret_cast<s16x8*>(reinterpret_cast<char*>(klds) +
            ((r * 128 + c8 * 16) ^ ((r & 7) << 4))) = v;
    }
    for (int i = tid; i < 6400; i += 256) {
        const int k2 = i >> 6, d = i & 63;
        const unsigned v0 = (unsigned short)vp16[base + (size_t)(2 * k2) * kH + hoff + d];
        const unsigned v1 = (unsigned short)vp16[base + (size_t)(2 * k2 + 1) * kH + hoff + d];
        *reinterpret_cast<unsigned*>(reinterpret_cast<char*>(vt) + d * (aVS * 2) + k2 * 4)
            = v0 | (v1 << 16);
    }
    for (int i = tid; i < 1024; i += 256) {
        const int d = i >> 4, k2 = 100 + (i & 15);
        *reinterpret_cast<unsigned*>(reinterpret_cast<char*>(vt) + d * (aVS * 2) + k2 * 4) = 0;
    }
    if (tid < 224) glds[tid] = (tid < 200) ? gates[(b * kT + tid) * 2 + gi] : 0.f;
    for (int i = lane; i < 16 * aVS / 2; i += 64)
        reinterpret_cast<unsigned*>(pl[wv])[i] = 0u;
    __syncthreads();

    const int c = lane & 15, hi = lane >> 4;
    const float scale = 0.125f;

    for (int qt = wv; qt < aNT; qt += 4) {
        const short* s0 = &qp16[base + (size_t)(qt * 16 + c) * kH + hoff + hi * 8];
        const s16x8 aq0 = *reinterpret_cast<const s16x8*>(s0);
        const s16x8 aq1 = *reinterpret_cast<const s16x8*>(s0 + 32);
        f32x4 sc[aNT];
#pragma unroll
        for (int kt = 0; kt < aNT; ++kt) {
            if (kt > qt) continue;
            const int krow = kt * 16 + c;
            const int sw = (krow & 7) << 4;
            const s16x8 bk0 = *reinterpret_cast<const s16x8*>(
                reinterpret_cast<const char*>(klds) + ((krow * 128 + hi * 16) ^ sw));
            const s16x8 bk1 = *reinterpret_cast<const s16x8*>(
                reinterpret_cast<const char*>(klds) + ((krow * 128 + 64 + hi * 16) ^ sw));
            f32x4 s = {0.f, 0.f, 0.f, 0.f};
            s = mfma16(aq0, bk0, s);
            s = mfma16(aq1, bk1, s);
            sc[kt] = s;
        }
        float gq[4], m[4], ps[4];
#pragma unroll
        for (int r = 0; r < 4; ++r) {
            gq[r] = glds[qt * 16 + hi * 4 + r];
            m[r] = kNEG_INF; ps[r] = 0.f;
        }
#pragma unroll
        for (int kt = 0; kt < aNT; ++kt) {
            if (kt > qt) continue;
            const int col = kt * 16 + c;
            const float gk = glds[col] * scale;
#pragma unroll
            for (int r = 0; r < 4; ++r) {
                const int row = qt * 16 + hi * 4 + r;
                const float v = (col <= row && col < 200) ? sc[kt][r] * gq[r] * gk : kNEG_INF;
                sc[kt][r] = v;
                m[r] = fmaxf(m[r], v);
            }
        }
#pragma unroll
        for (int r = 0; r < 4; ++r)
#pragma unroll
            for (int off = 1; off < 16; off <<= 1)
                m[r] = fmaxf(m[r], __shfl_xor(m[r], off));
#pragma unroll
        for (int kt = 0; kt < aNT; ++kt) {
            if (kt > qt) continue;
#pragma unroll
            for (int r = 0; r < 4; ++r) {
                const float p = __expf(sc[kt][r] - m[r]);
                ps[r] += p;
                *reinterpret_cast<short*>(reinterpret_cast<char*>(pl[wv]) +
                    ((hi * 4 + r) * aVS + kt * 16 + c) * 2) = f2bf(p);
            }
        }
#pragma unroll
        for (int r = 0; r < 4; ++r)
#pragma unroll
            for (int off = 1; off < 16; off <<= 1)
                ps[r] += __shfl_xor(ps[r], off);
        f32x4 oacc[4] = {};
        const int nch = (qt + 2) >> 1;
#pragma unroll
        for (int ks = 0; ks < 7; ++ks) {
            if (ks >= nch) continue;
            const s16x8 pa = *reinterpret_cast<const s16x8*>(
                reinterpret_cast<const char*>(pl[wv]) + (c * aVS + ks * 32 + hi * 8) * 2);
#pragma unroll
            for (int n = 0; n < 4; ++n) {
                const s16x8 bv = *reinterpret_cast<const s16x8*>(
                    reinterpret_cast<const char*>(vt) + ((n * 16 + c) * aVS + ks * 32 + hi * 8) * 2);
                oacc[n] = mfma16(pa, bv, oacc[n]);
            }
        }
#pragma unroll
        for (int r = 0; r < 4; ++r) {
            const int row = qt * 16 + hi * 4 + r;
            if (row < 200) {
                const float inv = 1.f / ps[r];
#pragma unroll
                for (int n = 0; n < 4; ++n) {
                    const size_t off = base + (size_t)row * kH + hoff + n * 16 + c;
                    outp[off] = resid[off] + oacc[n][r] * inv;
                }
            }
        }
    }
}

// ---------------------------------------------------------------------------
extern "C" void kernel_launch(void* const* d_in, const int* in_sizes, int n_in,
                              void* d_out, int out_size, void* d_ws, size_t ws_size,
                              hipStream_t stream)
{
    const int* ids_i[3] = { (const int*)d_in[0], (const int*)d_in[1], (const int*)d_in[2] };
    const int* pos_i[3] = { (const int*)d_in[3], (const int*)d_in[4], (const int*)d_in[5] };
    const int* tm_i[3]  = { (const int*)d_in[6], (const int*)d_in[7], (const int*)d_in[8] };
    const int* itv_i[3] = { (const int*)d_in[11], (const int*)d_in[9], (const int*)d_in[10] }; // o,x,y
    const float* emb_i[3] = { (const float*)d_in[14], (const float*)d_in[12], (const float*)d_in[13] };
    const float* time_table = (const float*)d_in[15];
    const float* interval_table = (const float*)d_in[16];
    const int* adj_idx  = (const int*)d_in[17];
    const float* adj_val = (const float*)d_in[18];
    const int* adjs_idx  = (const int*)d_in[19];
    const float* adjs_val = (const float*)d_in[20];
    const float* mlp_W1 = (const float*)d_in[21];
    const float* mlp_b1 = (const float*)d_in[22];
    const float* mlp_W2 = (const float*)d_in[23];
    const float* mlp_b2 = (const float*)d_in[24];
    const float* mlp_lng = (const float*)d_in[25];
    const float* mlp_lnb = (const float*)d_in[26];
    const float* pos_emb = (const float*)d_in[27];
    const float* gate_W = (const float*)d_in[28];
    const float* gate_b = (const float*)d_in[29];
    const float* aln_g = (const float*)d_in[30];
    const float* aln_b = (const float*)d_in[31];
    const float* qW = (const float*)d_in[32];
    const float* kW = (const float*)d_in[33];
    const float* vW = (const float*)d_in[34];
    const float* c1W = (const float*)d_in[35];
    const float* c2W = (const float*)d_in[36];
    const float* qb = (const float*)d_in[37];
    const float* kb = (const float*)d_in[38];
    const float* vb = (const float*)d_in[39];
    const float* c1b = (const float*)d_in[40];
    const float* c2b = (const float*)d_in[41];
    const float* fln_g = (const float*)d_in[42];
    const float* fln_b = (const float*)d_in[43];
    const float* lln_g = (const float*)d_in[44];
    const float* lln_b = (const float*)d_in[45];

    float* out = (float*)d_out;
    float* ws = (float*)d_ws;

    // ---- layout (floats) ----
    const size_t HDR = 900000;                 // WT + CSR ints + flags
    short* WT = (short*)ws;                    // 884,736 shorts = 442,368 floats
    int* COUNTS = (int*)(ws + 442368);
    int* OFFS   = COUNTS + kROWS;              // kROWS+1
    int* CURS   = OFFS + kROWS + 1;
    int* PART   = CURS + kROWS;                // 256
    int* ROWLIST = PART + 256;                 // 25600
    int* RANK   = ROWLIST + 25600;             // kROWS
    int* NFLAG  = RANK + kROWS;                // 16
    unsigned char* FLAGS = (unsigned char*)(NFLAG + 16);

    const size_t SCRATCH_F = 16307200;         // SMC + XBUF + HID + EDGES
    const size_t needFor = [&](int ne) {
        return (HDR + (size_t)ne * (3 * kSZ + kM * 2) + SCRATCH_F) * 4;
    }(1);
    const size_t need3 = (HDR + (size_t)3 * (3 * kSZ + kM * 2) + SCRATCH_F) * 4;
    if (ws_size < needFor) return;
    const bool merged = ws_size >= need3;
    const int NE = merged ? 3 : 1;

    float* SEQS  = ws + HDR;                   // NE * kSZ
    float* TEMB  = SEQS + (size_t)NE * kSZ;
    float* QBUF  = TEMB + (size_t)NE * kSZ;
    float* GATES = QBUF + (size_t)NE * kSZ;    // NE * kM*2
    float* SCRATCH = GATES + (size_t)NE * (kM * 2);
    float* SMC  = SCRATCH;                     // 25600*128
    float* XBUF = SMC + kSZ;                   // kM*128
    short* HID  = (short*)(XBUF + kSZ);        // kM*512 shorts
    int2* EDGES = (int2*)(XBUF + kSZ + kM * 256); // after HID
    short* QKV16 = (short*)SCRATCH;            // overlay: NE*3*kSZ shorts <= scratch

    const short* qkvWT = WT;                   // [3 mats][6 wo] 128x128
    const short* c1WT = WT + (size_t)18 * 16384;
    const short* c2WT = WT + (size_t)24 * 16384;
    const short* w1T = WT + (size_t)30 * 16384;   // 3 x 512x128
    const short* w2T = w1T + 3 * 65536;           // 3 x 128x512

    // ---- one-time weight transpose/convert ----
    wt_kernel<<<6 * 16384 / 256, 256, 0, stream>>>(qW, (short*)qkvWT, 7, 7);
    wt_kernel<<<6 * 16384 / 256, 256, 0, stream>>>(kW, (short*)qkvWT + 6 * 16384, 7, 7);
    wt_kernel<<<6 * 16384 / 256, 256, 0, stream>>>(vW, (short*)qkvWT + 12 * 16384, 7, 7);
    wt_kernel<<<6 * 16384 / 256, 256, 0, stream>>>(c1W, (short*)c1WT, 7, 7);
    wt_kernel<<<6 * 16384 / 256, 256, 0, stream>>>(c2W, (short*)c2WT, 7, 7);
    wt_kernel<<<3 * 65536 / 256, 256, 0, stream>>>(mlp_W1, (short*)w1T, 7, 9);
    wt_kernel<<<3 * 65536 / 256, 256, 0, stream>>>(mlp_W2, (short*)w2T, 9, 7);

    const int mi_of[3] = { 2, 0, 1 };          // mlp index per encoder (o,x,y)
    const int g4 = (kNNZ / 4 + 255) / 256;
    P3 idsPack{ { ids_i[0], ids_i[1], ids_i[2] } };

    auto phaseA = [&](int e, int l) {
        const int* a_idx = (e == 0) ? adj_idx : adjs_idx;
        const float* a_val = (e == 0) ? adj_val : adjs_val;
        float* SEQSl = SEQS + (size_t)l * kSZ;
        float* TEMBl = TEMB + (size_t)l * kSZ;
        float* QBUFl = QBUF + (size_t)l * kSZ;
        float* GATESl = GATES + (size_t)l * (kM * 2);
        hipMemsetAsync(FLAGS, 0, kROWS, stream);
        hipMemsetAsync(COUNTS, 0, kROWS * sizeof(int), stream);
        hipMemsetAsync(NFLAG, 0, sizeof(int), stream);
        flag_kernel<<<kM / 256, 256, 0, stream>>>(ids_i[e], FLAGS);
        rowlist_kernel<<<(kROWS + 255) / 256, 256, 0, stream>>>(FLAGS, ROWLIST, RANK, NFLAG);
        count4_kernel<<<g4, 256, 0, stream>>>(a_idx, FLAGS, COUNTS);
        scan_pass1<<<98, 256, 0, stream>>>(COUNTS, PART);
        scan_pass2<<<1, 128, 0, stream>>>(PART, 98);
        scan_pass3<<<98, 256, 0, stream>>>(COUNTS, PART, OFFS, CURS);
        scatter4_kernel<<<g4, 256, 0, stream>>>(a_idx, a_val, FLAGS, CURS, EDGES);
        smooth_kernel<<<6400, 256, 0, stream>>>(EDGES, OFFS, ROWLIST, NFLAG, emb_i[e], SMC);
        gather_kernel<<<kM / 2, 256, 0, stream>>>(ids_i[e], RANK, SMC, SEQSl);
        build_x_kernel<<<kM / 2, 256, 0, stream>>>(itv_i[e], tm_i[e], interval_table, time_table, XBUF);
        const int mi = mi_of[e];
        gemm_w1<<<dim3(4, kM / 128), 256, 0, stream>>>(
            XBUF, w1T + (size_t)mi * 65536, mlp_b1 + mi * 512, HID);
        gemm_w2<<<dim3(1, kM / 128), 256, 0, stream>>>(
            HID, w2T + (size_t)mi * 65536, mlp_b2 + mi * kH, TEMBl,
            mlp_lng + mi * kH, mlp_lnb + mi * kH);
        posmg_kernel<<<kM / 4, 256, 0, stream>>>(
            ids_i[e], pos_i[e], pos_emb + (size_t)e * kT * kH,
            gate_W + e * kH * 2, gate_b + e * 2, SEQSl, TEMBl, GATESl,
            aln_g + (e * 2) * kH, aln_b + (e * 2) * kH, QBUFl);
    };

    auto phaseB = [&](int enc0, int nenc) {
        for (int i = 0; i < 2; ++i) {
            gemm_qkv<<<dim3(1, kM / 128, 3 * nenc), 256, 0, stream>>>(
                QBUF, TEMB, SEQS, QKV16, qkvWT, enc0, i, qb, kb, vb);
            attn_mfma<<<256 * nenc, 256, 0, stream>>>(QKV16, GATES, i, QBUF, SEQS);
            ln_fln<<<(kM / 4) * nenc, 256, 0, stream>>>(SEQS, fln_g, fln_b, enc0, i);
            gemm_c1<<<dim3(1, kM / 128, nenc), 256, 0, stream>>>(
                SEQS, QKV16, c1WT, c1b, enc0, i);
            gemm_c2<<<dim3(1, kM / 128, nenc), 256, 0, stream>>>(
                QKV16, SEQS, QBUF, out, c2WT, c2b, idsPack,
                aln_g, aln_b, lln_g, lln_b, enc0, i);
        }
    };

    if (merged) {
        for (int e = 0; e < 3; ++e) phaseA(e, e);
        phaseB(0, 3);
    } else {
        for (int e = 0; e < 3; ++e) {
            phaseA(e, 0);
            phaseB(e, 1);
        }
    }
}